// Round 5
// baseline (12954.018 us; speedup 1.0000x reference)
//
#include <hip/hip_runtime.h>
#include <stdint.h>

typedef __bf16 bf16;
typedef __bf16 bf16x8 __attribute__((ext_vector_type(8)));
typedef short  s16x8  __attribute__((ext_vector_type(8)));
typedef float  f32x4  __attribute__((ext_vector_type(4)));
typedef uint32_t u32;

#define NB   1024
#define LSEQ 336
#define HID  384
#define HOR  18
#define SMEM_BYTES 36864

// ---------------- device-global scratch ----------------
__device__ bf16  g_A0[2*NB*HID];      // [2][1024][384]: h0 ping-pong (device-scope access only)
__device__ bf16  g_A1[2*NB*768];      // [2][1024][768]: h0_out | h1 (device-scope access only)
__device__ bf16  g_Adec[2*NB*768];    // [2][1024][768]: din | h_dec
__device__ bf16  g_Adin[NB*416];      // [1024][416]: y | feat4 | ctx384 | pad
__device__ bf16  g_xb[NB*LSEQ*8];     // bf16 x
__device__ float g_cdec[NB*HID];
__device__ float g_u[NB*HID];
__device__ float g_bias0[1536], g_bias1[1536], g_biasd[1536], g_biasdin[384];
__device__ bf16  g_Bp0[12*13*4096];         // enc L0 pack (32-col jb granularity)
__device__ bf16  g_Bp1n[24*24*4*64*8];      // enc L1 pack (16-col jn granularity)
__device__ bf16  g_Bpd[12*24*4096];
__device__ bf16  g_Bpi[3*13*4096];
__device__ bf16  g_Bpu[3*12*4096];
__device__ bf16  g_enc[(size_t)NB*LSEQ*HID];   // 264 MB, [B][L][H]
__device__ int   g_f0[8*LSEQ];        // [g][w], w in 0..335, target 12
__device__ int   g_f1[4*(LSEQ+1)];    // [m][s], s in 1..336, target 24

__device__ __forceinline__ float sigf(float x){ return 1.0f/(1.0f + __expf(-x)); }
__device__ __forceinline__ float tanh_f(float x){
  x = fminf(fmaxf(x, -15.f), 15.f);
  float e = __expf(2.f*x);
  return (e - 1.f)/(e + 1.f);
}

// ---- device-scope (L2-bypassing, L3-coherent) 16B access as 2x u64 relaxed atomics ----
__device__ __forceinline__ bf16x8 dl16(const bf16* p){
  uint64_t lo = __hip_atomic_load((uint64_t*)p,     __ATOMIC_RELAXED, __HIP_MEMORY_SCOPE_AGENT);
  uint64_t hi = __hip_atomic_load((uint64_t*)p + 1, __ATOMIC_RELAXED, __HIP_MEMORY_SCOPE_AGENT);
  union{ uint64_t q[2]; bf16x8 v; } u; u.q[0]=lo; u.q[1]=hi; return u.v;
}
__device__ __forceinline__ void ds16(bf16* p, s16x8 v){
  union{ s16x8 v; uint64_t q[2]; } u; u.v = v;
  __hip_atomic_store((uint64_t*)p,     u.q[0], __ATOMIC_RELAXED, __HIP_MEMORY_SCOPE_AGENT);
  __hip_atomic_store((uint64_t*)p + 1, u.q[1], __ATOMIC_RELAXED, __HIP_MEMORY_SCOPE_AGENT);
}

// ---------------- per-call state zeroing (replay determinism) ----------------
__global__ void zero_state_k(){
  int i = blockIdx.x*blockDim.x + threadIdx.x;
  int st = gridDim.x*blockDim.x;
  bf16 z = (bf16)0.f;
  for(int k=i;k<2*NB*HID;k+=st) g_A0[k]=z;
  for(int k=i;k<2*NB*768;k+=st) g_A1[k]=z;
  for(int k=i;k<NB*HID;k+=st) g_cdec[k]=0.f;
  for(int k=i;k<8*LSEQ;k+=st) g_f0[k]=0;
  for(int k=i;k<4*(LSEQ+1);k+=st) g_f1[k]=0;
}

__global__ void pack_xb_k(const float* __restrict__ x){
  int i = blockIdx.x*256 + threadIdx.x;
  int n = NB*LSEQ*8;
  for(int k=i; k<n; k+=gridDim.x*256) g_xb[k] = (bf16)x[k];
}

// ---------------- weight packs ----------------
// gates pack: out[jb][ks][tt(8)][lane(64)][8], n = (tt>>1)*384 + jb*32 + (tt&1)*16 + (lane&15)
__global__ void pack_gates_k(int mode, const float* __restrict__ W1, const float* __restrict__ W2,
                             int nks){
  bf16* out = (mode==0)? g_Bp0 : g_Bpd;
  size_t idx = (size_t)blockIdx.x*256 + threadIdx.x;
  size_t total = (size_t)12*nks*512;
  if(idx >= total) return;
  int lane = (int)(idx & 63);
  int tt   = (int)((idx>>6) & 7);
  size_t tmp = idx >> 9;
  int ks = (int)(tmp % nks);
  int jb = (int)(tmp / nks);
  int n  = (tt>>1)*HID + jb*32 + (tt&1)*16 + (lane&15);
  int kb = ks*32 + (lane>>4)*8;
  bf16x8 v;
  #pragma unroll
  for(int i=0;i<8;i++){
    int k = kb + i;
    float f;
    if(mode==0) f = (k<384) ? W1[(size_t)n*384 + k] : (k<392 ? W2[(size_t)n*8 + (k-384)] : 0.f);
    else        f = (k<384) ? W1[(size_t)n*384 + k] : W2[(size_t)n*384 + (k-384)];
    v[i] = (bf16)f;
  }
  *(bf16x8*)(out + idx*8) = v;
}

// enc L1 pack: out[jn(24)][ks(24)][g(4)][lane(64)][8], n = g*384 + jn*16 + (lane&15)
__global__ void pack_gates16_k(const float* __restrict__ Wih1, const float* __restrict__ Whh1){
  int idx = blockIdx.x*256 + threadIdx.x;
  if(idx >= 24*24*4*64) return;
  int lane = idx&63, rem = idx>>6;
  int g = rem&3; rem >>= 2;
  int ks = rem%24, jn = rem/24;
  int n  = g*HID + jn*16 + (lane&15);
  int kb = ks*32 + (lane>>4)*8;
  bf16x8 v;
  #pragma unroll
  for(int i=0;i<8;i++){
    int k = kb+i;
    float f = (k<384)? Wih1[(size_t)n*384 + k] : Whh1[(size_t)n*384 + (k-384)];
    v[i] = (bf16)f;
  }
  *(bf16x8*)(g_Bp1n + (size_t)idx*8) = v;
}

// plain pack: out[nb][ks][tt(8)][lane][8], n = nb*128 + tt*16 + (lane&15)
__global__ void pack_plain_k(int mode, const float* __restrict__ W, int nks, int nb_cnt){
  bf16* out = mode ? g_Bpu : g_Bpi;
  size_t idx = (size_t)blockIdx.x*256 + threadIdx.x;
  size_t total = (size_t)nb_cnt*nks*512;
  if(idx>=total) return;
  int lane = (int)(idx&63);
  int tt   = (int)((idx>>6)&7);
  size_t tmp = idx>>9;
  int ks = (int)(tmp%nks);
  int nb = (int)(tmp/nks);
  int n  = nb*128 + tt*16 + (lane&15);
  int kb = ks*32 + (lane>>4)*8;
  bf16x8 v;
  #pragma unroll
  for(int i=0;i<8;i++){
    int k = kb+i;
    float f;
    if(mode==0) f = (k<389)? W[(size_t)n*389 + k] : 0.f;
    else        f = W[(size_t)k*384 + n];
    v[i]=(bf16)f;
  }
  *(bf16x8*)(out + idx*8) = v;
}

__global__ void prep_misc_k(const float* bih0,const float* bhh0,const float* bih1,const float* bhh1,
                            const float* dbih,const float* dbhh,const float* dinb){
  int i = blockIdx.x*256 + threadIdx.x;
  if(i<1536){ g_bias0[i]=bih0[i]+bhh0[i]; g_bias1[i]=bih1[i]+bhh1[i]; g_biasd[i]=dbih[i]+dbhh[i]; }
  if(i<384) g_biasdin[i]=dinb[i];
}

// ---------------- dataflow spin (relaxed agent atomics, no cache maintenance) ----------------
__device__ __forceinline__ void spin_ge(int* p, int tgt){
  while(__hip_atomic_load(p, __ATOMIC_RELAXED, __HIP_MEMORY_SCOPE_AGENT) < tgt)
    __builtin_amdgcn_s_sleep(8);
}

// ---------------- persistent 2-layer encoder, dataflow-synchronized, fence-free ----------------
// blocks 0..95  : layer0, g=bid/12 (128 rows), jb=bid%12 (32 h-cols). B 104KB + tr 8KB LDS.
// blocks 96..191: layer1, m=(bid-96)/24 (256 rows), jn=(bid-96)%24 (16 h-cols). 96KB + 8KB.
// h-state exchanged via agent-scope relaxed atomics (L2-bypass, L3-coherent). No fences:
// producer stores are vmcnt-drained by __syncthreads before the flag bump; consumer loads
// are branch-ordered after the flag poll and bypass (possibly stale) L2 lines.
__global__ __launch_bounds__(256,1)
void enc3_k(){
  extern __shared__ char lds[];
  const int bid = blockIdx.x, tid = threadIdx.x;
  const int lane = tid&63, wv = tid>>6;
  const int l15 = lane&15, lk = (lane>>4)*8;

  if(bid < 96){
    const int g = bid/12, jb = bid%12;
    { const s16x8* src = (const s16x8*)(g_Bp0 + (size_t)jb*13*4096);
      s16x8* dst = (s16x8*)lds;
      for(int i=tid;i<13*512;i+=256) dst[i]=src[i]; }
    bf16* tr = (bf16*)(lds + 13*8192);        // [128][32] bf16
    __syncthreads();
    const int jj0 = jb*32 + l15;
    float bia[2],bfa[2],bga[2],boa[2];
    #pragma unroll
    for(int jh=0;jh<2;jh++){
      bia[jh]=g_bias0[jj0+jh*16];     bfa[jh]=g_bias0[384+jj0+jh*16];
      bga[jh]=g_bias0[768+jj0+jh*16]; boa[jh]=g_bias0[1152+jj0+jh*16];
    }
    size_t aoff[2], xoff[2];
    #pragma unroll
    for(int mt=0;mt<2;mt++){
      int row = g*128 + wv*32 + mt*16 + l15;
      aoff[mt] = (size_t)row*HID + lk;
      xoff[mt] = (size_t)row*LSEQ*8;
    }
    float c[2][2][4] = {};
    for(int w=0; w<LSEQ; w++){
      if(tid==0){
        if(w>=1) spin_ge(&g_f0[g*LSEQ + (w-1)], 12);
        if(w>=2) spin_ge(&g_f1[(g>>1)*(LSEQ+1) + (w-1)], 24);
      }
      __syncthreads();
      const bf16* Ar = g_A0 + (size_t)(w&1)*NB*HID;
      bf16x8 af[13][2];
      #pragma unroll
      for(int ks=0;ks<12;ks++)
        #pragma unroll
        for(int mt=0;mt<2;mt++)
          af[ks][mt] = dl16(Ar + aoff[mt] + ks*32);
      #pragma unroll
      for(int mt=0;mt<2;mt++){
        bf16x8 z;
        #pragma unroll
        for(int e=0;e<8;e++) z[e]=(bf16)0.f;
        if(lk==0) z = *(const bf16x8*)(g_xb + xoff[mt] + (size_t)w*8);
        af[12][mt] = z;
      }
      f32x4 acc[2][8];
      #pragma unroll
      for(int m2=0;m2<2;m2++)
        #pragma unroll
        for(int tt=0;tt<8;tt++) acc[m2][tt] = (f32x4){0.f,0.f,0.f,0.f};
      #pragma unroll
      for(int ks=0;ks<13;ks++){
        #pragma unroll
        for(int tt=0;tt<8;tt++){
          bf16x8 bfr = *(const bf16x8*)(lds + (ks*8+tt)*1024 + lane*16);
          acc[0][tt] = __builtin_amdgcn_mfma_f32_16x16x32_bf16(af[ks][0], bfr, acc[0][tt],0,0,0);
          acc[1][tt] = __builtin_amdgcn_mfma_f32_16x16x32_bf16(af[ks][1], bfr, acc[1][tt],0,0,0);
        }
      }
      #pragma unroll
      for(int mt=0;mt<2;mt++)
        #pragma unroll
        for(int jh=0;jh<2;jh++)
          #pragma unroll
          for(int r=0;r<4;r++){
            float zi=acc[mt][0+jh][r]+bia[jh], zf=acc[mt][2+jh][r]+bfa[jh],
                  zg=acc[mt][4+jh][r]+bga[jh], zo=acc[mt][6+jh][r]+boa[jh];
            float cn = sigf(zf)*c[mt][jh][r] + sigf(zi)*tanh_f(zg);
            c[mt][jh][r]=cn;
            int lr = wv*32 + mt*16 + (lane>>4)*4 + r;
            tr[lr*32 + jh*16 + l15] = (bf16)(sigf(zo)*tanh_f(cn));
          }
      __syncthreads();
      bf16* A0n = g_A0 + (size_t)((w&1)^1)*NB*HID;
      bf16* A1n = g_A1 + (size_t)((w&1)^1)*NB*768;
      #pragma unroll
      for(int h=0;h<2;h++){
        int p = tid + h*256;
        int row = p>>2, cc = p&3;
        s16x8 v = *(const s16x8*)(tr + row*32 + cc*8);
        int grow = g*128 + row;
        ds16(A0n + (size_t)grow*HID + jb*32 + cc*8, v);
        ds16(A1n + (size_t)grow*768 + jb*32 + cc*8, v);
      }
      __syncthreads();   // drains vmcnt(0): device-scope stores are at L3 before flag bump
      if(tid==0)
        __hip_atomic_fetch_add(&g_f0[g*LSEQ + w], 1, __ATOMIC_RELAXED, __HIP_MEMORY_SCOPE_AGENT);
    }
  } else {
    const int b2 = bid-96, m = b2/24, jn = b2%24;
    { const s16x8* src = (const s16x8*)(g_Bp1n + (size_t)jn*24*2048);
      s16x8* dst = (s16x8*)lds;
      for(int i=tid;i<24*256;i+=256) dst[i]=src[i]; }
    bf16* tr = (bf16*)(lds + 24*4096);        // [256][16] bf16
    __syncthreads();
    const int jj = jn*16 + l15;
    const float bi=g_bias1[jj], bff=g_bias1[384+jj], bg=g_bias1[768+jj], bo=g_bias1[1152+jj];
    size_t aoff[4];
    #pragma unroll
    for(int mt=0;mt<4;mt++) aoff[mt] = (size_t)(m*256 + wv*64 + mt*16 + l15)*768 + lk;
    float c[4][4] = {};
    for(int s=1; s<=LSEQ; s++){
      if(tid==0){
        spin_ge(&g_f0[(2*m)*LSEQ + (s-1)], 12);
        spin_ge(&g_f0[(2*m+1)*LSEQ + (s-1)], 12);
        if(s>=2) spin_ge(&g_f1[m*(LSEQ+1) + (s-1)], 24);
      }
      __syncthreads();
      const bf16* Ar = g_A1 + (size_t)(s&1)*NB*768;
      bf16x8 ap[4][4];
      #pragma unroll
      for(int d=0;d<4;d++)
        #pragma unroll
        for(int mt=0;mt<4;mt++) ap[d][mt] = dl16(Ar + aoff[mt] + d*32);
      f32x4 acc[4][4];
      #pragma unroll
      for(int mt=0;mt<4;mt++)
        #pragma unroll
        for(int g4=0;g4<4;g4++) acc[mt][g4] = (f32x4){0.f,0.f,0.f,0.f};
      #pragma unroll
      for(int ks=0;ks<24;ks++){
        bf16x8 bfr[4];
        #pragma unroll
        for(int g4=0;g4<4;g4++) bfr[g4] = *(const bf16x8*)(lds + (ks*4+g4)*1024 + lane*16);
        bf16x8 a[4];
        #pragma unroll
        for(int mt=0;mt<4;mt++) a[mt] = ap[ks&3][mt];
        if(ks<20){
          #pragma unroll
          for(int mt=0;mt<4;mt++) ap[ks&3][mt] = dl16(Ar + aoff[mt] + (ks+4)*32);
        }
        #pragma unroll
        for(int mt=0;mt<4;mt++)
          #pragma unroll
          for(int g4=0;g4<4;g4++)
            acc[mt][g4] = __builtin_amdgcn_mfma_f32_16x16x32_bf16(a[mt], bfr[g4], acc[mt][g4],0,0,0);
      }
      #pragma unroll
      for(int mt=0;mt<4;mt++)
        #pragma unroll
        for(int r=0;r<4;r++){
          float zi=acc[mt][0][r]+bi, zf=acc[mt][1][r]+bff,
                zg=acc[mt][2][r]+bg, zo=acc[mt][3][r]+bo;
          float cn = sigf(zf)*c[mt][r] + sigf(zi)*tanh_f(zg);
          c[mt][r]=cn;
          int lr = wv*64 + mt*16 + (lane>>4)*4 + r;
          tr[lr*16 + l15] = (bf16)(sigf(zo)*tanh_f(cn));
        }
      __syncthreads();
      bf16* A1n = g_A1 + (size_t)((s&1)^1)*NB*768;
      const int t = s-1;
      #pragma unroll
      for(int h=0;h<2;h++){
        int p = tid + h*256;
        int row = p>>1, hf2 = p&1;
        s16x8 v = *(const s16x8*)(tr + row*16 + hf2*8);
        int grow = m*256 + row;
        ds16(A1n + (size_t)grow*768 + 384 + jn*16 + hf2*8, v);
        *(s16x8*)(g_enc + ((size_t)grow*LSEQ + t)*HID + jn*16 + hf2*8) = v;  // plain: read after kernel end
      }
      __syncthreads();   // drains vmcnt(0) before flag bump
      if(tid==0)
        __hip_atomic_fetch_add(&g_f1[m*(LSEQ+1) + s], 1, __ATOMIC_RELAXED, __HIP_MEMORY_SCOPE_AGENT);
    }
  }
}

// ---------------- GEMM core (decoder) ----------------
struct SReg { s16x8 a0,a1,b0,b1; };

__device__ __forceinline__ void stage_load(const bf16* __restrict__ A, int ldA,
                                           const bf16* __restrict__ Bk, int tid, SReg& sr){
  int c0 = tid, c1 = tid+256;
  sr.a0 = *(const s16x8*)(A + (size_t)(c0>>2)*ldA + (c0&3)*8);
  sr.a1 = *(const s16x8*)(A + (size_t)(c1>>2)*ldA + (c1&3)*8);
  const s16x8* B8 = (const s16x8*)Bk;
  sr.b0 = B8[c0]; sr.b1 = B8[c1];
}

__device__ __forceinline__ void stage_write(char* Ab, char* Bb, int tid, const SReg& sr){
  int c0 = tid, c1 = tid+256;
  *(s16x8*)(Ab + (c0>>2)*80 + (c0&3)*16) = sr.a0;
  *(s16x8*)(Ab + (c1>>2)*80 + (c1&3)*16) = sr.a1;
  *(s16x8*)(Bb + c0*16) = sr.b0;
  *(s16x8*)(Bb + c1*16) = sr.b1;
}

__device__ __forceinline__ void gemm_core(const bf16* __restrict__ A, int ldA,
                                          const bf16* __restrict__ Bp, int nks,
                                          char* smem, f32x4 acc[4][4]){
  const int tid = threadIdx.x;
  const int lane = tid & 63, wv = tid>>6, wm = wv>>1, wn = wv&1;
  char* Ab0 = smem;            char* Ab1 = smem + 10240;
  char* Bb0 = smem + 20480;    char* Bb1 = smem + 28672;
  f32x4 z = {0.f,0.f,0.f,0.f};
  #pragma unroll
  for(int m=0;m<4;m++)
    #pragma unroll
    for(int g=0;g<4;g++) acc[m][g]=z;
  SReg sr;
  stage_load(A, ldA, Bp, tid, sr);
  stage_write(Ab0, Bb0, tid, sr);
  const int aoff = (wm*64 + (lane&15))*80 + (lane>>4)*16;
  const int boff = wn*1024 + lane*16;
  for(int ks=0; ks<nks; ks++){
    char* Ac = (ks&1)? Ab1: Ab0;
    char* Bc = (ks&1)? Bb1: Bb0;
    char* An = (ks&1)? Ab0: Ab1;
    char* Bn = (ks&1)? Bb0: Bb1;
    bool more = (ks+1)<nks;
    if(more) stage_load(A + (ks+1)*32, ldA, Bp + (size_t)(ks+1)*4096, tid, sr);
    __syncthreads();
    bf16x8 af[4], bfr[4];
    #pragma unroll
    for(int mt=0;mt<4;mt++) af[mt] = *(const bf16x8*)(Ac + aoff + mt*16*80);
    #pragma unroll
    for(int g=0;g<4;g++)    bfr[g] = *(const bf16x8*)(Bc + boff + g*2048);
    #pragma unroll
    for(int mt=0;mt<4;mt++)
      #pragma unroll
      for(int g=0;g<4;g++)
        acc[mt][g] = __builtin_amdgcn_mfma_f32_16x16x32_bf16(af[mt], bfr[g], acc[mt][g], 0,0,0);
    if(more) stage_write(An, Bn, tid, sr);
  }
}

// ---------------- LSTM epilogue (decoder) ----------------
__device__ __forceinline__ void lstm_epi(f32x4 acc[4][4], int mbase, int jb,
     const float* __restrict__ bias, float* __restrict__ cst,
     bf16* __restrict__ d0, int ld0, bf16* __restrict__ d1, size_t ld1){
  int lane = threadIdx.x&63, wv = threadIdx.x>>6, wm = wv>>1, wn = wv&1;
  int j = jb*32 + wn*16 + (lane&15);
  float bi = bias[j], bff = bias[384+j], bg = bias[768+j], bo = bias[1152+j];
  #pragma unroll
  for(int mt=0;mt<4;mt++){
    #pragma unroll
    for(int r=0;r<4;r++){
      int brow = mbase + wm*64 + mt*16 + (lane>>4)*4 + r;
      float zi = acc[mt][0][r]+bi, zf = acc[mt][1][r]+bff,
            zg = acc[mt][2][r]+bg, zo = acc[mt][3][r]+bo;
      size_t ci = (size_t)brow*HID + j;
      float cold = cst[ci];
      float cn = sigf(zf)*cold + sigf(zi)*tanh_f(zg);
      cst[ci] = cn;
      bf16 hb = (bf16)(sigf(zo)*tanh_f(cn));
      d0[(size_t)brow*ld0 + j] = hb;
      if(d1) d1[(size_t)brow*ld1 + j] = hb;
    }
  }
}

// ---------------- decoder LSTM ----------------
__global__ __launch_bounds__(256)
void dec_lstm_k(int t){
  __shared__ char smem[SMEM_BYTES];
  int bid = blockIdx.x, mb = bid/12, jb = bid%12;
  int rs = t&1, wsl = rs^1;
  f32x4 acc[4][4];
  gemm_core(g_Adec + (size_t)rs*NB*768 + (size_t)mb*128*768, 768,
            g_Bpd + (size_t)jb*24*4096, 24, smem, acc);
  lstm_epi(acc, mb*128, jb, g_biasd, g_cdec,
           g_Adec + (size_t)wsl*NB*768 + 384, 768, (bf16*)nullptr, 0);
}

// ---------------- plain GEMM: mode 1 = u-proj (h@Wa -> g_u f32), mode 0 = dec_in relu ----------------
__global__ __launch_bounds__(256)
void plain_gemm_k(int t, int mode){
  __shared__ char smem[SMEM_BYTES];
  int bid = blockIdx.x, mb = bid/3, nb = bid%3;
  int rs = t&1;
  const bf16* A; int ldA, nks; const bf16* Bp;
  if(mode==1){ A = g_Adec + (size_t)rs*NB*768 + 384; ldA=768; Bp = g_Bpu; nks=12; }
  else       { A = g_Adin;                           ldA=416; Bp = g_Bpi; nks=13; }
  f32x4 acc[4][4];
  gemm_core(A + (size_t)mb*128*ldA, ldA, Bp + (size_t)nb*nks*4096, nks, smem, acc);
  int lane = threadIdx.x&63, wv = threadIdx.x>>6, wm = wv>>1, wn = wv&1;
  bf16* dbf = g_Adec + (size_t)rs*NB*768;
  #pragma unroll
  for(int mt=0;mt<4;mt++){
    #pragma unroll
    for(int ti=0;ti<4;ti++){
      int n = nb*128 + (ti*2+wn)*16 + (lane&15);
      #pragma unroll
      for(int r=0;r<4;r++){
        int brow = mb*128 + wm*64 + mt*16 + (lane>>4)*4 + r;
        float v = acc[mt][ti][r];
        if(mode==0){ v += g_biasdin[n]; v = fmaxf(v,0.f); dbf[(size_t)brow*768 + n] = (bf16)v; }
        else g_u[(size_t)brow*384 + n] = v;
      }
    }
  }
}

// ---------------- attention: fused scores+softmax+ctx (online) ----------------
__global__ __launch_bounds__(256)
void attn_k(){
  __shared__ float sm[4][392];
  int tid = threadIdx.x, lane = tid&63, w = tid>>6;
  int bl = w>>1, hf = w&1;
  int b = blockIdx.x*2 + bl;
  const float* ub = g_u + (size_t)b*HID + lane*6;
  float u0=ub[0],u1=ub[1],u2=ub[2],u3=ub[3],u4=ub[4],u5=ub[5];
  const u32* er = (const u32*)(g_enc + (size_t)b*LSEQ*HID) + (size_t)hf*168*192 + lane*3;
  float m=-1e30f, den=0.f, a0=0,a1=0,a2=0,a3=0,a4=0,a5=0;
  for(int l=0;l<168;l++){
    u32 w0 = er[0], w1 = er[1], w2 = er[2];
    er += 192;
    float e0 = __uint_as_float(w0<<16);
    float e1 = __uint_as_float(w0 & 0xffff0000u);
    float e2 = __uint_as_float(w1<<16);
    float e3 = __uint_as_float(w1 & 0xffff0000u);
    float e4 = __uint_as_float(w2<<16);
    float e5 = __uint_as_float(w2 & 0xffff0000u);
    float p = e0*u0 + e1*u1 + e2*u2 + e3*u3 + e4*u4 + e5*u5;
    #pragma unroll
    for(int o=1;o<64;o<<=1) p += __shfl_xor(p, o, 64);
    float mn = fmaxf(m, p);
    float al = __expf(m - mn), pe = __expf(p - mn);
    den = den*al + pe;
    a0 = a0*al + pe*e0; a1 = a1*al + pe*e1; a2 = a2*al + pe*e2;
    a3 = a3*al + pe*e3; a4 = a4*al + pe*e4; a5 = a5*al + pe*e5;
    m = mn;
  }
  if(lane==0){ sm[w][0]=m; sm[w][1]=den; }
  sm[w][2+lane*6+0]=a0; sm[w][2+lane*6+1]=a1; sm[w][2+lane*6+2]=a2;
  sm[w][2+lane*6+3]=a3; sm[w][2+lane*6+4]=a4; sm[w][2+lane*6+5]=a5;
  __syncthreads();
  if(hf==0){
    float m2 = sm[w+1][0], d2 = sm[w+1][1];
    float M = fmaxf(m, m2);
    float f1 = __expf(m - M), f2 = __expf(m2 - M);
    float inv = 1.f/(den*f1 + d2*f2);
    bf16* cd = g_Adin + (size_t)b*416 + 5 + lane*6;
    cd[0] = (bf16)((a0*f1 + sm[w+1][2+lane*6+0]*f2)*inv);
    cd[1] = (bf16)((a1*f1 + sm[w+1][2+lane*6+1]*f2)*inv);
    cd[2] = (bf16)((a2*f1 + sm[w+1][2+lane*6+2]*f2)*inv);
    cd[3] = (bf16)((a3*f1 + sm[w+1][2+lane*6+3]*f2)*inv);
    cd[4] = (bf16)((a4*f1 + sm[w+1][2+lane*6+4]*f2)*inv);
    cd[5] = (bf16)((a5*f1 + sm[w+1][2+lane*6+5]*f2)*inv);
  }
}

// ---------------- output head + next-step A_din fill ----------------
__global__ void post_k(int t, const float* __restrict__ outW,
                       const float* __restrict__ outb, float* __restrict__ out,
                       const float* __restrict__ ff){
  int b = blockIdx.x*256 + threadIdx.x;
  if(b>=NB) return;
  int wsl = (t&1)^1;
  const s16x8* hp = (const s16x8*)(g_Adec + (size_t)wsl*NB*768 + (size_t)b*768 + 384);
  float acc = 0.f;
  #pragma unroll 4
  for(int i=0;i<48;i++){
    s16x8 v = hp[i];
    #pragma unroll
    for(int e=0;e<8;e++){
      float hv = __uint_as_float(((u32)(uint16_t)v[e])<<16);
      acc += hv*outW[i*8+e];
    }
  }
  float y = acc + outb[0];
  out[(size_t)b*HOR + t] = y;
  g_Adin[(size_t)b*416] = (bf16)y;
  if(t+1<HOR){
    #pragma unroll
    for(int k=0;k<4;k++) g_Adin[(size_t)b*416 + 1 + k] = (bf16)ff[(size_t)b*HOR*4 + (t+1)*4 + k];
  }
}

// ---------------- decoder init ----------------
__global__ void dec_prep_k(const float* __restrict__ ff){
  int i = blockIdx.x*256 + threadIdx.x;
  if(i < NB*HID){
    int b = i/HID, j = i%HID;
    g_Adec[(size_t)b*768 + 384 + j] = g_A1[(size_t)1*NB*768 + (size_t)b*768 + 384 + j];
  }
  if(i < NB*4){
    int b = i>>2, k = i&3;
    g_Adin[(size_t)b*416 + 1 + k] = (bf16)ff[(size_t)b*HOR*4 + k];
  }
  if(i < NB) g_Adin[(size_t)i*416] = (bf16)0.f;
}

extern "C" void kernel_launch(void* const* d_in, const int* in_sizes, int n_in,
                              void* d_out, int out_size, void* d_ws, size_t ws_size,
                              hipStream_t stream){
  const float* x    = (const float*)d_in[0];
  const float* ff   = (const float*)d_in[1];
  const float* Wih0 = (const float*)d_in[2];
  const float* Whh0 = (const float*)d_in[3];
  const float* bih0 = (const float*)d_in[4];
  const float* bhh0 = (const float*)d_in[5];
  const float* Wih1 = (const float*)d_in[6];
  const float* Whh1 = (const float*)d_in[7];
  const float* bih1 = (const float*)d_in[8];
  const float* bhh1 = (const float*)d_in[9];
  const float* Wa   = (const float*)d_in[10];
  const float* dinW = (const float*)d_in[11];
  const float* dinb = (const float*)d_in[12];
  const float* dWih = (const float*)d_in[13];
  const float* dWhh = (const float*)d_in[14];
  const float* dbih = (const float*)d_in[15];
  const float* dbhh = (const float*)d_in[16];
  const float* outW = (const float*)d_in[17];
  const float* outb = (const float*)d_in[18];
  float* out = (float*)d_out;

  zero_state_k<<<1024,256,0,stream>>>();
  pack_xb_k<<<2048,256,0,stream>>>(x);
  pack_gates_k<<<(12*13*512)/256,256,0,stream>>>(0, Whh0, Wih0, 13);
  pack_gates16_k<<<576,256,0,stream>>>(Wih1, Whh1);
  pack_gates_k<<<(12*24*512)/256,256,0,stream>>>(2, dWih, dWhh, 24);
  pack_plain_k<<<(3*13*512)/256,256,0,stream>>>(0, dinW, 13, 3);
  pack_plain_k<<<(3*12*512)/256,256,0,stream>>>(1, Wa, 12, 3);
  prep_misc_k<<<8,256,0,stream>>>(bih0,bhh0,bih1,bhh1,dbih,dbhh,dinb);

  hipFuncSetAttribute((const void*)enc3_k,
                      hipFuncAttributeMaxDynamicSharedMemorySize, 114688);
  enc3_k<<<192,256,114688,stream>>>();

  dec_prep_k<<<1536,256,0,stream>>>(ff);
  for(int t=0;t<HOR;t++){
    plain_gemm_k<<<24,256,0,stream>>>(t, 1);
    attn_k<<<512,256,0,stream>>>();
    plain_gemm_k<<<24,256,0,stream>>>(t, 0);
    dec_lstm_k<<<96,256,0,stream>>>(t);
    post_k<<<4,256,0,stream>>>(t, outW, outb, out, ff);
  }
  (void)in_sizes; (void)n_in; (void)out_size; (void)d_ws; (void)ws_size;
}

// Round 8
// 11104.200 us; speedup vs baseline: 1.1666x; 1.1666x over previous
//
#include <hip/hip_runtime.h>
#include <stdint.h>

typedef __bf16 bf16;
typedef __bf16 bf16x8 __attribute__((ext_vector_type(8)));
typedef short  s16x8  __attribute__((ext_vector_type(8)));
typedef float  f32x4  __attribute__((ext_vector_type(4)));
typedef uint32_t u32;

#define NB   1024
#define LSEQ 336
#define HID  384
#define HOR  18
#define SMEM_BYTES 36864

// ---------------- device-global scratch ----------------
__device__ bf16  g_A0[2*NB*HID];      // [2][1024][384]: h0 ping-pong
__device__ bf16  g_A1[2*NB*768];      // [2][1024][768]: h0_out | h1 ping-pong
__device__ bf16  g_enc[(size_t)NB*LSEQ*HID];   // 264 MB, [B][L][H]
__device__ bf16  g_Adec[2*NB*768];    // [2][1024][768]: din | h_dec
__device__ bf16  g_Adin[NB*416];      // [1024][416]: y | feat4 | ctx384 | pad
__device__ bf16  g_xb[NB*LSEQ*8];     // bf16 x
__device__ float g_c0[NB*HID];
__device__ float g_c1[NB*HID];
__device__ float g_cdec[NB*HID];
__device__ float g_u[NB*HID];
__device__ float g_bias0[1536], g_bias1[1536], g_biasd[1536], g_biasdin[384];
__device__ bf16  g_Bp0[12*13*4096];         // enc L0 pack (32-col jb granularity)
__device__ bf16  g_Bp1n[24*24*4*64*8];      // enc L1 pack (16-col jn granularity)
__device__ bf16  g_Bpd[12*24*4096];
__device__ bf16  g_Bpi[3*13*4096];
__device__ bf16  g_Bpu[3*12*4096];

__device__ __forceinline__ float sigf(float x){ return 1.0f/(1.0f + __expf(-x)); }
__device__ __forceinline__ float tanh_f(float x){
  x = fminf(fmaxf(x, -15.f), 15.f);
  float e = __expf(2.f*x);
  return (e - 1.f)/(e + 1.f);
}

// ---------------- per-call state zeroing (replay determinism) ----------------
__global__ void zero_state_k(){
  int i = blockIdx.x*blockDim.x + threadIdx.x;
  int st = gridDim.x*blockDim.x;
  bf16 z = (bf16)0.f;
  for(int k=i;k<2*NB*HID;k+=st) g_A0[k]=z;
  for(int k=i;k<2*NB*768;k+=st) g_A1[k]=z;
  for(int k=i;k<NB*HID;k+=st){ g_c0[k]=0.f; g_c1[k]=0.f; g_cdec[k]=0.f; }
}

__global__ void pack_xb_k(const float* __restrict__ x){
  int i = blockIdx.x*256 + threadIdx.x;
  int n = NB*LSEQ*8;
  for(int k=i; k<n; k+=gridDim.x*256) g_xb[k] = (bf16)x[k];
}

// ---------------- weight packs ----------------
// gates pack: out[jb][ks][tt(8)][lane(64)][8], n = (tt>>1)*384 + jb*32 + (tt&1)*16 + (lane&15)
__global__ void pack_gates_k(int mode, const float* __restrict__ W1, const float* __restrict__ W2,
                             int nks){
  bf16* out = (mode==0)? g_Bp0 : g_Bpd;
  size_t idx = (size_t)blockIdx.x*256 + threadIdx.x;
  size_t total = (size_t)12*nks*512;
  if(idx >= total) return;
  int lane = (int)(idx & 63);
  int tt   = (int)((idx>>6) & 7);
  size_t tmp = idx >> 9;
  int ks = (int)(tmp % nks);
  int jb = (int)(tmp / nks);
  int n  = (tt>>1)*HID + jb*32 + (tt&1)*16 + (lane&15);
  int kb = ks*32 + (lane>>4)*8;
  bf16x8 v;
  #pragma unroll
  for(int i=0;i<8;i++){
    int k = kb + i;
    float f;
    if(mode==0) f = (k<384) ? W1[(size_t)n*384 + k] : (k<392 ? W2[(size_t)n*8 + (k-384)] : 0.f);
    else        f = (k<384) ? W1[(size_t)n*384 + k] : W2[(size_t)n*384 + (k-384)];
    v[i] = (bf16)f;
  }
  *(bf16x8*)(out + idx*8) = v;
}

// enc L1 pack: out[jn(24)][ks(24)][g(4)][lane(64)][8], n = g*384 + jn*16 + (lane&15)
__global__ void pack_gates16_k(const float* __restrict__ Wih1, const float* __restrict__ Whh1){
  int idx = blockIdx.x*256 + threadIdx.x;
  if(idx >= 24*24*4*64) return;
  int lane = idx&63, rem = idx>>6;
  int g = rem&3; rem >>= 2;
  int ks = rem%24, jn = rem/24;
  int n  = g*HID + jn*16 + (lane&15);
  int kb = ks*32 + (lane>>4)*8;
  bf16x8 v;
  #pragma unroll
  for(int i=0;i<8;i++){
    int k = kb+i;
    float f = (k<384)? Wih1[(size_t)n*384 + k] : Whh1[(size_t)n*384 + (k-384)];
    v[i] = (bf16)f;
  }
  *(bf16x8*)(g_Bp1n + (size_t)idx*8) = v;
}

// plain pack: out[nb][ks][tt(8)][lane][8], n = nb*128 + tt*16 + (lane&15)
__global__ void pack_plain_k(int mode, const float* __restrict__ W, int nks, int nb_cnt){
  bf16* out = mode ? g_Bpu : g_Bpi;
  size_t idx = (size_t)blockIdx.x*256 + threadIdx.x;
  size_t total = (size_t)nb_cnt*nks*512;
  if(idx>=total) return;
  int lane = (int)(idx&63);
  int tt   = (int)((idx>>6)&7);
  size_t tmp = idx>>9;
  int ks = (int)(tmp%nks);
  int nb = (int)(tmp/nks);
  int n  = nb*128 + tt*16 + (lane&15);
  int kb = ks*32 + (lane>>4)*8;
  bf16x8 v;
  #pragma unroll
  for(int i=0;i<8;i++){
    int k = kb+i;
    float f;
    if(mode==0) f = (k<389)? W[(size_t)n*389 + k] : 0.f;
    else        f = W[(size_t)k*384 + n];
    v[i]=(bf16)f;
  }
  *(bf16x8*)(out + idx*8) = v;
}

__global__ void prep_misc_k(const float* bih0,const float* bhh0,const float* bih1,const float* bhh1,
                            const float* dbih,const float* dbhh,const float* dinb){
  int i = blockIdx.x*256 + threadIdx.x;
  if(i<1536){ g_bias0[i]=bih0[i]+bhh0[i]; g_bias1[i]=bih1[i]+bhh1[i]; g_biasd[i]=dbih[i]+dbhh[i]; }
  if(i<384) g_biasdin[i]=dinb[i];
}

// ---------------- encoder window kernel (launch-per-window; kernel-boundary sync) ----------------
// window s: blocks 0..95  -> layer0 @ t=s   (skip if s==336). g=bid&7 (128 rows), jb=bid>>3 (32 cols).
//           blocks 96..191-> layer1 @ t=s-1 (skip if s==0).  m=idx&3 (256 rows), jn=idx>>2 (16 cols).
// B staged once to LDS (1 barrier); A read direct to MFMA fragments; gate epilogue fused with
// global f32 c-state; h stores transposed via LDS for coalesced 16B writes (1 barrier).
__global__ __launch_bounds__(256,1)
void enc_win_k(int s){
  extern __shared__ char lds[];
  const int bid = blockIdx.x, tid = threadIdx.x;
  const int lane = tid&63, wv = tid>>6;
  const int l15 = lane&15, lk = (lane>>4)*8;
  const int rs = s&1, ws = rs^1;

  if(bid < 96){
    if(s >= LSEQ) return;
    const int g = bid & 7, jb = bid >> 3;
    { const s16x8* src = (const s16x8*)(g_Bp0 + (size_t)jb*13*4096);
      s16x8* dst = (s16x8*)lds;
      #pragma unroll
      for(int h=0;h<26;h++) dst[tid + h*256] = src[tid + h*256];
    }
    bf16* tr = (bf16*)(lds + 13*8192);        // [128][32] bf16
    __syncthreads();
    const int jj0 = jb*32 + l15;
    float bia[2],bfa[2],bga[2],boa[2];
    #pragma unroll
    for(int jh=0;jh<2;jh++){
      bia[jh]=g_bias0[jj0+jh*16];     bfa[jh]=g_bias0[384+jj0+jh*16];
      bga[jh]=g_bias0[768+jj0+jh*16]; boa[jh]=g_bias0[1152+jj0+jh*16];
    }
    size_t hoff[2], xoff[2];
    #pragma unroll
    for(int mt=0;mt<2;mt++){
      int row = g*128 + wv*32 + mt*16 + l15;
      hoff[mt] = (size_t)row*HID + lk;
      xoff[mt] = (size_t)row*LSEQ*8;
    }
    const bf16* Ar = g_A0 + (size_t)rs*NB*HID;
    bf16x8 af[13][2];
    #pragma unroll
    for(int ks=0;ks<12;ks++)
      #pragma unroll
      for(int mt=0;mt<2;mt++)
        af[ks][mt] = *(const bf16x8*)(Ar + hoff[mt] + ks*32);
    #pragma unroll
    for(int mt=0;mt<2;mt++){
      bf16x8 z;
      #pragma unroll
      for(int e=0;e<8;e++) z[e]=(bf16)0.f;
      if(lk==0) z = *(const bf16x8*)(g_xb + xoff[mt] + (size_t)s*8);
      af[12][mt] = z;
    }
    f32x4 acc[2][8];
    #pragma unroll
    for(int m2=0;m2<2;m2++)
      #pragma unroll
      for(int tt=0;tt<8;tt++) acc[m2][tt] = (f32x4){0.f,0.f,0.f,0.f};
    #pragma unroll
    for(int ks=0;ks<13;ks++){
      #pragma unroll
      for(int tt=0;tt<8;tt++){
        bf16x8 bfr = *(const bf16x8*)(lds + (ks*8+tt)*1024 + lane*16);
        acc[0][tt] = __builtin_amdgcn_mfma_f32_16x16x32_bf16(af[ks][0], bfr, acc[0][tt],0,0,0);
        acc[1][tt] = __builtin_amdgcn_mfma_f32_16x16x32_bf16(af[ks][1], bfr, acc[1][tt],0,0,0);
      }
    }
    const int rw = g*128 + wv*32 + (lane>>4)*4;
    #pragma unroll
    for(int mt=0;mt<2;mt++)
      #pragma unroll
      for(int jh=0;jh<2;jh++)
        #pragma unroll
        for(int r=0;r<4;r++){
          float zi=acc[mt][0+jh][r]+bia[jh], zf=acc[mt][2+jh][r]+bfa[jh],
                zg=acc[mt][4+jh][r]+bga[jh], zo=acc[mt][6+jh][r]+boa[jh];
          size_t ci = (size_t)(rw + mt*16 + r)*HID + jj0 + jh*16;
          float cn = sigf(zf)*g_c0[ci] + sigf(zi)*tanh_f(zg);
          g_c0[ci] = cn;
          int lr = wv*32 + mt*16 + (lane>>4)*4 + r;
          tr[lr*32 + jh*16 + l15] = (bf16)(sigf(zo)*tanh_f(cn));
        }
    __syncthreads();
    bf16* A0n = g_A0 + (size_t)ws*NB*HID;
    bf16* A1n = g_A1 + (size_t)ws*NB*768;
    #pragma unroll
    for(int h=0;h<2;h++){
      int p = tid + h*256;
      int row = p>>2, cc = p&3;
      s16x8 v = *(const s16x8*)(tr + row*32 + cc*8);
      *(s16x8*)(A0n + (size_t)(g*128+row)*HID + jb*32 + cc*8) = v;
      *(s16x8*)(A1n + (size_t)(g*128+row)*768 + jb*32 + cc*8) = v;
    }
  } else {
    if(s < 1) return;
    const int idx = bid-96, m = idx & 3, jn = idx >> 2, t = s-1;
    { const s16x8* src = (const s16x8*)(g_Bp1n + (size_t)jn*24*2048);
      s16x8* dst = (s16x8*)lds;
      #pragma unroll
      for(int h=0;h<24;h++) dst[tid + h*256] = src[tid + h*256];
    }
    bf16* tr = (bf16*)(lds + 24*4096);        // [256][16] bf16
    __syncthreads();
    const int jj = jn*16 + l15;
    const float bi=g_bias1[jj], bff=g_bias1[384+jj], bg=g_bias1[768+jj], bo=g_bias1[1152+jj];
    size_t aoff[4];
    #pragma unroll
    for(int mt=0;mt<4;mt++) aoff[mt] = (size_t)(m*256 + wv*64 + mt*16 + l15)*768 + lk;
    const bf16* Ar = g_A1 + (size_t)rs*NB*768;  // [h0@t | h1@t-1]
    bf16x8 ap[4][4];
    #pragma unroll
    for(int d=0;d<4;d++)
      #pragma unroll
      for(int mt=0;mt<4;mt++) ap[d][mt] = *(const bf16x8*)(Ar + aoff[mt] + d*32);
    f32x4 acc[4][4];
    #pragma unroll
    for(int mt=0;mt<4;mt++)
      #pragma unroll
      for(int g4=0;g4<4;g4++) acc[mt][g4] = (f32x4){0.f,0.f,0.f,0.f};
    #pragma unroll
    for(int ks=0;ks<24;ks++){
      bf16x8 bfr[4];
      #pragma unroll
      for(int g4=0;g4<4;g4++) bfr[g4] = *(const bf16x8*)(lds + (ks*4+g4)*1024 + lane*16);
      bf16x8 a[4];
      #pragma unroll
      for(int mt=0;mt<4;mt++) a[mt] = ap[ks&3][mt];
      if(ks<20){
        #pragma unroll
        for(int mt=0;mt<4;mt++) ap[ks&3][mt] = *(const bf16x8*)(Ar + aoff[mt] + (ks+4)*32);
      }
      #pragma unroll
      for(int mt=0;mt<4;mt++)
        #pragma unroll
        for(int g4=0;g4<4;g4++)
          acc[mt][g4] = __builtin_amdgcn_mfma_f32_16x16x32_bf16(a[mt], bfr[g4], acc[mt][g4],0,0,0);
    }
    const int rw = m*256 + wv*64 + (lane>>4)*4;
    #pragma unroll
    for(int mt=0;mt<4;mt++)
      #pragma unroll
      for(int r=0;r<4;r++){
        float zi=acc[mt][0][r]+bi, zf=acc[mt][1][r]+bff,
              zg=acc[mt][2][r]+bg, zo=acc[mt][3][r]+bo;
        size_t ci = (size_t)(rw + mt*16 + r)*HID + jj;
        float cn = sigf(zf)*g_c1[ci] + sigf(zi)*tanh_f(zg);
        g_c1[ci] = cn;
        int lr = wv*64 + mt*16 + (lane>>4)*4 + r;
        tr[lr*16 + l15] = (bf16)(sigf(zo)*tanh_f(cn));
      }
    __syncthreads();
    bf16* A1n = g_A1 + (size_t)ws*NB*768;
    #pragma unroll
    for(int h=0;h<2;h++){
      int p = tid + h*256;
      int row = p>>1, hf2 = p&1;
      s16x8 v = *(const s16x8*)(tr + row*16 + hf2*8);
      int grow = m*256 + row;
      *(s16x8*)(A1n + (size_t)grow*768 + 384 + jn*16 + hf2*8) = v;
      *(s16x8*)(g_enc + ((size_t)grow*LSEQ + t)*HID + jn*16 + hf2*8) = v;
    }
  }
}

// ---------------- GEMM core (decoder) ----------------
struct SReg { s16x8 a0,a1,b0,b1; };

__device__ __forceinline__ void stage_load(const bf16* __restrict__ A, int ldA,
                                           const bf16* __restrict__ Bk, int tid, SReg& sr){
  int c0 = tid, c1 = tid+256;
  sr.a0 = *(const s16x8*)(A + (size_t)(c0>>2)*ldA + (c0&3)*8);
  sr.a1 = *(const s16x8*)(A + (size_t)(c1>>2)*ldA + (c1&3)*8);
  const s16x8* B8 = (const s16x8*)Bk;
  sr.b0 = B8[c0]; sr.b1 = B8[c1];
}

__device__ __forceinline__ void stage_write(char* Ab, char* Bb, int tid, const SReg& sr){
  int c0 = tid, c1 = tid+256;
  *(s16x8*)(Ab + (c0>>2)*80 + (c0&3)*16) = sr.a0;
  *(s16x8*)(Ab + (c1>>2)*80 + (c1&3)*16) = sr.a1;
  *(s16x8*)(Bb + c0*16) = sr.b0;
  *(s16x8*)(Bb + c1*16) = sr.b1;
}

__device__ __forceinline__ void gemm_core(const bf16* __restrict__ A, int ldA,
                                          const bf16* __restrict__ Bp, int nks,
                                          char* smem, f32x4 acc[4][4]){
  const int tid = threadIdx.x;
  const int lane = tid & 63, wv = tid>>6, wm = wv>>1, wn = wv&1;
  char* Ab0 = smem;            char* Ab1 = smem + 10240;
  char* Bb0 = smem + 20480;    char* Bb1 = smem + 28672;
  f32x4 z = {0.f,0.f,0.f,0.f};
  #pragma unroll
  for(int m=0;m<4;m++)
    #pragma unroll
    for(int g=0;g<4;g++) acc[m][g]=z;
  SReg sr;
  stage_load(A, ldA, Bp, tid, sr);
  stage_write(Ab0, Bb0, tid, sr);
  const int aoff = (wm*64 + (lane&15))*80 + (lane>>4)*16;
  const int boff = wn*1024 + lane*16;
  for(int ks=0; ks<nks; ks++){
    char* Ac = (ks&1)? Ab1: Ab0;
    char* Bc = (ks&1)? Bb1: Bb0;
    char* An = (ks&1)? Ab0: Ab1;
    char* Bn = (ks&1)? Bb0: Bb1;
    bool more = (ks+1)<nks;
    if(more) stage_load(A + (ks+1)*32, ldA, Bp + (size_t)(ks+1)*4096, tid, sr);
    __syncthreads();
    bf16x8 af[4], bfr[4];
    #pragma unroll
    for(int mt=0;mt<4;mt++) af[mt] = *(const bf16x8*)(Ac + aoff + mt*16*80);
    #pragma unroll
    for(int g=0;g<4;g++)    bfr[g] = *(const bf16x8*)(Bc + boff + g*2048);
    #pragma unroll
    for(int mt=0;mt<4;mt++)
      #pragma unroll
      for(int g=0;g<4;g++)
        acc[mt][g] = __builtin_amdgcn_mfma_f32_16x16x32_bf16(af[mt], bfr[g], acc[mt][g], 0,0,0);
    if(more) stage_write(An, Bn, tid, sr);
  }
}

// ---------------- LSTM epilogue (decoder) ----------------
__device__ __forceinline__ void lstm_epi(f32x4 acc[4][4], int mbase, int jb,
     const float* __restrict__ bias, float* __restrict__ cst,
     bf16* __restrict__ d0, int ld0, bf16* __restrict__ d1, size_t ld1){
  int lane = threadIdx.x&63, wv = threadIdx.x>>6, wm = wv>>1, wn = wv&1;
  int j = jb*32 + wn*16 + (lane&15);
  float bi = bias[j], bff = bias[384+j], bg = bias[768+j], bo = bias[1152+j];
  #pragma unroll
  for(int mt=0;mt<4;mt++){
    #pragma unroll
    for(int r=0;r<4;r++){
      int brow = mbase + wm*64 + mt*16 + (lane>>4)*4 + r;
      float zi = acc[mt][0][r]+bi, zf = acc[mt][1][r]+bff,
            zg = acc[mt][2][r]+bg, zo = acc[mt][3][r]+bo;
      size_t ci = (size_t)brow*HID + j;
      float cold = cst[ci];
      float cn = sigf(zf)*cold + sigf(zi)*tanh_f(zg);
      cst[ci] = cn;
      bf16 hb = (bf16)(sigf(zo)*tanh_f(cn));
      d0[(size_t)brow*ld0 + j] = hb;
      if(d1) d1[(size_t)brow*ld1 + j] = hb;
    }
  }
}

// ---------------- decoder LSTM ----------------
__global__ __launch_bounds__(256)
void dec_lstm_k(int t){
  __shared__ char smem[SMEM_BYTES];
  int bid = blockIdx.x, mb = bid/12, jb = bid%12;
  int rs = t&1, wsl = rs^1;
  f32x4 acc[4][4];
  gemm_core(g_Adec + (size_t)rs*NB*768 + (size_t)mb*128*768, 768,
            g_Bpd + (size_t)jb*24*4096, 24, smem, acc);
  lstm_epi(acc, mb*128, jb, g_biasd, g_cdec,
           g_Adec + (size_t)wsl*NB*768 + 384, 768, (bf16*)nullptr, 0);
}

// ---------------- plain GEMM: mode 1 = u-proj (h@Wa -> g_u f32), mode 0 = dec_in relu ----------------
__global__ __launch_bounds__(256)
void plain_gemm_k(int t, int mode){
  __shared__ char smem[SMEM_BYTES];
  int bid = blockIdx.x, mb = bid/3, nb = bid%3;
  int rs = t&1;
  const bf16* A; int ldA, nks; const bf16* Bp;
  if(mode==1){ A = g_Adec + (size_t)rs*NB*768 + 384; ldA=768; Bp = g_Bpu; nks=12; }
  else       { A = g_Adin;                           ldA=416; Bp = g_Bpi; nks=13; }
  f32x4 acc[4][4];
  gemm_core(A + (size_t)mb*128*ldA, ldA, Bp + (size_t)nb*nks*4096, nks, smem, acc);
  int lane = threadIdx.x&63, wv = threadIdx.x>>6, wm = wv>>1, wn = wv&1;
  bf16* dbf = g_Adec + (size_t)rs*NB*768;
  #pragma unroll
  for(int mt=0;mt<4;mt++){
    #pragma unroll
    for(int ti=0;ti<4;ti++){
      int n = nb*128 + (ti*2+wn)*16 + (lane&15);
      #pragma unroll
      for(int r=0;r<4;r++){
        int brow = mb*128 + wm*64 + mt*16 + (lane>>4)*4 + r;
        float v = acc[mt][ti][r];
        if(mode==0){ v += g_biasdin[n]; v = fmaxf(v,0.f); dbf[(size_t)brow*768 + n] = (bf16)v; }
        else g_u[(size_t)brow*384 + n] = v;
      }
    }
  }
}

// ---------------- attention: fused scores+softmax+ctx (online) ----------------
__global__ __launch_bounds__(256)
void attn_k(){
  __shared__ float sm[4][392];
  int tid = threadIdx.x, lane = tid&63, w = tid>>6;
  int bl = w>>1, hf = w&1;
  int b = blockIdx.x*2 + bl;
  const float* ub = g_u + (size_t)b*HID + lane*6;
  float u0=ub[0],u1=ub[1],u2=ub[2],u3=ub[3],u4=ub[4],u5=ub[5];
  const u32* er = (const u32*)(g_enc + (size_t)b*LSEQ*HID) + (size_t)hf*168*192 + lane*3;
  float m=-1e30f, den=0.f, a0=0,a1=0,a2=0,a3=0,a4=0,a5=0;
  for(int l=0;l<168;l++){
    u32 w0 = er[0], w1 = er[1], w2 = er[2];
    er += 192;
    float e0 = __uint_as_float(w0<<16);
    float e1 = __uint_as_float(w0 & 0xffff0000u);
    float e2 = __uint_as_float(w1<<16);
    float e3 = __uint_as_float(w1 & 0xffff0000u);
    float e4 = __uint_as_float(w2<<16);
    float e5 = __uint_as_float(w2 & 0xffff0000u);
    float p = e0*u0 + e1*u1 + e2*u2 + e3*u3 + e4*u4 + e5*u5;
    #pragma unroll
    for(int o=1;o<64;o<<=1) p += __shfl_xor(p, o, 64);
    float mn = fmaxf(m, p);
    float al = __expf(m - mn), pe = __expf(p - mn);
    den = den*al + pe;
    a0 = a0*al + pe*e0; a1 = a1*al + pe*e1; a2 = a2*al + pe*e2;
    a3 = a3*al + pe*e3; a4 = a4*al + pe*e4; a5 = a5*al + pe*e5;
    m = mn;
  }
  if(lane==0){ sm[w][0]=m; sm[w][1]=den; }
  sm[w][2+lane*6+0]=a0; sm[w][2+lane*6+1]=a1; sm[w][2+lane*6+2]=a2;
  sm[w][2+lane*6+3]=a3; sm[w][2+lane*6+4]=a4; sm[w][2+lane*6+5]=a5;
  __syncthreads();
  if(hf==0){
    float m2 = sm[w+1][0], d2 = sm[w+1][1];
    float M = fmaxf(m, m2);
    float f1 = __expf(m - M), f2 = __expf(m2 - M);
    float inv = 1.f/(den*f1 + d2*f2);
    bf16* cd = g_Adin + (size_t)b*416 + 5 + lane*6;
    cd[0] = (bf16)((a0*f1 + sm[w+1][2+lane*6+0]*f2)*inv);
    cd[1] = (bf16)((a1*f1 + sm[w+1][2+lane*6+1]*f2)*inv);
    cd[2] = (bf16)((a2*f1 + sm[w+1][2+lane*6+2]*f2)*inv);
    cd[3] = (bf16)((a3*f1 + sm[w+1][2+lane*6+3]*f2)*inv);
    cd[4] = (bf16)((a4*f1 + sm[w+1][2+lane*6+4]*f2)*inv);
    cd[5] = (bf16)((a5*f1 + sm[w+1][2+lane*6+5]*f2)*inv);
  }
}

// ---------------- output head + next-step A_din fill ----------------
__global__ void post_k(int t, const float* __restrict__ outW,
                       const float* __restrict__ outb, float* __restrict__ out,
                       const float* __restrict__ ff){
  int b = blockIdx.x*256 + threadIdx.x;
  if(b>=NB) return;
  int wsl = (t&1)^1;
  const s16x8* hp = (const s16x8*)(g_Adec + (size_t)wsl*NB*768 + (size_t)b*768 + 384);
  float acc = 0.f;
  #pragma unroll 4
  for(int i=0;i<48;i++){
    s16x8 v = hp[i];
    #pragma unroll
    for(int e=0;e<8;e++){
      float hv = __uint_as_float(((u32)(uint16_t)v[e])<<16);
      acc += hv*outW[i*8+e];
    }
  }
  float y = acc + outb[0];
  out[(size_t)b*HOR + t] = y;
  g_Adin[(size_t)b*416] = (bf16)y;
  if(t+1<HOR){
    #pragma unroll
    for(int k=0;k<4;k++) g_Adin[(size_t)b*416 + 1 + k] = (bf16)ff[(size_t)b*HOR*4 + (t+1)*4 + k];
  }
}

// ---------------- decoder init ----------------
__global__ void dec_prep_k(const float* __restrict__ ff){
  int i = blockIdx.x*256 + threadIdx.x;
  if(i < NB*HID){
    int b = i/HID, j = i%HID;
    g_Adec[(size_t)b*768 + 384 + j] = g_enc[(size_t)b*LSEQ*HID + (size_t)(LSEQ-1)*HID + j];
  }
  if(i < NB*4){
    int b = i>>2, k = i&3;
    g_Adin[(size_t)b*416 + 1 + k] = (bf16)ff[(size_t)b*HOR*4 + k];
  }
  if(i < NB) g_Adin[(size_t)i*416] = (bf16)0.f;
}

extern "C" void kernel_launch(void* const* d_in, const int* in_sizes, int n_in,
                              void* d_out, int out_size, void* d_ws, size_t ws_size,
                              hipStream_t stream){
  const float* x    = (const float*)d_in[0];
  const float* ff   = (const float*)d_in[1];
  const float* Wih0 = (const float*)d_in[2];
  const float* Whh0 = (const float*)d_in[3];
  const float* bih0 = (const float*)d_in[4];
  const float* bhh0 = (const float*)d_in[5];
  const float* Wih1 = (const float*)d_in[6];
  const float* Whh1 = (const float*)d_in[7];
  const float* bih1 = (const float*)d_in[8];
  const float* bhh1 = (const float*)d_in[9];
  const float* Wa   = (const float*)d_in[10];
  const float* dinW = (const float*)d_in[11];
  const float* dinb = (const float*)d_in[12];
  const float* dWih = (const float*)d_in[13];
  const float* dWhh = (const float*)d_in[14];
  const float* dbih = (const float*)d_in[15];
  const float* dbhh = (const float*)d_in[16];
  const float* outW = (const float*)d_in[17];
  const float* outb = (const float*)d_in[18];
  float* out = (float*)d_out;

  zero_state_k<<<1024,256,0,stream>>>();
  pack_xb_k<<<2048,256,0,stream>>>(x);
  pack_gates_k<<<(12*13*512)/256,256,0,stream>>>(0, Whh0, Wih0, 13);
  pack_gates16_k<<<576,256,0,stream>>>(Wih1, Whh1);
  pack_gates_k<<<(12*24*512)/256,256,0,stream>>>(2, dWih, dWhh, 24);
  pack_plain_k<<<(3*13*512)/256,256,0,stream>>>(0, dinW, 13, 3);
  pack_plain_k<<<(3*12*512)/256,256,0,stream>>>(1, Wa, 12, 3);
  prep_misc_k<<<8,256,0,stream>>>(bih0,bhh0,bih1,bhh1,dbih,dbhh,dinb);

  hipFuncSetAttribute((const void*)enc_win_k,
                      hipFuncAttributeMaxDynamicSharedMemorySize, 114688);
  for(int s=0;s<=LSEQ;s++)
    enc_win_k<<<192,256,114688,stream>>>(s);

  dec_prep_k<<<1536,256,0,stream>>>(ff);
  for(int t=0;t<HOR;t++){
    plain_gemm_k<<<24,256,0,stream>>>(t, 1);
    attn_k<<<512,256,0,stream>>>();
    plain_gemm_k<<<24,256,0,stream>>>(t, 0);
    dec_lstm_k<<<96,256,0,stream>>>(t);
    post_k<<<4,256,0,stream>>>(t, outW, outb, out, ff);
  }
  (void)in_sizes; (void)n_in; (void)out_size; (void)d_ws; (void)ws_size;
}

// Round 9
// 8752.505 us; speedup vs baseline: 1.4800x; 1.2687x over previous
//
#include <hip/hip_runtime.h>
#include <stdint.h>

typedef __bf16 bf16;
typedef __bf16 bf16x8 __attribute__((ext_vector_type(8)));
typedef short  s16x8  __attribute__((ext_vector_type(8)));
typedef float  f32x4  __attribute__((ext_vector_type(4)));
typedef uint32_t u32;

#define NB   1024
#define LSEQ 336
#define HID  384
#define HOR  18
#define SMEM_BYTES 36864

// ---------------- device-global scratch ----------------
__device__ bf16  g_H0[(size_t)(LSEQ+1)*NB*HID];  // 265 MB: h0 chain; slot w+1 = h0[t=w]; slot0 zeroed
__device__ bf16  g_enc[(size_t)NB*LSEQ*HID];     // 264 MB, [B][L][H]; doubles as h1 chain
__device__ bf16  g_zero[HID];                    // never written: zeros (s==1 h1 reads)
__device__ bf16  g_Adec[2*NB*768];    // [2][1024][768]: din | h_dec
__device__ bf16  g_Adin[NB*416];      // [1024][416]: y | feat4 | ctx384 | pad
__device__ bf16  g_xb[NB*LSEQ*8];     // bf16 x
__device__ float g_c0[NB*HID];
__device__ float g_c1[NB*HID];
__device__ float g_cdec[NB*HID];
__device__ float g_u[NB*HID];
__device__ float g_bias0[1536], g_bias1[1536], g_biasd[1536], g_biasdin[384];
__device__ bf16  g_Bp0[12*13*4096];         // enc L0 pack (32-col jb granularity)
__device__ bf16  g_Bp1n[24*24*4*64*8];      // enc L1 pack (16-col jn granularity)
__device__ bf16  g_Bpd[12*24*4096];
__device__ bf16  g_Bpi[3*13*4096];
__device__ bf16  g_Bpu[3*12*4096];
__device__ int   g_f0[8*LSEQ];        // [g][w]: L0 group g finished window w (target 12)
__device__ int   g_f1[4*(LSEQ+1)];    // [m][s]: L1 group m finished step s (target 24)

__device__ __forceinline__ float sigf(float x){ return 1.0f/(1.0f + __expf(-x)); }
__device__ __forceinline__ float tanh_f(float x){
  x = fminf(fmaxf(x, -15.f), 15.f);
  float e = __expf(2.f*x);
  return (e - 1.f)/(e + 1.f);
}

// Device-scope 16B store as 2x u64 relaxed atomics: completes AT the MALL (R5-proven
// visibility). vmcnt-drained by __syncthreads before the flag bump.
__device__ __forceinline__ void ds16(bf16* p, s16x8 v){
  union{ s16x8 v; uint64_t q[2]; } u; u.v = v;
  __hip_atomic_store((uint64_t*)p,     u.q[0], __ATOMIC_RELAXED, __HIP_MEMORY_SCOPE_AGENT);
  __hip_atomic_store((uint64_t*)p + 1, u.q[1], __ATOMIC_RELAXED, __HIP_MEMORY_SCOPE_AGENT);
}

// ---------------- per-call state zeroing (replay determinism) ----------------
__global__ void zero_state_k(){
  int i = blockIdx.x*blockDim.x + threadIdx.x;
  int st = gridDim.x*blockDim.x;
  bf16 z = (bf16)0.f;
  for(int k=i;k<NB*HID;k+=st){ g_H0[k]=z; g_c0[k]=0.f; g_c1[k]=0.f; g_cdec[k]=0.f; }
  for(int k=i;k<8*LSEQ;k+=st) g_f0[k]=0;
  for(int k=i;k<4*(LSEQ+1);k+=st) g_f1[k]=0;
}

__global__ void pack_xb_k(const float* __restrict__ x){
  int i = blockIdx.x*256 + threadIdx.x;
  int n = NB*LSEQ*8;
  for(int k=i; k<n; k+=gridDim.x*256) g_xb[k] = (bf16)x[k];
}

// ---------------- weight packs ----------------
// gates pack: out[jb][ks][tt(8)][lane(64)][8], n = (tt>>1)*384 + jb*32 + (tt&1)*16 + (lane&15)
__global__ void pack_gates_k(int mode, const float* __restrict__ W1, const float* __restrict__ W2,
                             int nks){
  bf16* out = (mode==0)? g_Bp0 : g_Bpd;
  size_t idx = (size_t)blockIdx.x*256 + threadIdx.x;
  size_t total = (size_t)12*nks*512;
  if(idx >= total) return;
  int lane = (int)(idx & 63);
  int tt   = (int)((idx>>6) & 7);
  size_t tmp = idx >> 9;
  int ks = (int)(tmp % nks);
  int jb = (int)(tmp / nks);
  int n  = (tt>>1)*HID + jb*32 + (tt&1)*16 + (lane&15);
  int kb = ks*32 + (lane>>4)*8;
  bf16x8 v;
  #pragma unroll
  for(int i=0;i<8;i++){
    int k = kb + i;
    float f;
    if(mode==0) f = (k<384) ? W1[(size_t)n*384 + k] : (k<392 ? W2[(size_t)n*8 + (k-384)] : 0.f);
    else        f = (k<384) ? W1[(size_t)n*384 + k] : W2[(size_t)n*384 + (k-384)];
    v[i] = (bf16)f;
  }
  *(bf16x8*)(out + idx*8) = v;
}

// enc L1 pack: out[jn(24)][ks(24)][g(4)][lane(64)][8], n = g*384 + jn*16 + (lane&15)
__global__ void pack_gates16_k(const float* __restrict__ Wih1, const float* __restrict__ Whh1){
  int idx = blockIdx.x*256 + threadIdx.x;
  if(idx >= 24*24*4*64) return;
  int lane = idx&63, rem = idx>>6;
  int g = rem&3; rem >>= 2;
  int ks = rem%24, jn = rem/24;
  int n  = g*HID + jn*16 + (lane&15);
  int kb = ks*32 + (lane>>4)*8;
  bf16x8 v;
  #pragma unroll
  for(int i=0;i<8;i++){
    int k = kb+i;
    float f = (k<384)? Wih1[(size_t)n*384 + k] : Whh1[(size_t)n*384 + (k-384)];
    v[i] = (bf16)f;
  }
  *(bf16x8*)(g_Bp1n + (size_t)idx*8) = v;
}

// plain pack: out[nb][ks][tt(8)][lane][8], n = nb*128 + tt*16 + (lane&15)
__global__ void pack_plain_k(int mode, const float* __restrict__ W, int nks, int nb_cnt){
  bf16* out = mode ? g_Bpu : g_Bpi;
  size_t idx = (size_t)blockIdx.x*256 + threadIdx.x;
  size_t total = (size_t)nb_cnt*nks*512;
  if(idx>=total) return;
  int lane = (int)(idx&63);
  int tt   = (int)((idx>>6)&7);
  size_t tmp = idx>>9;
  int ks = (int)(tmp%nks);
  int nb = (int)(tmp/nks);
  int n  = nb*128 + tt*16 + (lane&15);
  int kb = ks*32 + (lane>>4)*8;
  bf16x8 v;
  #pragma unroll
  for(int i=0;i<8;i++){
    int k = kb+i;
    float f;
    if(mode==0) f = (k<389)? W[(size_t)n*389 + k] : 0.f;
    else        f = W[(size_t)k*384 + n];
    v[i]=(bf16)f;
  }
  *(bf16x8*)(out + idx*8) = v;
}

__global__ void prep_misc_k(const float* bih0,const float* bhh0,const float* bih1,const float* bhh1,
                            const float* dbih,const float* dbhh,const float* dinb){
  int i = blockIdx.x*256 + threadIdx.x;
  if(i<1536){ g_bias0[i]=bih0[i]+bhh0[i]; g_bias1[i]=bih1[i]+bhh1[i]; g_biasd[i]=dbih[i]+dbhh[i]; }
  if(i<384) g_biasdin[i]=dinb[i];
}

// ---------------- dataflow spin (relaxed agent atomics on flags only) ----------------
__device__ __forceinline__ void spin_ge(int* p, int tgt){
  while(__hip_atomic_load(p, __ATOMIC_RELAXED, __HIP_MEMORY_SCOPE_AGENT) < tgt)
    __builtin_amdgcn_s_sleep(1);
}

// ---------------- persistent 2-layer encoder: fresh-slot chains + atomic producers,
// cached consumers.
// L0: bid<96: g=bid&7 (128 rows; all 12 jb siblings land on XCD g), jb=bid>>3 (32 cols).
//     Reads g_H0[w] (plain, L2-shared among siblings), writes g_H0[w+1] (ds16 atomics).
// L1: bid>=96: idx=bid-96, m=idx&3 (256 rows), jn=idx>>2 (16 cols).
//     Reads g_H0[s] + g_enc[t-1] (plain), writes g_enc[t] (ds16 atomics).
// Fresh addresses => consumer demand-miss pulls MALL-correct data into L2, shared by
// siblings; no fences, no invalidates, flags relaxed-agent only.
__global__ __launch_bounds__(256,1)
void enc6_k(){
  extern __shared__ char lds[];
  const int bid = blockIdx.x, tid = threadIdx.x;
  const int lane = tid&63, wv = tid>>6;
  const int l15 = lane&15, lk = (lane>>4)*8;

  if(bid < 96){
    const int g = bid & 7, jb = bid >> 3;
    { const s16x8* src = (const s16x8*)(g_Bp0 + (size_t)jb*13*4096);
      s16x8* dst = (s16x8*)lds;
      #pragma unroll
      for(int h=0;h<26;h++) dst[tid + h*256] = src[tid + h*256];
    }
    bf16* tr = (bf16*)(lds + 13*8192);        // [128][32] bf16
    __syncthreads();
    const int jj0 = jb*32 + l15;
    float bia[2],bfa[2],bga[2],boa[2];
    #pragma unroll
    for(int jh=0;jh<2;jh++){
      bia[jh]=g_bias0[jj0+jh*16];     bfa[jh]=g_bias0[384+jj0+jh*16];
      bga[jh]=g_bias0[768+jj0+jh*16]; boa[jh]=g_bias0[1152+jj0+jh*16];
    }
    size_t hoff[2], xoff[2];
    #pragma unroll
    for(int mt=0;mt<2;mt++){
      int row = g*128 + wv*32 + mt*16 + l15;
      hoff[mt] = (size_t)row*HID + lk;
      xoff[mt] = (size_t)row*LSEQ*8;
    }
    float c[2][2][4] = {};
    for(int w=0; w<LSEQ; w++){
      if(tid==0 && w>=1) spin_ge(&g_f0[g*LSEQ + (w-1)], 12);
      __syncthreads();
      asm volatile("" ::: "memory");
      const bf16* H0w = g_H0 + (size_t)w*NB*HID;
      bf16x8 af[13][2];
      #pragma unroll
      for(int ks=0;ks<12;ks++)
        #pragma unroll
        for(int mt=0;mt<2;mt++)
          af[ks][mt] = *(const bf16x8*)(H0w + hoff[mt] + ks*32);
      #pragma unroll
      for(int mt=0;mt<2;mt++){
        bf16x8 z;
        #pragma unroll
        for(int e=0;e<8;e++) z[e]=(bf16)0.f;
        if(lk==0) z = *(const bf16x8*)(g_xb + xoff[mt] + (size_t)w*8);
        af[12][mt] = z;
      }
      f32x4 acc[2][8];
      #pragma unroll
      for(int m2=0;m2<2;m2++)
        #pragma unroll
        for(int tt=0;tt<8;tt++) acc[m2][tt] = (f32x4){0.f,0.f,0.f,0.f};
      #pragma unroll
      for(int ks=0;ks<13;ks++){
        #pragma unroll
        for(int tt=0;tt<8;tt++){
          bf16x8 bfr = *(const bf16x8*)(lds + (ks*8+tt)*1024 + lane*16);
          acc[0][tt] = __builtin_amdgcn_mfma_f32_16x16x32_bf16(af[ks][0], bfr, acc[0][tt],0,0,0);
          acc[1][tt] = __builtin_amdgcn_mfma_f32_16x16x32_bf16(af[ks][1], bfr, acc[1][tt],0,0,0);
        }
      }
      #pragma unroll
      for(int mt=0;mt<2;mt++)
        #pragma unroll
        for(int jh=0;jh<2;jh++)
          #pragma unroll
          for(int r=0;r<4;r++){
            float zi=acc[mt][0+jh][r]+bia[jh], zf=acc[mt][2+jh][r]+bfa[jh],
                  zg=acc[mt][4+jh][r]+bga[jh], zo=acc[mt][6+jh][r]+boa[jh];
            size_t ci = (size_t)(g*128 + wv*32 + mt*16 + (lane>>4)*4 + r)*HID + jj0 + jh*16;
            float cn = sigf(zf)*g_c0[ci] + sigf(zi)*tanh_f(zg);
            g_c0[ci] = cn;
            int lr = wv*32 + mt*16 + (lane>>4)*4 + r;
            tr[lr*32 + jh*16 + l15] = (bf16)(sigf(zo)*tanh_f(cn));
          }
      __syncthreads();
      bf16* H0n = g_H0 + (size_t)(w+1)*NB*HID;
      #pragma unroll
      for(int h=0;h<2;h++){
        int p = tid + h*256;
        int row = p>>2, cc = p&3;
        s16x8 v = *(const s16x8*)(tr + row*32 + cc*8);
        ds16(H0n + (size_t)(g*128+row)*HID + jb*32 + cc*8, v);
      }
      __syncthreads();   // drains vmcnt: atomic stores are at MALL before flag
      if(tid==0)
        __hip_atomic_fetch_add(&g_f0[g*LSEQ + w], 1, __ATOMIC_RELAXED, __HIP_MEMORY_SCOPE_AGENT);
    }
  } else {
    const int idx = bid-96, m = idx & 3, jn = idx >> 2;
    { const s16x8* src = (const s16x8*)(g_Bp1n + (size_t)jn*24*2048);
      s16x8* dst = (s16x8*)lds;
      #pragma unroll
      for(int h=0;h<24;h++) dst[tid + h*256] = src[tid + h*256];
    }
    bf16* tr = (bf16*)(lds + 24*4096);        // [256][16] bf16
    __syncthreads();
    const int jj = jn*16 + l15;
    const float bi=g_bias1[jj], bff=g_bias1[384+jj], bg=g_bias1[768+jj], bo=g_bias1[1152+jj];
    int rows[4]; size_t hoff[4];
    #pragma unroll
    for(int mt=0;mt<4;mt++){
      rows[mt] = m*256 + wv*64 + mt*16 + l15;
      hoff[mt] = (size_t)rows[mt]*HID + lk;
    }
    float c[4][4] = {};
    for(int s=1; s<=LSEQ; s++){
      if(tid==0){
        spin_ge(&g_f0[(2*m)*LSEQ + (s-1)], 12);
        spin_ge(&g_f0[(2*m+1)*LSEQ + (s-1)], 12);
        if(s>=2) spin_ge(&g_f1[m*(LSEQ+1) + (s-1)], 24);
      }
      __syncthreads();
      asm volatile("" ::: "memory");
      const bf16* H0s = g_H0 + (size_t)s*NB*HID;          // h0[t=s-1]
      const size_t strideE = (s>=2)? (size_t)LSEQ*HID : 0;
      const bf16* Es = (s>=2)? (g_enc + (size_t)(s-2)*HID) : g_zero;  // h1[t=s-2]
      size_t eoff[4];
      #pragma unroll
      for(int mt=0;mt<4;mt++) eoff[mt] = (size_t)rows[mt]*strideE + lk;
      bf16x8 ap[8][4];
      #pragma unroll
      for(int d=0; d<8; d++)
        #pragma unroll
        for(int mt=0;mt<4;mt++)
          ap[d][mt] = *(const bf16x8*)(H0s + hoff[mt] + d*32);
      f32x4 acc[4][4];
      #pragma unroll
      for(int mt=0;mt<4;mt++)
        #pragma unroll
        for(int g4=0;g4<4;g4++) acc[mt][g4] = (f32x4){0.f,0.f,0.f,0.f};
      #pragma unroll
      for(int ks=0;ks<24;ks++){
        bf16x8 bfr[4];
        #pragma unroll
        for(int g4=0;g4<4;g4++) bfr[g4] = *(const bf16x8*)(lds + (ks*4+g4)*1024 + lane*16);
        bf16x8 a[4];
        #pragma unroll
        for(int mt=0;mt<4;mt++) a[mt] = ap[ks&7][mt];
        int kn = ks+8;
        if(kn<24){
          if(kn<12){
            #pragma unroll
            for(int mt=0;mt<4;mt++) ap[ks&7][mt] = *(const bf16x8*)(H0s + hoff[mt] + kn*32);
          } else {
            #pragma unroll
            for(int mt=0;mt<4;mt++) ap[ks&7][mt] = *(const bf16x8*)(Es + eoff[mt] + (kn-12)*32);
          }
        }
        #pragma unroll
        for(int mt=0;mt<4;mt++)
          #pragma unroll
          for(int g4=0;g4<4;g4++)
            acc[mt][g4] = __builtin_amdgcn_mfma_f32_16x16x32_bf16(a[mt], bfr[g4], acc[mt][g4],0,0,0);
      }
      #pragma unroll
      for(int mt=0;mt<4;mt++)
        #pragma unroll
        for(int r=0;r<4;r++){
          float zi=acc[mt][0][r]+bi, zf=acc[mt][1][r]+bff,
                zg=acc[mt][2][r]+bg, zo=acc[mt][3][r]+bo;
          size_t ci = (size_t)(m*256 + wv*64 + mt*16 + (lane>>4)*4 + r)*HID + jj;
          float cn = sigf(zf)*g_c1[ci] + sigf(zi)*tanh_f(zg);
          g_c1[ci] = cn;
          int lr = wv*64 + mt*16 + (lane>>4)*4 + r;
          tr[lr*16 + l15] = (bf16)(sigf(zo)*tanh_f(cn));
        }
      __syncthreads();
      const int t = s-1;
      #pragma unroll
      for(int h=0;h<2;h++){
        int p = tid + h*256;
        int row = p>>1, hf2 = p&1;
        s16x8 v = *(const s16x8*)(tr + row*16 + hf2*8);
        ds16(g_enc + ((size_t)(m*256+row)*LSEQ + t)*HID + jn*16 + hf2*8, v);
      }
      __syncthreads();   // drains vmcnt before flag
      if(tid==0)
        __hip_atomic_fetch_add(&g_f1[m*(LSEQ+1) + s], 1, __ATOMIC_RELAXED, __HIP_MEMORY_SCOPE_AGENT);
    }
  }
}

// ---------------- GEMM core (decoder) ----------------
struct SReg { s16x8 a0,a1,b0,b1; };

__device__ __forceinline__ void stage_load(const bf16* __restrict__ A, int ldA,
                                           const bf16* __restrict__ Bk, int tid, SReg& sr){
  int c0 = tid, c1 = tid+256;
  sr.a0 = *(const s16x8*)(A + (size_t)(c0>>2)*ldA + (c0&3)*8);
  sr.a1 = *(const s16x8*)(A + (size_t)(c1>>2)*ldA + (c1&3)*8);
  const s16x8* B8 = (const s16x8*)Bk;
  sr.b0 = B8[c0]; sr.b1 = B8[c1];
}

__device__ __forceinline__ void stage_write(char* Ab, char* Bb, int tid, const SReg& sr){
  int c0 = tid, c1 = tid+256;
  *(s16x8*)(Ab + (c0>>2)*80 + (c0&3)*16) = sr.a0;
  *(s16x8*)(Ab + (c1>>2)*80 + (c1&3)*16) = sr.a1;
  *(s16x8*)(Bb + c0*16) = sr.b0;
  *(s16x8*)(Bb + c1*16) = sr.b1;
}

__device__ __forceinline__ void gemm_core(const bf16* __restrict__ A, int ldA,
                                          const bf16* __restrict__ Bp, int nks,
                                          char* smem, f32x4 acc[4][4]){
  const int tid = threadIdx.x;
  const int lane = tid & 63, wv = tid>>6, wm = wv>>1, wn = wv&1;
  char* Ab0 = smem;            char* Ab1 = smem + 10240;
  char* Bb0 = smem + 20480;    char* Bb1 = smem + 28672;
  f32x4 z = {0.f,0.f,0.f,0.f};
  #pragma unroll
  for(int m=0;m<4;m++)
    #pragma unroll
    for(int g=0;g<4;g++) acc[m][g]=z;
  SReg sr;
  stage_load(A, ldA, Bp, tid, sr);
  stage_write(Ab0, Bb0, tid, sr);
  const int aoff = (wm*64 + (lane&15))*80 + (lane>>4)*16;
  const int boff = wn*1024 + lane*16;
  for(int ks=0; ks<nks; ks++){
    char* Ac = (ks&1)? Ab1: Ab0;
    char* Bc = (ks&1)? Bb1: Bb0;
    char* An = (ks&1)? Ab0: Ab1;
    char* Bn = (ks&1)? Bb0: Bb1;
    bool more = (ks+1)<nks;
    if(more) stage_load(A + (ks+1)*32, ldA, Bp + (size_t)(ks+1)*4096, tid, sr);
    __syncthreads();
    bf16x8 af[4], bfr[4];
    #pragma unroll
    for(int mt=0;mt<4;mt++) af[mt] = *(const bf16x8*)(Ac + aoff + mt*16*80);
    #pragma unroll
    for(int g=0;g<4;g++)    bfr[g] = *(const bf16x8*)(Bc + boff + g*2048);
    #pragma unroll
    for(int mt=0;mt<4;mt++)
      #pragma unroll
      for(int g=0;g<4;g++)
        acc[mt][g] = __builtin_amdgcn_mfma_f32_16x16x32_bf16(af[mt], bfr[g], acc[mt][g], 0,0,0);
    if(more) stage_write(An, Bn, tid, sr);
  }
}

// ---------------- LSTM epilogue (decoder) ----------------
__device__ __forceinline__ void lstm_epi(f32x4 acc[4][4], int mbase, int jb,
     const float* __restrict__ bias, float* __restrict__ cst,
     bf16* __restrict__ d0, int ld0, bf16* __restrict__ d1, size_t ld1){
  int lane = threadIdx.x&63, wv = threadIdx.x>>6, wm = wv>>1, wn = wv&1;
  int j = jb*32 + wn*16 + (lane&15);
  float bi = bias[j], bff = bias[384+j], bg = bias[768+j], bo = bias[1152+j];
  #pragma unroll
  for(int mt=0;mt<4;mt++){
    #pragma unroll
    for(int r=0;r<4;r++){
      int brow = mbase + wm*64 + mt*16 + (lane>>4)*4 + r;
      float zi = acc[mt][0][r]+bi, zf = acc[mt][1][r]+bff,
            zg = acc[mt][2][r]+bg, zo = acc[mt][3][r]+bo;
      size_t ci = (size_t)brow*HID + j;
      float cold = cst[ci];
      float cn = sigf(zf)*cold + sigf(zi)*tanh_f(zg);
      cst[ci] = cn;
      bf16 hb = (bf16)(sigf(zo)*tanh_f(cn));
      d0[(size_t)brow*ld0 + j] = hb;
      if(d1) d1[(size_t)brow*ld1 + j] = hb;
    }
  }
}

// ---------------- decoder LSTM ----------------
__global__ __launch_bounds__(256)
void dec_lstm_k(int t){
  __shared__ char smem[SMEM_BYTES];
  int bid = blockIdx.x, mb = bid/12, jb = bid%12;
  int rs = t&1, wsl = rs^1;
  f32x4 acc[4][4];
  gemm_core(g_Adec + (size_t)rs*NB*768 + (size_t)mb*128*768, 768,
            g_Bpd + (size_t)jb*24*4096, 24, smem, acc);
  lstm_epi(acc, mb*128, jb, g_biasd, g_cdec,
           g_Adec + (size_t)wsl*NB*768 + 384, 768, (bf16*)nullptr, 0);
}

// ---------------- plain GEMM: mode 1 = u-proj (h@Wa -> g_u f32), mode 0 = dec_in relu ----------------
__global__ __launch_bounds__(256)
void plain_gemm_k(int t, int mode){
  __shared__ char smem[SMEM_BYTES];
  int bid = blockIdx.x, mb = bid/3, nb = bid%3;
  int rs = t&1;
  const bf16* A; int ldA, nks; const bf16* Bp;
  if(mode==1){ A = g_Adec + (size_t)rs*NB*768 + 384; ldA=768; Bp = g_Bpu; nks=12; }
  else       { A = g_Adin;                           ldA=416; Bp = g_Bpi; nks=13; }
  f32x4 acc[4][4];
  gemm_core(A + (size_t)mb*128*ldA, ldA, Bp + (size_t)nb*nks*4096, nks, smem, acc);
  int lane = threadIdx.x&63, wv = threadIdx.x>>6, wm = wv>>1, wn = wv&1;
  bf16* dbf = g_Adec + (size_t)rs*NB*768;
  #pragma unroll
  for(int mt=0;mt<4;mt++){
    #pragma unroll
    for(int ti=0;ti<4;ti++){
      int n = nb*128 + (ti*2+wn)*16 + (lane&15);
      #pragma unroll
      for(int r=0;r<4;r++){
        int brow = mb*128 + wm*64 + mt*16 + (lane>>4)*4 + r;
        float v = acc[mt][ti][r];
        if(mode==0){ v += g_biasdin[n]; v = fmaxf(v,0.f); dbf[(size_t)brow*768 + n] = (bf16)v; }
        else g_u[(size_t)brow*384 + n] = v;
      }
    }
  }
}

// ---------------- attention: fused scores+softmax+ctx (online) ----------------
__global__ __launch_bounds__(256)
void attn_k(){
  __shared__ float sm[4][392];
  int tid = threadIdx.x, lane = tid&63, w = tid>>6;
  int bl = w>>1, hf = w&1;
  int b = blockIdx.x*2 + bl;
  const float* ub = g_u + (size_t)b*HID + lane*6;
  float u0=ub[0],u1=ub[1],u2=ub[2],u3=ub[3],u4=ub[4],u5=ub[5];
  const u32* er = (const u32*)(g_enc + (size_t)b*LSEQ*HID) + (size_t)hf*168*192 + lane*3;
  float m=-1e30f, den=0.f, a0=0,a1=0,a2=0,a3=0,a4=0,a5=0;
  for(int l=0;l<168;l++){
    u32 w0 = er[0], w1 = er[1], w2 = er[2];
    er += 192;
    float e0 = __uint_as_float(w0<<16);
    float e1 = __uint_as_float(w0 & 0xffff0000u);
    float e2 = __uint_as_float(w1<<16);
    float e3 = __uint_as_float(w1 & 0xffff0000u);
    float e4 = __uint_as_float(w2<<16);
    float e5 = __uint_as_float(w2 & 0xffff0000u);
    float p = e0*u0 + e1*u1 + e2*u2 + e3*u3 + e4*u4 + e5*u5;
    #pragma unroll
    for(int o=1;o<64;o<<=1) p += __shfl_xor(p, o, 64);
    float mn = fmaxf(m, p);
    float al = __expf(m - mn), pe = __expf(p - mn);
    den = den*al + pe;
    a0 = a0*al + pe*e0; a1 = a1*al + pe*e1; a2 = a2*al + pe*e2;
    a3 = a3*al + pe*e3; a4 = a4*al + pe*e4; a5 = a5*al + pe*e5;
    m = mn;
  }
  if(lane==0){ sm[w][0]=m; sm[w][1]=den; }
  sm[w][2+lane*6+0]=a0; sm[w][2+lane*6+1]=a1; sm[w][2+lane*6+2]=a2;
  sm[w][2+lane*6+3]=a3; sm[w][2+lane*6+4]=a4; sm[w][2+lane*6+5]=a5;
  __syncthreads();
  if(hf==0){
    float m2 = sm[w+1][0], d2 = sm[w+1][1];
    float M = fmaxf(m, m2);
    float f1 = __expf(m - M), f2 = __expf(m2 - M);
    float inv = 1.f/(den*f1 + d2*f2);
    bf16* cd = g_Adin + (size_t)b*416 + 5 + lane*6;
    cd[0] = (bf16)((a0*f1 + sm[w+1][2+lane*6+0]*f2)*inv);
    cd[1] = (bf16)((a1*f1 + sm[w+1][2+lane*6+1]*f2)*inv);
    cd[2] = (bf16)((a2*f1 + sm[w+1][2+lane*6+2]*f2)*inv);
    cd[3] = (bf16)((a3*f1 + sm[w+1][2+lane*6+3]*f2)*inv);
    cd[4] = (bf16)((a4*f1 + sm[w+1][2+lane*6+4]*f2)*inv);
    cd[5] = (bf16)((a5*f1 + sm[w+1][2+lane*6+5]*f2)*inv);
  }
}

// ---------------- output head + next-step A_din fill ----------------
__global__ void post_k(int t, const float* __restrict__ outW,
                       const float* __restrict__ outb, float* __restrict__ out,
                       const float* __restrict__ ff){
  int b = blockIdx.x*256 + threadIdx.x;
  if(b>=NB) return;
  int wsl = (t&1)^1;
  const s16x8* hp = (const s16x8*)(g_Adec + (size_t)wsl*NB*768 + (size_t)b*768 + 384);
  float acc = 0.f;
  #pragma unroll 4
  for(int i=0;i<48;i++){
    s16x8 v = hp[i];
    #pragma unroll
    for(int e=0;e<8;e++){
      float hv = __uint_as_float(((u32)(uint16_t)v[e])<<16);
      acc += hv*outW[i*8+e];
    }
  }
  float y = acc + outb[0];
  out[(size_t)b*HOR + t] = y;
  g_Adin[(size_t)b*416] = (bf16)y;
  if(t+1<HOR){
    #pragma unroll
    for(int k=0;k<4;k++) g_Adin[(size_t)b*416 + 1 + k] = (bf16)ff[(size_t)b*HOR*4 + (t+1)*4 + k];
  }
}

// ---------------- decoder init ----------------
__global__ void dec_prep_k(const float* __restrict__ ff){
  int i = blockIdx.x*256 + threadIdx.x;
  if(i < NB*HID){
    int b = i/HID, j = i%HID;
    g_Adec[(size_t)b*768 + 384 + j] = g_enc[(size_t)b*LSEQ*HID + (size_t)(LSEQ-1)*HID + j];
  }
  if(i < NB*4){
    int b = i>>2, k = i&3;
    g_Adin[(size_t)b*416 + 1 + k] = (bf16)ff[(size_t)b*HOR*4 + k];
  }
  if(i < NB) g_Adin[(size_t)i*416] = (bf16)0.f;
}

extern "C" void kernel_launch(void* const* d_in, const int* in_sizes, int n_in,
                              void* d_out, int out_size, void* d_ws, size_t ws_size,
                              hipStream_t stream){
  const float* x    = (const float*)d_in[0];
  const float* ff   = (const float*)d_in[1];
  const float* Wih0 = (const float*)d_in[2];
  const float* Whh0 = (const float*)d_in[3];
  const float* bih0 = (const float*)d_in[4];
  const float* bhh0 = (const float*)d_in[5];
  const float* Wih1 = (const float*)d_in[6];
  const float* Whh1 = (const float*)d_in[7];
  const float* bih1 = (const float*)d_in[8];
  const float* bhh1 = (const float*)d_in[9];
  const float* Wa   = (const float*)d_in[10];
  const float* dinW = (const float*)d_in[11];
  const float* dinb = (const float*)d_in[12];
  const float* dWih = (const float*)d_in[13];
  const float* dWhh = (const float*)d_in[14];
  const float* dbih = (const float*)d_in[15];
  const float* dbhh = (const float*)d_in[16];
  const float* outW = (const float*)d_in[17];
  const float* outb = (const float*)d_in[18];
  float* out = (float*)d_out;

  zero_state_k<<<1024,256,0,stream>>>();
  pack_xb_k<<<2048,256,0,stream>>>(x);
  pack_gates_k<<<(12*13*512)/256,256,0,stream>>>(0, Whh0, Wih0, 13);
  pack_gates16_k<<<576,256,0,stream>>>(Wih1, Whh1);
  pack_gates_k<<<(12*24*512)/256,256,0,stream>>>(2, dWih, dWhh, 24);
  pack_plain_k<<<(3*13*512)/256,256,0,stream>>>(0, dinW, 13, 3);
  pack_plain_k<<<(3*12*512)/256,256,0,stream>>>(1, Wa, 12, 3);
  prep_misc_k<<<8,256,0,stream>>>(bih0,bhh0,bih1,bhh1,dbih,dbhh,dinb);

  hipFuncSetAttribute((const void*)enc6_k,
                      hipFuncAttributeMaxDynamicSharedMemorySize, 114688);
  enc6_k<<<192,256,114688,stream>>>();

  dec_prep_k<<<1536,256,0,stream>>>(ff);
  for(int t=0;t<HOR;t++){
    plain_gemm_k<<<24,256,0,stream>>>(t, 1);
    attn_k<<<512,256,0,stream>>>();
    plain_gemm_k<<<24,256,0,stream>>>(t, 0);
    dec_lstm_k<<<96,256,0,stream>>>(t);
    post_k<<<4,256,0,stream>>>(t, outW, outb, out, ff);
  }
  (void)in_sizes; (void)n_in; (void)out_size; (void)d_ws; (void)ws_size;
}

// Round 10
// 8571.394 us; speedup vs baseline: 1.5113x; 1.0211x over previous
//
#include <hip/hip_runtime.h>
#include <stdint.h>

typedef __bf16 bf16;
typedef __bf16 bf16x8 __attribute__((ext_vector_type(8)));
typedef short  s16x8  __attribute__((ext_vector_type(8)));
typedef float  f32x4  __attribute__((ext_vector_type(4)));
typedef uint32_t u32;

#define NB   1024
#define LSEQ 336
#define HID  384
#define HOR  18
#define SMEM_BYTES 36864

// ---------------- device-global scratch ----------------
__device__ bf16  g_H0[(size_t)(LSEQ+1)*NB*HID];  // 265 MB: h0 chain; slot w+1 = h0[t=w]; slot0 zeroed
__device__ bf16  g_enc[(size_t)NB*LSEQ*HID];     // 264 MB, [B][L][H]; doubles as h1 chain
__device__ bf16  g_zero[HID];                    // never written: zeros (s==1 h1 reads)
__device__ bf16  g_Adec[2*NB*768];    // [2][1024][768]: din | h_dec
__device__ bf16  g_Adin[NB*416];      // [1024][416]: y | feat4 | ctx384 | pad
__device__ bf16  g_xb[NB*LSEQ*8];     // bf16 x
__device__ float g_cdec[NB*HID];
__device__ float g_u[NB*HID];
__device__ float g_bias0[1536], g_bias1[1536], g_biasd[1536], g_biasdin[384];
__device__ bf16  g_Bp0[12*13*4096];         // enc L0 pack (32-col jb granularity)
__device__ bf16  g_Bp1n[24*24*4*64*8];      // enc L1 pack (16-col jn granularity)
__device__ bf16  g_Bpd[12*24*4096];
__device__ bf16  g_Bpi[3*13*4096];
__device__ bf16  g_Bpu[3*12*4096];
__device__ int   g_f0[8*LSEQ];        // [g][w]: L0 group g finished window w (target 12)
__device__ int   g_f1[4*(LSEQ+1)];    // [m][s]: L1 group m finished step s (target 24)

__device__ __forceinline__ float sigf(float x){ return 1.0f/(1.0f + __expf(-x)); }
__device__ __forceinline__ float tanh_f(float x){
  x = fminf(fmaxf(x, -15.f), 15.f);
  float e = __expf(2.f*x);
  return (e - 1.f)/(e + 1.f);
}

// Device-scope 16B store as 2x u64 relaxed atomics: completes AT the MALL (R5/R9-proven
// visibility). vmcnt-drained by __syncthreads before the flag bump.
__device__ __forceinline__ void ds16(bf16* p, s16x8 v){
  union{ s16x8 v; uint64_t q[2]; } u; u.v = v;
  __hip_atomic_store((uint64_t*)p,     u.q[0], __ATOMIC_RELAXED, __HIP_MEMORY_SCOPE_AGENT);
  __hip_atomic_store((uint64_t*)p + 1, u.q[1], __ATOMIC_RELAXED, __HIP_MEMORY_SCOPE_AGENT);
}

// ---------------- per-call state zeroing (replay determinism) ----------------
__global__ void zero_state_k(){
  int i = blockIdx.x*blockDim.x + threadIdx.x;
  int st = gridDim.x*blockDim.x;
  bf16 z = (bf16)0.f;
  for(int k=i;k<NB*HID;k+=st){ g_H0[k]=z; g_cdec[k]=0.f; }
  for(int k=i;k<8*LSEQ;k+=st) g_f0[k]=0;
  for(int k=i;k<4*(LSEQ+1);k+=st) g_f1[k]=0;
}

__global__ void pack_xb_k(const float* __restrict__ x){
  int i = blockIdx.x*256 + threadIdx.x;
  int n = NB*LSEQ*8;
  for(int k=i; k<n; k+=gridDim.x*256) g_xb[k] = (bf16)x[k];
}

// ---------------- weight packs ----------------
// gates pack: out[jb][ks][tt(8)][lane(64)][8], n = (tt>>1)*384 + jb*32 + (tt&1)*16 + (lane&15)
__global__ void pack_gates_k(int mode, const float* __restrict__ W1, const float* __restrict__ W2,
                             int nks){
  bf16* out = (mode==0)? g_Bp0 : g_Bpd;
  size_t idx = (size_t)blockIdx.x*256 + threadIdx.x;
  size_t total = (size_t)12*nks*512;
  if(idx >= total) return;
  int lane = (int)(idx & 63);
  int tt   = (int)((idx>>6) & 7);
  size_t tmp = idx >> 9;
  int ks = (int)(tmp % nks);
  int jb = (int)(tmp / nks);
  int n  = (tt>>1)*HID + jb*32 + (tt&1)*16 + (lane&15);
  int kb = ks*32 + (lane>>4)*8;
  bf16x8 v;
  #pragma unroll
  for(int i=0;i<8;i++){
    int k = kb + i;
    float f;
    if(mode==0) f = (k<384) ? W1[(size_t)n*384 + k] : (k<392 ? W2[(size_t)n*8 + (k-384)] : 0.f);
    else        f = (k<384) ? W1[(size_t)n*384 + k] : W2[(size_t)n*384 + (k-384)];
    v[i] = (bf16)f;
  }
  *(bf16x8*)(out + idx*8) = v;
}

// enc L1 pack: out[jn(24)][ks(24)][g(4)][lane(64)][8], n = g*384 + jn*16 + (lane&15)
__global__ void pack_gates16_k(const float* __restrict__ Wih1, const float* __restrict__ Whh1){
  int idx = blockIdx.x*256 + threadIdx.x;
  if(idx >= 24*24*4*64) return;
  int lane = idx&63, rem = idx>>6;
  int g = rem&3; rem >>= 2;
  int ks = rem%24, jn = rem/24;
  int n  = g*HID + jn*16 + (lane&15);
  int kb = ks*32 + (lane>>4)*8;
  bf16x8 v;
  #pragma unroll
  for(int i=0;i<8;i++){
    int k = kb+i;
    float f = (k<384)? Wih1[(size_t)n*384 + k] : Whh1[(size_t)n*384 + (k-384)];
    v[i] = (bf16)f;
  }
  *(bf16x8*)(g_Bp1n + (size_t)idx*8) = v;
}

// plain pack: out[nb][ks][tt(8)][lane][8], n = nb*128 + tt*16 + (lane&15)
__global__ void pack_plain_k(int mode, const float* __restrict__ W, int nks, int nb_cnt){
  bf16* out = mode ? g_Bpu : g_Bpi;
  size_t idx = (size_t)blockIdx.x*256 + threadIdx.x;
  size_t total = (size_t)nb_cnt*nks*512;
  if(idx>=total) return;
  int lane = (int)(idx&63);
  int tt   = (int)((idx>>6)&7);
  size_t tmp = idx>>9;
  int ks = (int)(tmp%nks);
  int nb = (int)(tmp/nks);
  int n  = nb*128 + tt*16 + (lane&15);
  int kb = ks*32 + (lane>>4)*8;
  bf16x8 v;
  #pragma unroll
  for(int i=0;i<8;i++){
    int k = kb+i;
    float f;
    if(mode==0) f = (k<389)? W[(size_t)n*389 + k] : 0.f;
    else        f = W[(size_t)k*384 + n];
    v[i]=(bf16)f;
  }
  *(bf16x8*)(out + idx*8) = v;
}

__global__ void prep_misc_k(const float* bih0,const float* bhh0,const float* bih1,const float* bhh1,
                            const float* dbih,const float* dbhh,const float* dinb){
  int i = blockIdx.x*256 + threadIdx.x;
  if(i<1536){ g_bias0[i]=bih0[i]+bhh0[i]; g_bias1[i]=bih1[i]+bhh1[i]; g_biasd[i]=dbih[i]+dbhh[i]; }
  if(i<384) g_biasdin[i]=dinb[i];
}

// ---------------- dataflow spin (relaxed agent atomics on flags only) ----------------
__device__ __forceinline__ void spin_ge(int* p, int tgt){
  while(__hip_atomic_load(p, __ATOMIC_RELAXED, __HIP_MEMORY_SCOPE_AGENT) < tgt)
    __builtin_amdgcn_s_sleep(1);
}

// ---------------- persistent 2-layer encoder (R9 protocol; c-state in registers) ----------------
// L0: bid<96: g=bid&7 (128 rows; 12 jb siblings share XCD g), jb=bid>>3 (32 cols).
// L1: bid>=96: idx=bid-96, m=idx&3 (256 rows), jn=idx>>2 (16 cols).
// Producers: ds16 agent atomics (MALL-visible at vmcnt drain). Consumers: plain cached
// loads at fresh-slot addresses. Flags: relaxed agent atomics; L1 polls 3 flags in parallel.
__global__ __launch_bounds__(256,1)
void enc7_k(){
  extern __shared__ char lds[];
  const int bid = blockIdx.x, tid = threadIdx.x;
  const int lane = tid&63, wv = tid>>6;
  const int l15 = lane&15, lk = (lane>>4)*8;

  if(bid < 96){
    const int g = bid & 7, jb = bid >> 3;
    { const s16x8* src = (const s16x8*)(g_Bp0 + (size_t)jb*13*4096);
      s16x8* dst = (s16x8*)lds;
      #pragma unroll
      for(int h=0;h<26;h++) dst[tid + h*256] = src[tid + h*256];
    }
    bf16* tr = (bf16*)(lds + 13*8192);        // [128][32] bf16
    __syncthreads();
    const int jj0 = jb*32 + l15;
    float bia[2],bfa[2],bga[2],boa[2];
    #pragma unroll
    for(int jh=0;jh<2;jh++){
      bia[jh]=g_bias0[jj0+jh*16];     bfa[jh]=g_bias0[384+jj0+jh*16];
      bga[jh]=g_bias0[768+jj0+jh*16]; boa[jh]=g_bias0[1152+jj0+jh*16];
    }
    size_t hoff[2], xoff[2];
    #pragma unroll
    for(int mt=0;mt<2;mt++){
      int row = g*128 + wv*32 + mt*16 + l15;
      hoff[mt] = (size_t)row*HID + lk;
      xoff[mt] = (size_t)row*LSEQ*8;
    }
    float c[2][2][4] = {};
    for(int w=0; w<LSEQ; w++){
      if(tid==0 && w>=1) spin_ge(&g_f0[g*LSEQ + (w-1)], 12);
      __syncthreads();
      asm volatile("" ::: "memory");
      const bf16* H0w = g_H0 + (size_t)w*NB*HID;
      bf16x8 af[13][2];
      #pragma unroll
      for(int ks=0;ks<12;ks++)
        #pragma unroll
        for(int mt=0;mt<2;mt++)
          af[ks][mt] = *(const bf16x8*)(H0w + hoff[mt] + ks*32);
      #pragma unroll
      for(int mt=0;mt<2;mt++){
        bf16x8 z;
        #pragma unroll
        for(int e=0;e<8;e++) z[e]=(bf16)0.f;
        if(lk==0) z = *(const bf16x8*)(g_xb + xoff[mt] + (size_t)w*8);
        af[12][mt] = z;
      }
      f32x4 acc[2][8];
      #pragma unroll
      for(int m2=0;m2<2;m2++)
        #pragma unroll
        for(int tt=0;tt<8;tt++) acc[m2][tt] = (f32x4){0.f,0.f,0.f,0.f};
      #pragma unroll
      for(int ks=0;ks<13;ks++){
        #pragma unroll
        for(int tt=0;tt<8;tt++){
          bf16x8 bfr = *(const bf16x8*)(lds + (ks*8+tt)*1024 + lane*16);
          acc[0][tt] = __builtin_amdgcn_mfma_f32_16x16x32_bf16(af[ks][0], bfr, acc[0][tt],0,0,0);
          acc[1][tt] = __builtin_amdgcn_mfma_f32_16x16x32_bf16(af[ks][1], bfr, acc[1][tt],0,0,0);
        }
      }
      #pragma unroll
      for(int mt=0;mt<2;mt++)
        #pragma unroll
        for(int jh=0;jh<2;jh++)
          #pragma unroll
          for(int r=0;r<4;r++){
            float zi=acc[mt][0+jh][r]+bia[jh], zf=acc[mt][2+jh][r]+bfa[jh],
                  zg=acc[mt][4+jh][r]+bga[jh], zo=acc[mt][6+jh][r]+boa[jh];
            float cn = sigf(zf)*c[mt][jh][r] + sigf(zi)*tanh_f(zg);
            c[mt][jh][r]=cn;
            int lr = wv*32 + mt*16 + (lane>>4)*4 + r;
            tr[lr*32 + jh*16 + l15] = (bf16)(sigf(zo)*tanh_f(cn));
          }
      __syncthreads();
      bf16* H0n = g_H0 + (size_t)(w+1)*NB*HID;
      #pragma unroll
      for(int h=0;h<2;h++){
        int p = tid + h*256;
        int row = p>>2, cc = p&3;
        s16x8 v = *(const s16x8*)(tr + row*32 + cc*8);
        ds16(H0n + (size_t)(g*128+row)*HID + jb*32 + cc*8, v);
      }
      __syncthreads();   // drains vmcnt: atomic stores are at MALL before flag
      if(tid==0)
        __hip_atomic_fetch_add(&g_f0[g*LSEQ + w], 1, __ATOMIC_RELAXED, __HIP_MEMORY_SCOPE_AGENT);
    }
  } else {
    const int idx = bid-96, m = idx & 3, jn = idx >> 2;
    { const s16x8* src = (const s16x8*)(g_Bp1n + (size_t)jn*24*2048);
      s16x8* dst = (s16x8*)lds;
      #pragma unroll
      for(int h=0;h<24;h++) dst[tid + h*256] = src[tid + h*256];
    }
    bf16* tr = (bf16*)(lds + 24*4096);        // [256][16] bf16
    __syncthreads();
    const int jj = jn*16 + l15;
    const float bi=g_bias1[jj], bff=g_bias1[384+jj], bg=g_bias1[768+jj], bo=g_bias1[1152+jj];
    int rows[4]; size_t hoff[4];
    #pragma unroll
    for(int mt=0;mt<4;mt++){
      rows[mt] = m*256 + wv*64 + mt*16 + l15;
      hoff[mt] = (size_t)rows[mt]*HID + lk;
    }
    float c[4][4] = {};
    for(int s=1; s<=LSEQ; s++){
      if(tid==0)           spin_ge(&g_f0[(2*m)*LSEQ + (s-1)], 12);
      else if(tid==1)      spin_ge(&g_f0[(2*m+1)*LSEQ + (s-1)], 12);
      else if(tid==2 && s>=2) spin_ge(&g_f1[m*(LSEQ+1) + (s-1)], 24);
      __syncthreads();
      asm volatile("" ::: "memory");
      const bf16* H0s = g_H0 + (size_t)s*NB*HID;          // h0[t=s-1]
      const size_t strideE = (s>=2)? (size_t)LSEQ*HID : 0;
      const bf16* Es = (s>=2)? (g_enc + (size_t)(s-2)*HID) : g_zero;  // h1[t=s-2]
      size_t eoff[4];
      #pragma unroll
      for(int mt=0;mt<4;mt++) eoff[mt] = (size_t)rows[mt]*strideE + lk;
      bf16x8 ap[8][4];
      #pragma unroll
      for(int d=0; d<8; d++)
        #pragma unroll
        for(int mt=0;mt<4;mt++)
          ap[d][mt] = *(const bf16x8*)(H0s + hoff[mt] + d*32);
      f32x4 acc[4][4];
      #pragma unroll
      for(int mt=0;mt<4;mt++)
        #pragma unroll
        for(int g4=0;g4<4;g4++) acc[mt][g4] = (f32x4){0.f,0.f,0.f,0.f};
      #pragma unroll
      for(int ks=0;ks<24;ks++){
        bf16x8 bfr[4];
        #pragma unroll
        for(int g4=0;g4<4;g4++) bfr[g4] = *(const bf16x8*)(lds + (ks*4+g4)*1024 + lane*16);
        bf16x8 a[4];
        #pragma unroll
        for(int mt=0;mt<4;mt++) a[mt] = ap[ks&7][mt];
        int kn = ks+8;
        if(kn<24){
          if(kn<12){
            #pragma unroll
            for(int mt=0;mt<4;mt++) ap[ks&7][mt] = *(const bf16x8*)(H0s + hoff[mt] + kn*32);
          } else {
            #pragma unroll
            for(int mt=0;mt<4;mt++) ap[ks&7][mt] = *(const bf16x8*)(Es + eoff[mt] + (kn-12)*32);
          }
        }
        #pragma unroll
        for(int mt=0;mt<4;mt++)
          #pragma unroll
          for(int g4=0;g4<4;g4++)
            acc[mt][g4] = __builtin_amdgcn_mfma_f32_16x16x32_bf16(a[mt], bfr[g4], acc[mt][g4],0,0,0);
      }
      #pragma unroll
      for(int mt=0;mt<4;mt++)
        #pragma unroll
        for(int r=0;r<4;r++){
          float zi=acc[mt][0][r]+bi, zf=acc[mt][1][r]+bff,
                zg=acc[mt][2][r]+bg, zo=acc[mt][3][r]+bo;
          float cn = sigf(zf)*c[mt][r] + sigf(zi)*tanh_f(zg);
          c[mt][r]=cn;
          int lr = wv*64 + mt*16 + (lane>>4)*4 + r;
          tr[lr*16 + l15] = (bf16)(sigf(zo)*tanh_f(cn));
        }
      __syncthreads();
      const int t = s-1;
      #pragma unroll
      for(int h=0;h<2;h++){
        int p = tid + h*256;
        int row = p>>1, hf2 = p&1;
        s16x8 v = *(const s16x8*)(tr + row*16 + hf2*8);
        ds16(g_enc + ((size_t)(m*256+row)*LSEQ + t)*HID + jn*16 + hf2*8, v);
      }
      __syncthreads();   // drains vmcnt before flag
      if(tid==0)
        __hip_atomic_fetch_add(&g_f1[m*(LSEQ+1) + s], 1, __ATOMIC_RELAXED, __HIP_MEMORY_SCOPE_AGENT);
    }
  }
}

// ---------------- GEMM core (decoder) ----------------
struct SReg { s16x8 a0,a1,b0,b1; };

__device__ __forceinline__ void stage_load(const bf16* __restrict__ A, int ldA,
                                           const bf16* __restrict__ Bk, int tid, SReg& sr){
  int c0 = tid, c1 = tid+256;
  sr.a0 = *(const s16x8*)(A + (size_t)(c0>>2)*ldA + (c0&3)*8);
  sr.a1 = *(const s16x8*)(A + (size_t)(c1>>2)*ldA + (c1&3)*8);
  const s16x8* B8 = (const s16x8*)Bk;
  sr.b0 = B8[c0]; sr.b1 = B8[c1];
}

__device__ __forceinline__ void stage_write(char* Ab, char* Bb, int tid, const SReg& sr){
  int c0 = tid, c1 = tid+256;
  *(s16x8*)(Ab + (c0>>2)*80 + (c0&3)*16) = sr.a0;
  *(s16x8*)(Ab + (c1>>2)*80 + (c1&3)*16) = sr.a1;
  *(s16x8*)(Bb + c0*16) = sr.b0;
  *(s16x8*)(Bb + c1*16) = sr.b1;
}

__device__ __forceinline__ void gemm_core(const bf16* __restrict__ A, int ldA,
                                          const bf16* __restrict__ Bp, int nks,
                                          char* smem, f32x4 acc[4][4]){
  const int tid = threadIdx.x;
  const int lane = tid & 63, wv = tid>>6, wm = wv>>1, wn = wv&1;
  char* Ab0 = smem;            char* Ab1 = smem + 10240;
  char* Bb0 = smem + 20480;    char* Bb1 = smem + 28672;
  f32x4 z = {0.f,0.f,0.f,0.f};
  #pragma unroll
  for(int m=0;m<4;m++)
    #pragma unroll
    for(int g=0;g<4;g++) acc[m][g]=z;
  SReg sr;
  stage_load(A, ldA, Bp, tid, sr);
  stage_write(Ab0, Bb0, tid, sr);
  const int aoff = (wm*64 + (lane&15))*80 + (lane>>4)*16;
  const int boff = wn*1024 + lane*16;
  for(int ks=0; ks<nks; ks++){
    char* Ac = (ks&1)? Ab1: Ab0;
    char* Bc = (ks&1)? Bb1: Bb0;
    char* An = (ks&1)? Ab0: Ab1;
    char* Bn = (ks&1)? Bb0: Bb1;
    bool more = (ks+1)<nks;
    if(more) stage_load(A + (ks+1)*32, ldA, Bp + (size_t)(ks+1)*4096, tid, sr);
    __syncthreads();
    bf16x8 af[4], bfr[4];
    #pragma unroll
    for(int mt=0;mt<4;mt++) af[mt] = *(const bf16x8*)(Ac + aoff + mt*16*80);
    #pragma unroll
    for(int g=0;g<4;g++)    bfr[g] = *(const bf16x8*)(Bc + boff + g*2048);
    #pragma unroll
    for(int mt=0;mt<4;mt++)
      #pragma unroll
      for(int g=0;g<4;g++)
        acc[mt][g] = __builtin_amdgcn_mfma_f32_16x16x32_bf16(af[mt], bfr[g], acc[mt][g], 0,0,0);
    if(more) stage_write(An, Bn, tid, sr);
  }
}

// ---------------- LSTM epilogue (decoder) ----------------
__device__ __forceinline__ void lstm_epi(f32x4 acc[4][4], int mbase, int jb,
     const float* __restrict__ bias, float* __restrict__ cst,
     bf16* __restrict__ d0, int ld0, bf16* __restrict__ d1, size_t ld1){
  int lane = threadIdx.x&63, wv = threadIdx.x>>6, wm = wv>>1, wn = wv&1;
  int j = jb*32 + wn*16 + (lane&15);
  float bi = bias[j], bff = bias[384+j], bg = bias[768+j], bo = bias[1152+j];
  #pragma unroll
  for(int mt=0;mt<4;mt++){
    #pragma unroll
    for(int r=0;r<4;r++){
      int brow = mbase + wm*64 + mt*16 + (lane>>4)*4 + r;
      float zi = acc[mt][0][r]+bi, zf = acc[mt][1][r]+bff,
            zg = acc[mt][2][r]+bg, zo = acc[mt][3][r]+bo;
      size_t ci = (size_t)brow*HID + j;
      float cold = cst[ci];
      float cn = sigf(zf)*cold + sigf(zi)*tanh_f(zg);
      cst[ci] = cn;
      bf16 hb = (bf16)(sigf(zo)*tanh_f(cn));
      d0[(size_t)brow*ld0 + j] = hb;
      if(d1) d1[(size_t)brow*ld1 + j] = hb;
    }
  }
}

// ---------------- decoder LSTM ----------------
__global__ __launch_bounds__(256)
void dec_lstm_k(int t){
  __shared__ char smem[SMEM_BYTES];
  int bid = blockIdx.x, mb = bid/12, jb = bid%12;
  int rs = t&1, wsl = rs^1;
  f32x4 acc[4][4];
  gemm_core(g_Adec + (size_t)rs*NB*768 + (size_t)mb*128*768, 768,
            g_Bpd + (size_t)jb*24*4096, 24, smem, acc);
  lstm_epi(acc, mb*128, jb, g_biasd, g_cdec,
           g_Adec + (size_t)wsl*NB*768 + 384, 768, (bf16*)nullptr, 0);
}

// ---------------- plain GEMM: mode 1 = u-proj (+fused post for t-1), mode 0 = dec_in relu ----------------
__global__ __launch_bounds__(256)
void plain_gemm_k(int t, int mode, const float* __restrict__ outW,
                  const float* __restrict__ outb, float* __restrict__ out,
                  const float* __restrict__ ff){
  __shared__ char smem[SMEM_BYTES];
  int bid = blockIdx.x, mb = bid/3, nb = bid%3;
  int rs = t&1;
  const bf16* A; int ldA, nks; const bf16* Bp;
  if(mode==1){ A = g_Adec + (size_t)rs*NB*768 + 384; ldA=768; Bp = g_Bpu; nks=12; }
  else       { A = g_Adin;                           ldA=416; Bp = g_Bpi; nks=13; }
  f32x4 acc[4][4];
  gemm_core(A + (size_t)mb*128*ldA, ldA, Bp + (size_t)nb*nks*4096, nks, smem, acc);
  int lane = threadIdx.x&63, wv = threadIdx.x>>6, wm = wv>>1, wn = wv&1;
  bf16* dbf = g_Adec + (size_t)rs*NB*768;
  #pragma unroll
  for(int mt=0;mt<4;mt++){
    #pragma unroll
    for(int ti=0;ti<4;ti++){
      int n = nb*128 + (ti*2+wn)*16 + (lane&15);
      #pragma unroll
      for(int r=0;r<4;r++){
        int brow = mb*128 + wm*64 + mt*16 + (lane>>4)*4 + r;
        float v = acc[mt][ti][r];
        if(mode==0){ v += g_biasdin[n]; v = fmaxf(v,0.f); dbf[(size_t)brow*768 + n] = (bf16)v; }
        else g_u[(size_t)brow*384 + n] = v;
      }
    }
  }
  // fused post for step t-1 (h slot rs == (t-1 parity)^1): nb==0 blocks, 128 rows each
  if(mode==1 && t>=1 && nb==0 && threadIdx.x<128){
    int b = mb*128 + threadIdx.x;
    const s16x8* hp = (const s16x8*)(g_Adec + (size_t)rs*NB*768 + (size_t)b*768 + 384);
    float acc2 = 0.f;
    #pragma unroll 4
    for(int i=0;i<48;i++){
      s16x8 v = hp[i];
      #pragma unroll
      for(int e=0;e<8;e++){
        float hv = __uint_as_float(((u32)(uint16_t)v[e])<<16);
        acc2 += hv*outW[i*8+e];
      }
    }
    float y = acc2 + outb[0];
    out[(size_t)b*HOR + (t-1)] = y;
    g_Adin[(size_t)b*416] = (bf16)y;
    #pragma unroll
    for(int k=0;k<4;k++) g_Adin[(size_t)b*416 + 1 + k] = (bf16)ff[(size_t)b*HOR*4 + t*4 + k];
  }
}

// ---------------- attention: fused scores+softmax+ctx (online) ----------------
__global__ __launch_bounds__(256)
void attn_k(){
  __shared__ float sm[4][392];
  int tid = threadIdx.x, lane = tid&63, w = tid>>6;
  int bl = w>>1, hf = w&1;
  int b = blockIdx.x*2 + bl;
  const float* ub = g_u + (size_t)b*HID + lane*6;
  float u0=ub[0],u1=ub[1],u2=ub[2],u3=ub[3],u4=ub[4],u5=ub[5];
  const u32* er = (const u32*)(g_enc + (size_t)b*LSEQ*HID) + (size_t)hf*168*192 + lane*3;
  float m=-1e30f, den=0.f, a0=0,a1=0,a2=0,a3=0,a4=0,a5=0;
  for(int l=0;l<168;l++){
    u32 w0 = er[0], w1 = er[1], w2 = er[2];
    er += 192;
    float e0 = __uint_as_float(w0<<16);
    float e1 = __uint_as_float(w0 & 0xffff0000u);
    float e2 = __uint_as_float(w1<<16);
    float e3 = __uint_as_float(w1 & 0xffff0000u);
    float e4 = __uint_as_float(w2<<16);
    float e5 = __uint_as_float(w2 & 0xffff0000u);
    float p = e0*u0 + e1*u1 + e2*u2 + e3*u3 + e4*u4 + e5*u5;
    #pragma unroll
    for(int o=1;o<64;o<<=1) p += __shfl_xor(p, o, 64);
    float mn = fmaxf(m, p);
    float al = __expf(m - mn), pe = __expf(p - mn);
    den = den*al + pe;
    a0 = a0*al + pe*e0; a1 = a1*al + pe*e1; a2 = a2*al + pe*e2;
    a3 = a3*al + pe*e3; a4 = a4*al + pe*e4; a5 = a5*al + pe*e5;
    m = mn;
  }
  if(lane==0){ sm[w][0]=m; sm[w][1]=den; }
  sm[w][2+lane*6+0]=a0; sm[w][2+lane*6+1]=a1; sm[w][2+lane*6+2]=a2;
  sm[w][2+lane*6+3]=a3; sm[w][2+lane*6+4]=a4; sm[w][2+lane*6+5]=a5;
  __syncthreads();
  if(hf==0){
    float m2 = sm[w+1][0], d2 = sm[w+1][1];
    float M = fmaxf(m, m2);
    float f1 = __expf(m - M), f2 = __expf(m2 - M);
    float inv = 1.f/(den*f1 + d2*f2);
    bf16* cd = g_Adin + (size_t)b*416 + 5 + lane*6;
    cd[0] = (bf16)((a0*f1 + sm[w+1][2+lane*6+0]*f2)*inv);
    cd[1] = (bf16)((a1*f1 + sm[w+1][2+lane*6+1]*f2)*inv);
    cd[2] = (bf16)((a2*f1 + sm[w+1][2+lane*6+2]*f2)*inv);
    cd[3] = (bf16)((a3*f1 + sm[w+1][2+lane*6+3]*f2)*inv);
    cd[4] = (bf16)((a4*f1 + sm[w+1][2+lane*6+4]*f2)*inv);
    cd[5] = (bf16)((a5*f1 + sm[w+1][2+lane*6+5]*f2)*inv);
  }
}

// ---------------- output head (final step only; earlier steps fused into plain_gemm) ----------------
__global__ void post_k(int t, const float* __restrict__ outW,
                       const float* __restrict__ outb, float* __restrict__ out){
  int b = blockIdx.x*256 + threadIdx.x;
  if(b>=NB) return;
  int wsl = (t&1)^1;
  const s16x8* hp = (const s16x8*)(g_Adec + (size_t)wsl*NB*768 + (size_t)b*768 + 384);
  float acc = 0.f;
  #pragma unroll 4
  for(int i=0;i<48;i++){
    s16x8 v = hp[i];
    #pragma unroll
    for(int e=0;e<8;e++){
      float hv = __uint_as_float(((u32)(uint16_t)v[e])<<16);
      acc += hv*outW[i*8+e];
    }
  }
  out[(size_t)b*HOR + t] = acc + outb[0];
}

// ---------------- decoder init ----------------
__global__ void dec_prep_k(const float* __restrict__ ff){
  int i = blockIdx.x*256 + threadIdx.x;
  if(i < NB*HID){
    int b = i/HID, j = i%HID;
    g_Adec[(size_t)b*768 + 384 + j] = g_enc[(size_t)b*LSEQ*HID + (size_t)(LSEQ-1)*HID + j];
  }
  if(i < NB*4){
    int b = i>>2, k = i&3;
    g_Adin[(size_t)b*416 + 1 + k] = (bf16)ff[(size_t)b*HOR*4 + k];
  }
  if(i < NB) g_Adin[(size_t)i*416] = (bf16)0.f;
}

extern "C" void kernel_launch(void* const* d_in, const int* in_sizes, int n_in,
                              void* d_out, int out_size, void* d_ws, size_t ws_size,
                              hipStream_t stream){
  const float* x    = (const float*)d_in[0];
  const float* ff   = (const float*)d_in[1];
  const float* Wih0 = (const float*)d_in[2];
  const float* Whh0 = (const float*)d_in[3];
  const float* bih0 = (const float*)d_in[4];
  const float* bhh0 = (const float*)d_in[5];
  const float* Wih1 = (const float*)d_in[6];
  const float* Whh1 = (const float*)d_in[7];
  const float* bih1 = (const float*)d_in[8];
  const float* bhh1 = (const float*)d_in[9];
  const float* Wa   = (const float*)d_in[10];
  const float* dinW = (const float*)d_in[11];
  const float* dinb = (const float*)d_in[12];
  const float* dWih = (const float*)d_in[13];
  const float* dWhh = (const float*)d_in[14];
  const float* dbih = (const float*)d_in[15];
  const float* dbhh = (const float*)d_in[16];
  const float* outW = (const float*)d_in[17];
  const float* outb = (const float*)d_in[18];
  float* out = (float*)d_out;

  zero_state_k<<<1024,256,0,stream>>>();
  pack_xb_k<<<2048,256,0,stream>>>(x);
  pack_gates_k<<<(12*13*512)/256,256,0,stream>>>(0, Whh0, Wih0, 13);
  pack_gates16_k<<<576,256,0,stream>>>(Wih1, Whh1);
  pack_gates_k<<<(12*24*512)/256,256,0,stream>>>(2, dWih, dWhh, 24);
  pack_plain_k<<<(3*13*512)/256,256,0,stream>>>(0, dinW, 13, 3);
  pack_plain_k<<<(3*12*512)/256,256,0,stream>>>(1, Wa, 12, 3);
  prep_misc_k<<<8,256,0,stream>>>(bih0,bhh0,bih1,bhh1,dbih,dbhh,dinb);

  hipFuncSetAttribute((const void*)enc7_k,
                      hipFuncAttributeMaxDynamicSharedMemorySize, 114688);
  enc7_k<<<192,256,114688,stream>>>();

  dec_prep_k<<<1536,256,0,stream>>>(ff);
  for(int t=0;t<HOR;t++){
    plain_gemm_k<<<24,256,0,stream>>>(t, 1, outW, outb, out, ff);
    attn_k<<<512,256,0,stream>>>();
    plain_gemm_k<<<24,256,0,stream>>>(t, 0, outW, outb, out, ff);
    dec_lstm_k<<<96,256,0,stream>>>(t);
  }
  post_k<<<4,256,0,stream>>>(17, outW, outb, out);
  (void)in_sizes; (void)n_in; (void)out_size; (void)d_ws; (void)ws_size;
}

// Round 11
// 8401.936 us; speedup vs baseline: 1.5418x; 1.0202x over previous
//
#include <hip/hip_runtime.h>
#include <stdint.h>

typedef __bf16 bf16;
typedef __bf16 bf16x8 __attribute__((ext_vector_type(8)));
typedef short  s16x8  __attribute__((ext_vector_type(8)));
typedef float  f32x4  __attribute__((ext_vector_type(4)));
typedef uint32_t u32;

#define NB   1024
#define LSEQ 336
#define HID  384
#define HOR  18
#define SMEM_BYTES 36864

// ---------------- device-global scratch ----------------
__device__ bf16  g_H0[(size_t)(LSEQ+1)*NB*HID];  // 265 MB: h0 chain; slot w+1 = h0[t=w]; slot0 zeroed
__device__ bf16  g_enc[(size_t)NB*LSEQ*HID];     // 264 MB, [B][L][H]; doubles as h1 chain
__device__ bf16  g_zero[HID];                    // never written: zeros (s==1 h1 reads)
__device__ bf16  g_Adec[2*NB*768];    // [2][1024][768]: din | h_dec
__device__ bf16  g_Adin[NB*416];      // [1024][416]: y | feat4 | ctx384 | pad
__device__ bf16  g_xb[NB*LSEQ*8];     // bf16 x
__device__ float g_cdec[NB*HID];
__device__ float g_u[NB*HID];
__device__ float g_bias0[1536], g_bias1[1536], g_biasd[1536], g_biasdin[384];
__device__ bf16  g_Bp0[12*13*4096];         // enc L0 pack (32-col jb granularity)
__device__ bf16  g_Bp1n[24*24*4*64*8];      // enc L1 pack (16-col jn granularity)
__device__ bf16  g_Bpd[12*24*4096];
__device__ bf16  g_Bpi[3*13*4096];
__device__ bf16  g_Bpu[3*12*4096];
__device__ int   g_f0[8*LSEQ];        // [g][w]: L0 group g finished window w (target 12)
__device__ int   g_f1[4*(LSEQ+1)];    // [m][s]: L1 group m finished step s (target 24)

__device__ __forceinline__ float sigf(float x){ return 1.0f/(1.0f + __expf(-x)); }
__device__ __forceinline__ float tanh_f(float x){
  x = fminf(fmaxf(x, -15.f), 15.f);
  float e = __expf(2.f*x);
  return (e - 1.f)/(e + 1.f);
}

// Device-scope 16B store as 2x u64 relaxed atomics: completes AT the MALL (R5/R9-proven
// visibility). vmcnt-drained by __syncthreads before the flag bump.
__device__ __forceinline__ void ds16(bf16* p, s16x8 v){
  union{ s16x8 v; uint64_t q[2]; } u; u.v = v;
  __hip_atomic_store((uint64_t*)p,     u.q[0], __ATOMIC_RELAXED, __HIP_MEMORY_SCOPE_AGENT);
  __hip_atomic_store((uint64_t*)p + 1, u.q[1], __ATOMIC_RELAXED, __HIP_MEMORY_SCOPE_AGENT);
}

// ---------------- per-call state zeroing (replay determinism) ----------------
__global__ void zero_state_k(){
  int i = blockIdx.x*blockDim.x + threadIdx.x;
  int st = gridDim.x*blockDim.x;
  bf16 z = (bf16)0.f;
  for(int k=i;k<NB*HID;k+=st){ g_H0[k]=z; g_cdec[k]=0.f; }
  for(int k=i;k<8*LSEQ;k+=st) g_f0[k]=0;
  for(int k=i;k<4*(LSEQ+1);k+=st) g_f1[k]=0;
}

__global__ void pack_xb_k(const float* __restrict__ x){
  int i = blockIdx.x*256 + threadIdx.x;
  int n = NB*LSEQ*8;
  for(int k=i; k<n; k+=gridDim.x*256) g_xb[k] = (bf16)x[k];
}

// ---------------- weight packs ----------------
// gates pack: out[jb][ks][tt(8)][lane(64)][8], n = (tt>>1)*384 + jb*32 + (tt&1)*16 + (lane&15)
__global__ void pack_gates_k(int mode, const float* __restrict__ W1, const float* __restrict__ W2,
                             int nks){
  bf16* out = (mode==0)? g_Bp0 : g_Bpd;
  size_t idx = (size_t)blockIdx.x*256 + threadIdx.x;
  size_t total = (size_t)12*nks*512;
  if(idx >= total) return;
  int lane = (int)(idx & 63);
  int tt   = (int)((idx>>6) & 7);
  size_t tmp = idx >> 9;
  int ks = (int)(tmp % nks);
  int jb = (int)(tmp / nks);
  int n  = (tt>>1)*HID + jb*32 + (tt&1)*16 + (lane&15);
  int kb = ks*32 + (lane>>4)*8;
  bf16x8 v;
  #pragma unroll
  for(int i=0;i<8;i++){
    int k = kb + i;
    float f;
    if(mode==0) f = (k<384) ? W1[(size_t)n*384 + k] : (k<392 ? W2[(size_t)n*8 + (k-384)] : 0.f);
    else        f = (k<384) ? W1[(size_t)n*384 + k] : W2[(size_t)n*384 + (k-384)];
    v[i] = (bf16)f;
  }
  *(bf16x8*)(out + idx*8) = v;
}

// enc L1 pack: out[jn(24)][ks(24)][g(4)][lane(64)][8], n = g*384 + jn*16 + (lane&15)
__global__ void pack_gates16_k(const float* __restrict__ Wih1, const float* __restrict__ Whh1){
  int idx = blockIdx.x*256 + threadIdx.x;
  if(idx >= 24*24*4*64) return;
  int lane = idx&63, rem = idx>>6;
  int g = rem&3; rem >>= 2;
  int ks = rem%24, jn = rem/24;
  int n  = g*HID + jn*16 + (lane&15);
  int kb = ks*32 + (lane>>4)*8;
  bf16x8 v;
  #pragma unroll
  for(int i=0;i<8;i++){
    int k = kb+i;
    float f = (k<384)? Wih1[(size_t)n*384 + k] : Whh1[(size_t)n*384 + (k-384)];
    v[i] = (bf16)f;
  }
  *(bf16x8*)(g_Bp1n + (size_t)idx*8) = v;
}

// plain pack: out[nb][ks][tt(8)][lane][8], n = nb*128 + tt*16 + (lane&15)
__global__ void pack_plain_k(int mode, const float* __restrict__ W, int nks, int nb_cnt){
  bf16* out = mode ? g_Bpu : g_Bpi;
  size_t idx = (size_t)blockIdx.x*256 + threadIdx.x;
  size_t total = (size_t)nb_cnt*nks*512;
  if(idx>=total) return;
  int lane = (int)(idx&63);
  int tt   = (int)((idx>>6)&7);
  size_t tmp = idx>>9;
  int ks = (int)(tmp%nks);
  int nb = (int)(tmp/nks);
  int n  = nb*128 + tt*16 + (lane&15);
  int kb = ks*32 + (lane>>4)*8;
  bf16x8 v;
  #pragma unroll
  for(int i=0;i<8;i++){
    int k = kb+i;
    float f;
    if(mode==0) f = (k<389)? W[(size_t)n*389 + k] : 0.f;
    else        f = W[(size_t)k*384 + n];
    v[i]=(bf16)f;
  }
  *(bf16x8*)(out + idx*8) = v;
}

__global__ void prep_misc_k(const float* bih0,const float* bhh0,const float* bih1,const float* bhh1,
                            const float* dbih,const float* dbhh,const float* dinb){
  int i = blockIdx.x*256 + threadIdx.x;
  if(i<1536){ g_bias0[i]=bih0[i]+bhh0[i]; g_bias1[i]=bih1[i]+bhh1[i]; g_biasd[i]=dbih[i]+dbhh[i]; }
  if(i<384) g_biasdin[i]=dinb[i];
}

// ---------------- dataflow spin (busy poll; relaxed agent atomics on flags only) ----------------
__device__ __forceinline__ void spin_ge(int* p, int tgt){
  while(__hip_atomic_load(p, __ATOMIC_RELAXED, __HIP_MEMORY_SCOPE_AGENT) < tgt){}
}

// ---------------- persistent 2-layer encoder (R9 protocol; c-state in registers) ----------------
__global__ __launch_bounds__(256,1)
void enc7_k(){
  extern __shared__ char lds[];
  const int bid = blockIdx.x, tid = threadIdx.x;
  const int lane = tid&63, wv = tid>>6;
  const int l15 = lane&15, lk = (lane>>4)*8;

  if(bid < 96){
    const int g = bid & 7, jb = bid >> 3;
    { const s16x8* src = (const s16x8*)(g_Bp0 + (size_t)jb*13*4096);
      s16x8* dst = (s16x8*)lds;
      #pragma unroll
      for(int h=0;h<26;h++) dst[tid + h*256] = src[tid + h*256];
    }
    bf16* tr = (bf16*)(lds + 13*8192);        // [128][32] bf16
    __syncthreads();
    const int jj0 = jb*32 + l15;
    float bia[2],bfa[2],bga[2],boa[2];
    #pragma unroll
    for(int jh=0;jh<2;jh++){
      bia[jh]=g_bias0[jj0+jh*16];     bfa[jh]=g_bias0[384+jj0+jh*16];
      bga[jh]=g_bias0[768+jj0+jh*16]; boa[jh]=g_bias0[1152+jj0+jh*16];
    }
    size_t hoff[2], xoff[2];
    #pragma unroll
    for(int mt=0;mt<2;mt++){
      int row = g*128 + wv*32 + mt*16 + l15;
      hoff[mt] = (size_t)row*HID + lk;
      xoff[mt] = (size_t)row*LSEQ*8;
    }
    float c[2][2][4] = {};
    for(int w=0; w<LSEQ; w++){
      if(tid==0 && w>=1) spin_ge(&g_f0[g*LSEQ + (w-1)], 12);
      __syncthreads();
      asm volatile("" ::: "memory");
      const bf16* H0w = g_H0 + (size_t)w*NB*HID;
      bf16x8 af[13][2];
      #pragma unroll
      for(int ks=0;ks<12;ks++)
        #pragma unroll
        for(int mt=0;mt<2;mt++)
          af[ks][mt] = *(const bf16x8*)(H0w + hoff[mt] + ks*32);
      #pragma unroll
      for(int mt=0;mt<2;mt++){
        bf16x8 z;
        #pragma unroll
        for(int e=0;e<8;e++) z[e]=(bf16)0.f;
        if(lk==0) z = *(const bf16x8*)(g_xb + xoff[mt] + (size_t)w*8);
        af[12][mt] = z;
      }
      f32x4 acc[2][8];
      #pragma unroll
      for(int m2=0;m2<2;m2++)
        #pragma unroll
        for(int tt=0;tt<8;tt++) acc[m2][tt] = (f32x4){0.f,0.f,0.f,0.f};
      #pragma unroll
      for(int ks=0;ks<13;ks++){
        #pragma unroll
        for(int tt=0;tt<8;tt++){
          bf16x8 bfr = *(const bf16x8*)(lds + (ks*8+tt)*1024 + lane*16);
          acc[0][tt] = __builtin_amdgcn_mfma_f32_16x16x32_bf16(af[ks][0], bfr, acc[0][tt],0,0,0);
          acc[1][tt] = __builtin_amdgcn_mfma_f32_16x16x32_bf16(af[ks][1], bfr, acc[1][tt],0,0,0);
        }
      }
      #pragma unroll
      for(int mt=0;mt<2;mt++)
        #pragma unroll
        for(int jh=0;jh<2;jh++)
          #pragma unroll
          for(int r=0;r<4;r++){
            float zi=acc[mt][0+jh][r]+bia[jh], zf=acc[mt][2+jh][r]+bfa[jh],
                  zg=acc[mt][4+jh][r]+bga[jh], zo=acc[mt][6+jh][r]+boa[jh];
            float cn = sigf(zf)*c[mt][jh][r] + sigf(zi)*tanh_f(zg);
            c[mt][jh][r]=cn;
            int lr = wv*32 + mt*16 + (lane>>4)*4 + r;
            tr[lr*32 + jh*16 + l15] = (bf16)(sigf(zo)*tanh_f(cn));
          }
      __syncthreads();
      bf16* H0n = g_H0 + (size_t)(w+1)*NB*HID;
      #pragma unroll
      for(int h=0;h<2;h++){
        int p = tid + h*256;
        int row = p>>2, cc = p&3;
        s16x8 v = *(const s16x8*)(tr + row*32 + cc*8);
        ds16(H0n + (size_t)(g*128+row)*HID + jb*32 + cc*8, v);
      }
      __syncthreads();   // drains vmcnt: atomic stores are at MALL before flag
      if(tid==0)
        __hip_atomic_fetch_add(&g_f0[g*LSEQ + w], 1, __ATOMIC_RELAXED, __HIP_MEMORY_SCOPE_AGENT);
    }
  } else {
    const int idx = bid-96, m = idx & 3, jn = idx >> 2;
    { const s16x8* src = (const s16x8*)(g_Bp1n + (size_t)jn*24*2048);
      s16x8* dst = (s16x8*)lds;
      #pragma unroll
      for(int h=0;h<24;h++) dst[tid + h*256] = src[tid + h*256];
    }
    bf16* tr = (bf16*)(lds + 24*4096);        // [256][16] bf16
    __syncthreads();
    const int jj = jn*16 + l15;
    const float bi=g_bias1[jj], bff=g_bias1[384+jj], bg=g_bias1[768+jj], bo=g_bias1[1152+jj];
    int rows[4]; size_t hoff[4];
    #pragma unroll
    for(int mt=0;mt<4;mt++){
      rows[mt] = m*256 + wv*64 + mt*16 + l15;
      hoff[mt] = (size_t)rows[mt]*HID + lk;
    }
    float c[4][4] = {};
    for(int s=1; s<=LSEQ; s++){
      if(tid==0)           spin_ge(&g_f0[(2*m)*LSEQ + (s-1)], 12);
      else if(tid==1)      spin_ge(&g_f0[(2*m+1)*LSEQ + (s-1)], 12);
      else if(tid==2 && s>=2) spin_ge(&g_f1[m*(LSEQ+1) + (s-1)], 24);
      __syncthreads();
      asm volatile("" ::: "memory");
      const bf16* H0s = g_H0 + (size_t)s*NB*HID;          // h0[t=s-1]
      const size_t strideE = (s>=2)? (size_t)LSEQ*HID : 0;
      const bf16* Es = (s>=2)? (g_enc + (size_t)(s-2)*HID) : g_zero;  // h1[t=s-2]
      size_t eoff[4];
      #pragma unroll
      for(int mt=0;mt<4;mt++) eoff[mt] = (size_t)rows[mt]*strideE + lk;
      bf16x8 ap[8][4];
      #pragma unroll
      for(int d=0; d<8; d++)
        #pragma unroll
        for(int mt=0;mt<4;mt++)
          ap[d][mt] = *(const bf16x8*)(H0s + hoff[mt] + d*32);
      f32x4 acc[4][4];
      #pragma unroll
      for(int mt=0;mt<4;mt++)
        #pragma unroll
        for(int g4=0;g4<4;g4++) acc[mt][g4] = (f32x4){0.f,0.f,0.f,0.f};
      #pragma unroll
      for(int ks=0;ks<24;ks++){
        bf16x8 bfr[4];
        #pragma unroll
        for(int g4=0;g4<4;g4++) bfr[g4] = *(const bf16x8*)(lds + (ks*4+g4)*1024 + lane*16);
        bf16x8 a[4];
        #pragma unroll
        for(int mt=0;mt<4;mt++) a[mt] = ap[ks&7][mt];
        int kn = ks+8;
        if(kn<24){
          if(kn<12){
            #pragma unroll
            for(int mt=0;mt<4;mt++) ap[ks&7][mt] = *(const bf16x8*)(H0s + hoff[mt] + kn*32);
          } else {
            #pragma unroll
            for(int mt=0;mt<4;mt++) ap[ks&7][mt] = *(const bf16x8*)(Es + eoff[mt] + (kn-12)*32);
          }
        }
        #pragma unroll
        for(int mt=0;mt<4;mt++)
          #pragma unroll
          for(int g4=0;g4<4;g4++)
            acc[mt][g4] = __builtin_amdgcn_mfma_f32_16x16x32_bf16(a[mt], bfr[g4], acc[mt][g4],0,0,0);
      }
      #pragma unroll
      for(int mt=0;mt<4;mt++)
        #pragma unroll
        for(int r=0;r<4;r++){
          float zi=acc[mt][0][r]+bi, zf=acc[mt][1][r]+bff,
                zg=acc[mt][2][r]+bg, zo=acc[mt][3][r]+bo;
          float cn = sigf(zf)*c[mt][r] + sigf(zi)*tanh_f(zg);
          c[mt][r]=cn;
          int lr = wv*64 + mt*16 + (lane>>4)*4 + r;
          tr[lr*16 + l15] = (bf16)(sigf(zo)*tanh_f(cn));
        }
      __syncthreads();
      const int t = s-1;
      #pragma unroll
      for(int h=0;h<2;h++){
        int p = tid + h*256;
        int row = p>>1, hf2 = p&1;
        s16x8 v = *(const s16x8*)(tr + row*16 + hf2*8);
        ds16(g_enc + ((size_t)(m*256+row)*LSEQ + t)*HID + jn*16 + hf2*8, v);
      }
      __syncthreads();   // drains vmcnt before flag
      if(tid==0)
        __hip_atomic_fetch_add(&g_f1[m*(LSEQ+1) + s], 1, __ATOMIC_RELAXED, __HIP_MEMORY_SCOPE_AGENT);
    }
  }
}

// ---------------- GEMM core (decoder) ----------------
struct SReg { s16x8 a0,a1,b0,b1; };

__device__ __forceinline__ void stage_load(const bf16* __restrict__ A, int ldA,
                                           const bf16* __restrict__ Bk, int tid, SReg& sr){
  int c0 = tid, c1 = tid+256;
  sr.a0 = *(const s16x8*)(A + (size_t)(c0>>2)*ldA + (c0&3)*8);
  sr.a1 = *(const s16x8*)(A + (size_t)(c1>>2)*ldA + (c1&3)*8);
  const s16x8* B8 = (const s16x8*)Bk;
  sr.b0 = B8[c0]; sr.b1 = B8[c1];
}

__device__ __forceinline__ void stage_write(char* Ab, char* Bb, int tid, const SReg& sr){
  int c0 = tid, c1 = tid+256;
  *(s16x8*)(Ab + (c0>>2)*80 + (c0&3)*16) = sr.a0;
  *(s16x8*)(Ab + (c1>>2)*80 + (c1&3)*16) = sr.a1;
  *(s16x8*)(Bb + c0*16) = sr.b0;
  *(s16x8*)(Bb + c1*16) = sr.b1;
}

__device__ __forceinline__ void gemm_core(const bf16* __restrict__ A, int ldA,
                                          const bf16* __restrict__ Bp, int nks,
                                          char* smem, f32x4 acc[4][4]){
  const int tid = threadIdx.x;
  const int lane = tid & 63, wv = tid>>6, wm = wv>>1, wn = wv&1;
  char* Ab0 = smem;            char* Ab1 = smem + 10240;
  char* Bb0 = smem + 20480;    char* Bb1 = smem + 28672;
  f32x4 z = {0.f,0.f,0.f,0.f};
  #pragma unroll
  for(int m=0;m<4;m++)
    #pragma unroll
    for(int g=0;g<4;g++) acc[m][g]=z;
  SReg sr;
  stage_load(A, ldA, Bp, tid, sr);
  stage_write(Ab0, Bb0, tid, sr);
  const int aoff = (wm*64 + (lane&15))*80 + (lane>>4)*16;
  const int boff = wn*1024 + lane*16;
  for(int ks=0; ks<nks; ks++){
    char* Ac = (ks&1)? Ab1: Ab0;
    char* Bc = (ks&1)? Bb1: Bb0;
    char* An = (ks&1)? Ab0: Ab1;
    char* Bn = (ks&1)? Bb0: Bb1;
    bool more = (ks+1)<nks;
    if(more) stage_load(A + (ks+1)*32, ldA, Bp + (size_t)(ks+1)*4096, tid, sr);
    __syncthreads();
    bf16x8 af[4], bfr[4];
    #pragma unroll
    for(int mt=0;mt<4;mt++) af[mt] = *(const bf16x8*)(Ac + aoff + mt*16*80);
    #pragma unroll
    for(int g=0;g<4;g++)    bfr[g] = *(const bf16x8*)(Bc + boff + g*2048);
    #pragma unroll
    for(int mt=0;mt<4;mt++)
      #pragma unroll
      for(int g=0;g<4;g++)
        acc[mt][g] = __builtin_amdgcn_mfma_f32_16x16x32_bf16(af[mt], bfr[g], acc[mt][g], 0,0,0);
    if(more) stage_write(An, Bn, tid, sr);
  }
}

// ---------------- LSTM epilogue (decoder) ----------------
__device__ __forceinline__ void lstm_epi(f32x4 acc[4][4], int mbase, int jb,
     const float* __restrict__ bias, float* __restrict__ cst,
     bf16* __restrict__ d0, int ld0, bf16* __restrict__ d1, size_t ld1){
  int lane = threadIdx.x&63, wv = threadIdx.x>>6, wm = wv>>1, wn = wv&1;
  int j = jb*32 + wn*16 + (lane&15);
  float bi = bias[j], bff = bias[384+j], bg = bias[768+j], bo = bias[1152+j];
  #pragma unroll
  for(int mt=0;mt<4;mt++){
    #pragma unroll
    for(int r=0;r<4;r++){
      int brow = mbase + wm*64 + mt*16 + (lane>>4)*4 + r;
      float zi = acc[mt][0][r]+bi, zf = acc[mt][1][r]+bff,
            zg = acc[mt][2][r]+bg, zo = acc[mt][3][r]+bo;
      size_t ci = (size_t)brow*HID + j;
      float cold = cst[ci];
      float cn = sigf(zf)*cold + sigf(zi)*tanh_f(zg);
      cst[ci] = cn;
      bf16 hb = (bf16)(sigf(zo)*tanh_f(cn));
      d0[(size_t)brow*ld0 + j] = hb;
      if(d1) d1[(size_t)brow*ld1 + j] = hb;
    }
  }
}

// ---------------- decoder LSTM ----------------
__global__ __launch_bounds__(256)
void dec_lstm_k(int t){
  __shared__ char smem[SMEM_BYTES];
  int bid = blockIdx.x, mb = bid/12, jb = bid%12;
  int rs = t&1, wsl = rs^1;
  f32x4 acc[4][4];
  gemm_core(g_Adec + (size_t)rs*NB*768 + (size_t)mb*128*768, 768,
            g_Bpd + (size_t)jb*24*4096, 24, smem, acc);
  lstm_epi(acc, mb*128, jb, g_biasd, g_cdec,
           g_Adec + (size_t)wsl*NB*768 + 384, 768, (bf16*)nullptr, 0);
}

// ---------------- plain GEMM: mode 1 = u-proj (+fused post for t-1), mode 0 = dec_in relu ----------------
__global__ __launch_bounds__(256)
void plain_gemm_k(int t, int mode, const float* __restrict__ outW,
                  const float* __restrict__ outb, float* __restrict__ out,
                  const float* __restrict__ ff){
  __shared__ char smem[SMEM_BYTES];
  int bid = blockIdx.x, mb = bid/3, nb = bid%3;
  int rs = t&1;
  const bf16* A; int ldA, nks; const bf16* Bp;
  if(mode==1){ A = g_Adec + (size_t)rs*NB*768 + 384; ldA=768; Bp = g_Bpu; nks=12; }
  else       { A = g_Adin;                           ldA=416; Bp = g_Bpi; nks=13; }
  f32x4 acc[4][4];
  gemm_core(A + (size_t)mb*128*ldA, ldA, Bp + (size_t)nb*nks*4096, nks, smem, acc);
  int lane = threadIdx.x&63, wv = threadIdx.x>>6, wm = wv>>1, wn = wv&1;
  bf16* dbf = g_Adec + (size_t)rs*NB*768;
  #pragma unroll
  for(int mt=0;mt<4;mt++){
    #pragma unroll
    for(int ti=0;ti<4;ti++){
      int n = nb*128 + (ti*2+wn)*16 + (lane&15);
      #pragma unroll
      for(int r=0;r<4;r++){
        int brow = mb*128 + wm*64 + mt*16 + (lane>>4)*4 + r;
        float v = acc[mt][ti][r];
        if(mode==0){ v += g_biasdin[n]; v = fmaxf(v,0.f); dbf[(size_t)brow*768 + n] = (bf16)v; }
        else g_u[(size_t)brow*384 + n] = v;
      }
    }
  }
  // fused post for step t-1 (h slot rs == (t-1 parity)^1): nb==0 blocks, 128 rows each
  if(mode==1 && t>=1 && nb==0 && threadIdx.x<128){
    int b = mb*128 + threadIdx.x;
    const s16x8* hp = (const s16x8*)(g_Adec + (size_t)rs*NB*768 + (size_t)b*768 + 384);
    float acc2 = 0.f;
    #pragma unroll 4
    for(int i=0;i<48;i++){
      s16x8 v = hp[i];
      #pragma unroll
      for(int e=0;e<8;e++){
        float hv = __uint_as_float(((u32)(uint16_t)v[e])<<16);
        acc2 += hv*outW[i*8+e];
      }
    }
    float y = acc2 + outb[0];
    out[(size_t)b*HOR + (t-1)] = y;
    g_Adin[(size_t)b*416] = (bf16)y;
    #pragma unroll
    for(int k=0;k<4;k++) g_Adin[(size_t)b*416 + 1 + k] = (bf16)ff[(size_t)b*HOR*4 + t*4 + k];
  }
}

// ---------------- attention: fused scores+softmax+ctx (online, LRU-friendly alternating sweep) ----------------
__global__ __launch_bounds__(256)
void attn_k(int t){
  __shared__ float sm[4][392];
  int tid = threadIdx.x, lane = tid&63, w = tid>>6;
  int bl = w>>1, hf = w&1;
  int b = blockIdx.x*2 + bl;
  const float* ub = g_u + (size_t)b*HID + lane*6;
  float u0=ub[0],u1=ub[1],u2=ub[2],u3=ub[3],u4=ub[4],u5=ub[5];
  const u32* er = (const u32*)(g_enc + (size_t)b*LSEQ*HID) + (size_t)hf*168*192 + lane*3;
  int estep = 192;
  if(t & 1){ er += (size_t)167*192; estep = -192; }   // odd steps sweep backwards (L3 LRU)
  float m=-1e30f, den=0.f, a0=0,a1=0,a2=0,a3=0,a4=0,a5=0;
  for(int l=0;l<168;l++){
    u32 w0 = er[0], w1 = er[1], w2 = er[2];
    er += estep;
    float e0 = __uint_as_float(w0<<16);
    float e1 = __uint_as_float(w0 & 0xffff0000u);
    float e2 = __uint_as_float(w1<<16);
    float e3 = __uint_as_float(w1 & 0xffff0000u);
    float e4 = __uint_as_float(w2<<16);
    float e5 = __uint_as_float(w2 & 0xffff0000u);
    float p = e0*u0 + e1*u1 + e2*u2 + e3*u3 + e4*u4 + e5*u5;
    #pragma unroll
    for(int o=1;o<64;o<<=1) p += __shfl_xor(p, o, 64);
    float mn = fmaxf(m, p);
    float al = __expf(m - mn), pe = __expf(p - mn);
    den = den*al + pe;
    a0 = a0*al + pe*e0; a1 = a1*al + pe*e1; a2 = a2*al + pe*e2;
    a3 = a3*al + pe*e3; a4 = a4*al + pe*e4; a5 = a5*al + pe*e5;
    m = mn;
  }
  if(lane==0){ sm[w][0]=m; sm[w][1]=den; }
  sm[w][2+lane*6+0]=a0; sm[w][2+lane*6+1]=a1; sm[w][2+lane*6+2]=a2;
  sm[w][2+lane*6+3]=a3; sm[w][2+lane*6+4]=a4; sm[w][2+lane*6+5]=a5;
  __syncthreads();
  if(hf==0){
    float m2 = sm[w+1][0], d2 = sm[w+1][1];
    float M = fmaxf(m, m2);
    float f1 = __expf(m - M), f2 = __expf(m2 - M);
    float inv = 1.f/(den*f1 + d2*f2);
    bf16* cd = g_Adin + (size_t)b*416 + 5 + lane*6;
    cd[0] = (bf16)((a0*f1 + sm[w+1][2+lane*6+0]*f2)*inv);
    cd[1] = (bf16)((a1*f1 + sm[w+1][2+lane*6+1]*f2)*inv);
    cd[2] = (bf16)((a2*f1 + sm[w+1][2+lane*6+2]*f2)*inv);
    cd[3] = (bf16)((a3*f1 + sm[w+1][2+lane*6+3]*f2)*inv);
    cd[4] = (bf16)((a4*f1 + sm[w+1][2+lane*6+4]*f2)*inv);
    cd[5] = (bf16)((a5*f1 + sm[w+1][2+lane*6+5]*f2)*inv);
  }
}

// ---------------- output head (final step only; earlier steps fused into plain_gemm) ----------------
__global__ void post_k(int t, const float* __restrict__ outW,
                       const float* __restrict__ outb, float* __restrict__ out){
  int b = blockIdx.x*256 + threadIdx.x;
  if(b>=NB) return;
  int wsl = (t&1)^1;
  const s16x8* hp = (const s16x8*)(g_Adec + (size_t)wsl*NB*768 + (size_t)b*768 + 384);
  float acc = 0.f;
  #pragma unroll 4
  for(int i=0;i<48;i++){
    s16x8 v = hp[i];
    #pragma unroll
    for(int e=0;e<8;e++){
      float hv = __uint_as_float(((u32)(uint16_t)v[e])<<16);
      acc += hv*outW[i*8+e];
    }
  }
  out[(size_t)b*HOR + t] = acc + outb[0];
}

// ---------------- decoder init ----------------
__global__ void dec_prep_k(const float* __restrict__ ff){
  int i = blockIdx.x*256 + threadIdx.x;
  if(i < NB*HID){
    int b = i/HID, j = i%HID;
    g_Adec[(size_t)b*768 + 384 + j] = g_enc[(size_t)b*LSEQ*HID + (size_t)(LSEQ-1)*HID + j];
  }
  if(i < NB*4){
    int b = i>>2, k = i&3;
    g_Adin[(size_t)b*416 + 1 + k] = (bf16)ff[(size_t)b*HOR*4 + k];
  }
  if(i < NB) g_Adin[(size_t)i*416] = (bf16)0.f;
}

extern "C" void kernel_launch(void* const* d_in, const int* in_sizes, int n_in,
                              void* d_out, int out_size, void* d_ws, size_t ws_size,
                              hipStream_t stream){
  const float* x    = (const float*)d_in[0];
  const float* ff   = (const float*)d_in[1];
  const float* Wih0 = (const float*)d_in[2];
  const float* Whh0 = (const float*)d_in[3];
  const float* bih0 = (const float*)d_in[4];
  const float* bhh0 = (const float*)d_in[5];
  const float* Wih1 = (const float*)d_in[6];
  const float* Whh1 = (const float*)d_in[7];
  const float* bih1 = (const float*)d_in[8];
  const float* bhh1 = (const float*)d_in[9];
  const float* Wa   = (const float*)d_in[10];
  const float* dinW = (const float*)d_in[11];
  const float* dinb = (const float*)d_in[12];
  const float* dWih = (const float*)d_in[13];
  const float* dWhh = (const float*)d_in[14];
  const float* dbih = (const float*)d_in[15];
  const float* dbhh = (const float*)d_in[16];
  const float* outW = (const float*)d_in[17];
  const float* outb = (const float*)d_in[18];
  float* out = (float*)d_out;

  zero_state_k<<<1024,256,0,stream>>>();
  pack_xb_k<<<2048,256,0,stream>>>(x);
  pack_gates_k<<<(12*13*512)/256,256,0,stream>>>(0, Whh0, Wih0, 13);
  pack_gates16_k<<<576,256,0,stream>>>(Wih1, Whh1);
  pack_gates_k<<<(12*24*512)/256,256,0,stream>>>(2, dWih, dWhh, 24);
  pack_plain_k<<<(3*13*512)/256,256,0,stream>>>(0, dinW, 13, 3);
  pack_plain_k<<<(3*12*512)/256,256,0,stream>>>(1, Wa, 12, 3);
  prep_misc_k<<<8,256,0,stream>>>(bih0,bhh0,bih1,bhh1,dbih,dbhh,dinb);

  hipFuncSetAttribute((const void*)enc7_k,
                      hipFuncAttributeMaxDynamicSharedMemorySize, 114688);
  enc7_k<<<192,256,114688,stream>>>();

  dec_prep_k<<<1536,256,0,stream>>>(ff);
  for(int t=0;t<HOR;t++){
    plain_gemm_k<<<24,256,0,stream>>>(t, 1, outW, outb, out, ff);
    attn_k<<<512,256,0,stream>>>(t);
    plain_gemm_k<<<24,256,0,stream>>>(t, 0, outW, outb, out, ff);
    dec_lstm_k<<<96,256,0,stream>>>(t);
  }
  post_k<<<4,256,0,stream>>>(17, outW, outb, out);
  (void)in_sizes; (void)n_in; (void)out_size; (void)d_ws; (void)ws_size;
}

// Round 12
// 7944.070 us; speedup vs baseline: 1.6307x; 1.0576x over previous
//
#include <hip/hip_runtime.h>
#include <stdint.h>

typedef __bf16 bf16;
typedef __bf16 bf16x8 __attribute__((ext_vector_type(8)));
typedef short  s16x8  __attribute__((ext_vector_type(8)));
typedef float  f32x4  __attribute__((ext_vector_type(4)));
typedef uint32_t u32;

#define NB   1024
#define LSEQ 336
#define HID  384
#define HOR  18
#define SMEM_BYTES 36864
#define E1T  ((size_t)24*NB*16)   // 393216 elems per g_E1 slot

// ---------------- device-global scratch ----------------
__device__ bf16  g_H0[(size_t)(LSEQ+1)*NB*HID];  // 265 MB: h0 chain; slot w+1 = h0(w); slot0 zeroed
__device__ bf16  g_E1[(size_t)(LSEQ+1)*E1T];     // 265 MB: h1 chain; slot t+1 = h1(t), [slot][jn][row][16]
__device__ bf16  g_enc[(size_t)NB*LSEQ*HID];     // 264 MB, [B][L][H] (decoder input)
__device__ bf16  g_Adec[2*NB*768];    // [2][1024][768]: din | h_dec
__device__ bf16  g_Adin[NB*416];      // [1024][416]: y | feat4 | ctx384 | pad
__device__ bf16  g_xb[NB*LSEQ*8];     // bf16 x
__device__ float g_cdec[NB*HID];
__device__ float g_u[NB*HID];
__device__ float g_bias0[1536], g_bias1[1536], g_biasd[1536], g_biasdin[384];
__device__ bf16  g_Bp0[12*13*4096];         // enc L0 pack (32-col jb granularity)
__device__ bf16  g_Bp1n[24*24*4*64*8];      // enc L1 pack (16-col jn granularity)
__device__ bf16  g_Bpd[12*24*4096];
__device__ bf16  g_Bpi[3*13*4096];
__device__ bf16  g_Bpu[3*12*4096];
__device__ int   g_f0[8*LSEQ];        // [g][w]: L0 group g finished window w (target 12)
__device__ int   g_f1[4*(LSEQ+1)];    // [m][s]: L1 group m finished step s (target 24)

__device__ __forceinline__ float sigf(float x){ return 1.0f/(1.0f + __expf(-x)); }
__device__ __forceinline__ float tanh_f(float x){
  x = fminf(fmaxf(x, -15.f), 15.f);
  float e = __expf(2.f*x);
  return (e - 1.f)/(e + 1.f);
}

// ---------------- per-call state zeroing (replay determinism) ----------------
__global__ void zero_state_k(){
  int i = blockIdx.x*blockDim.x + threadIdx.x;
  int st = gridDim.x*blockDim.x;
  bf16 z = (bf16)0.f;
  for(int k=i;k<NB*HID;k+=st){ g_H0[k]=z; g_E1[k]=z; g_cdec[k]=0.f; }  // E1T == NB*HID
  for(int k=i;k<8*LSEQ;k+=st) g_f0[k]=0;
  for(int k=i;k<4*(LSEQ+1);k+=st) g_f1[k]=0;
}

__global__ void pack_xb_k(const float* __restrict__ x){
  int i = blockIdx.x*256 + threadIdx.x;
  int n = NB*LSEQ*8;
  for(int k=i; k<n; k+=gridDim.x*256) g_xb[k] = (bf16)x[k];
}

// ---------------- weight packs ----------------
__global__ void pack_gates_k(int mode, const float* __restrict__ W1, const float* __restrict__ W2,
                             int nks){
  bf16* out = (mode==0)? g_Bp0 : g_Bpd;
  size_t idx = (size_t)blockIdx.x*256 + threadIdx.x;
  size_t total = (size_t)12*nks*512;
  if(idx >= total) return;
  int lane = (int)(idx & 63);
  int tt   = (int)((idx>>6) & 7);
  size_t tmp = idx >> 9;
  int ks = (int)(tmp % nks);
  int jb = (int)(tmp / nks);
  int n  = (tt>>1)*HID + jb*32 + (tt&1)*16 + (lane&15);
  int kb = ks*32 + (lane>>4)*8;
  bf16x8 v;
  #pragma unroll
  for(int i=0;i<8;i++){
    int k = kb + i;
    float f;
    if(mode==0) f = (k<384) ? W1[(size_t)n*384 + k] : (k<392 ? W2[(size_t)n*8 + (k-384)] : 0.f);
    else        f = (k<384) ? W1[(size_t)n*384 + k] : W2[(size_t)n*384 + (k-384)];
    v[i] = (bf16)f;
  }
  *(bf16x8*)(out + idx*8) = v;
}

__global__ void pack_gates16_k(const float* __restrict__ Wih1, const float* __restrict__ Whh1){
  int idx = blockIdx.x*256 + threadIdx.x;
  if(idx >= 24*24*4*64) return;
  int lane = idx&63, rem = idx>>6;
  int g = rem&3; rem >>= 2;
  int ks = rem%24, jn = rem/24;
  int n  = g*HID + jn*16 + (lane&15);
  int kb = ks*32 + (lane>>4)*8;
  bf16x8 v;
  #pragma unroll
  for(int i=0;i<8;i++){
    int k = kb+i;
    float f = (k<384)? Wih1[(size_t)n*384 + k] : Whh1[(size_t)n*384 + (k-384)];
    v[i] = (bf16)f;
  }
  *(bf16x8*)(g_Bp1n + (size_t)idx*8) = v;
}

__global__ void pack_plain_k(int mode, const float* __restrict__ W, int nks, int nb_cnt){
  bf16* out = mode ? g_Bpu : g_Bpi;
  size_t idx = (size_t)blockIdx.x*256 + threadIdx.x;
  size_t total = (size_t)nb_cnt*nks*512;
  if(idx>=total) return;
  int lane = (int)(idx&63);
  int tt   = (int)((idx>>6)&7);
  size_t tmp = idx>>9;
  int ks = (int)(tmp%nks);
  int nb = (int)(tmp/nks);
  int n  = nb*128 + tt*16 + (lane&15);
  int kb = ks*32 + (lane>>4)*8;
  bf16x8 v;
  #pragma unroll
  for(int i=0;i<8;i++){
    int k = kb+i;
    float f;
    if(mode==0) f = (k<389)? W[(size_t)n*389 + k] : 0.f;
    else        f = W[(size_t)k*384 + n];
    v[i]=(bf16)f;
  }
  *(bf16x8*)(out + idx*8) = v;
}

__global__ void prep_misc_k(const float* bih0,const float* bhh0,const float* bih1,const float* bhh1,
                            const float* dbih,const float* dbhh,const float* dinb){
  int i = blockIdx.x*256 + threadIdx.x;
  if(i<1536){ g_bias0[i]=bih0[i]+bhh0[i]; g_bias1[i]=bih1[i]+bhh1[i]; g_biasd[i]=dbih[i]+dbhh[i]; }
  if(i<384) g_biasdin[i]=dinb[i];
}

// ---------------- dataflow spin (busy poll; relaxed agent atomics on flags only) ----------------
__device__ __forceinline__ void spin_ge(int* p, int tgt){
  while(__hip_atomic_load(p, __ATOMIC_RELAXED, __HIP_MEMORY_SCOPE_AGENT) < tgt){}
}
// Release: writeback (no invalidate) so prior plain stores are MALL-visible, then callers flag.
__device__ __forceinline__ void release_agent(){
  __builtin_amdgcn_fence(__ATOMIC_RELEASE, "agent");
}

// ---------------- persistent 2-layer encoder v3: plain-store exchange + release fence ----------------
// All h buffers are full chains (fresh addresses) and line/region-exclusive per block:
//   h0: g_H0[w+1], 64B per row per jb-block.  h1: g_E1[t+1][jn][1024][16] block regions.
//   g_enc written by even-jn blocks in 32-col (full 64B line) strips from g_E1[s-1].
// Producers: plain stores -> syncthreads (vmcnt drain) -> tid0 release fence (wbl2) -> MALL flag.
// Consumers: poll flag, plain loads at fresh-chain addresses (miss -> MALL / dirty-L2 hit).
__global__ __launch_bounds__(256,1)
void enc8_k(){
  extern __shared__ char lds[];
  const int bid = blockIdx.x, tid = threadIdx.x;
  const int lane = tid&63, wv = tid>>6;
  const int l15 = lane&15, lk = (lane>>4)*8;

  if(bid < 96){
    const int g = bid & 7, jb = bid >> 3;
    { const s16x8* src = (const s16x8*)(g_Bp0 + (size_t)jb*13*4096);
      s16x8* dst = (s16x8*)lds;
      #pragma unroll
      for(int h=0;h<26;h++) dst[tid + h*256] = src[tid + h*256];
    }
    bf16* tr = (bf16*)(lds + 13*8192);        // [128][32] bf16
    __syncthreads();
    const int jj0 = jb*32 + l15;
    float bia[2],bfa[2],bga[2],boa[2];
    #pragma unroll
    for(int jh=0;jh<2;jh++){
      bia[jh]=g_bias0[jj0+jh*16];     bfa[jh]=g_bias0[384+jj0+jh*16];
      bga[jh]=g_bias0[768+jj0+jh*16]; boa[jh]=g_bias0[1152+jj0+jh*16];
    }
    size_t hoff[2], xoff[2];
    #pragma unroll
    for(int mt=0;mt<2;mt++){
      int row = g*128 + wv*32 + mt*16 + l15;
      hoff[mt] = (size_t)row*HID + lk;
      xoff[mt] = (size_t)row*LSEQ*8;
    }
    float c[2][2][4] = {};
    for(int w=0; w<LSEQ; w++){
      if(tid==0 && w>=1) spin_ge(&g_f0[g*LSEQ + (w-1)], 12);
      __syncthreads();
      asm volatile("" ::: "memory");
      const bf16* H0w = g_H0 + (size_t)w*NB*HID;
      bf16x8 af[13][2];
      #pragma unroll
      for(int ks=0;ks<12;ks++)
        #pragma unroll
        for(int mt=0;mt<2;mt++)
          af[ks][mt] = *(const bf16x8*)(H0w + hoff[mt] + ks*32);
      #pragma unroll
      for(int mt=0;mt<2;mt++){
        bf16x8 z;
        #pragma unroll
        for(int e=0;e<8;e++) z[e]=(bf16)0.f;
        if(lk==0) z = *(const bf16x8*)(g_xb + xoff[mt] + (size_t)w*8);
        af[12][mt] = z;
      }
      f32x4 acc[2][8];
      #pragma unroll
      for(int m2=0;m2<2;m2++)
        #pragma unroll
        for(int tt=0;tt<8;tt++) acc[m2][tt] = (f32x4){0.f,0.f,0.f,0.f};
      #pragma unroll
      for(int ks=0;ks<13;ks++){
        #pragma unroll
        for(int tt=0;tt<8;tt++){
          bf16x8 bfr = *(const bf16x8*)(lds + (ks*8+tt)*1024 + lane*16);
          acc[0][tt] = __builtin_amdgcn_mfma_f32_16x16x32_bf16(af[ks][0], bfr, acc[0][tt],0,0,0);
          acc[1][tt] = __builtin_amdgcn_mfma_f32_16x16x32_bf16(af[ks][1], bfr, acc[1][tt],0,0,0);
        }
      }
      #pragma unroll
      for(int mt=0;mt<2;mt++)
        #pragma unroll
        for(int jh=0;jh<2;jh++)
          #pragma unroll
          for(int r=0;r<4;r++){
            float zi=acc[mt][0+jh][r]+bia[jh], zf=acc[mt][2+jh][r]+bfa[jh],
                  zg=acc[mt][4+jh][r]+bga[jh], zo=acc[mt][6+jh][r]+boa[jh];
            float cn = sigf(zf)*c[mt][jh][r] + sigf(zi)*tanh_f(zg);
            c[mt][jh][r]=cn;
            int lr = wv*32 + mt*16 + (lane>>4)*4 + r;
            tr[lr*32 + jh*16 + l15] = (bf16)(sigf(zo)*tanh_f(cn));
          }
      __syncthreads();
      bf16* H0n = g_H0 + (size_t)(w+1)*NB*HID;
      #pragma unroll
      for(int h=0;h<2;h++){
        int p = tid + h*256;
        int row = p>>2, cc = p&3;
        s16x8 v = *(const s16x8*)(tr + row*32 + cc*8);
        *(s16x8*)(H0n + (size_t)(g*128+row)*HID + jb*32 + cc*8) = v;   // plain; 64B-line exclusive
      }
      __syncthreads();   // vmcnt drained (stores in L2)
      if(tid==0){
        release_agent();  // wbl2: dirty lines -> MALL
        __hip_atomic_fetch_add(&g_f0[g*LSEQ + w], 1, __ATOMIC_RELAXED, __HIP_MEMORY_SCOPE_AGENT);
      }
    }
  } else {
    const int idx = bid-96, m = idx & 3, jn = idx >> 2;
    { const s16x8* src = (const s16x8*)(g_Bp1n + (size_t)jn*24*2048);
      s16x8* dst = (s16x8*)lds;
      #pragma unroll
      for(int h=0;h<24;h++) dst[tid + h*256] = src[tid + h*256];
    }
    bf16* tr = (bf16*)(lds + 24*4096);        // [256][16] bf16
    __syncthreads();
    const int jj = jn*16 + l15;
    const float bi=g_bias1[jj], bff=g_bias1[384+jj], bg=g_bias1[768+jj], bo=g_bias1[1152+jj];
    int rows[4]; size_t hoff[4], eo[4];
    const int jn_half = (lane>>4)>>1, colin = ((lane>>4)&1)*8;
    #pragma unroll
    for(int mt=0;mt<4;mt++){
      rows[mt] = m*256 + wv*64 + mt*16 + l15;
      hoff[mt] = (size_t)rows[mt]*HID + lk;
      eo[mt]   = (size_t)jn_half*(NB*16) + (size_t)rows[mt]*16 + colin;
    }
    float c[4][4] = {};
    for(int s=1; s<=LSEQ; s++){
      if(tid==0)      spin_ge(&g_f0[(2*m)*LSEQ + (s-1)], 12);
      else if(tid==1) spin_ge(&g_f0[(2*m+1)*LSEQ + (s-1)], 12);
      __syncthreads();
      asm volatile("" ::: "memory");
      const bf16* H0s = g_H0 + (size_t)s*NB*HID;          // h0(s-1)
      const bf16* Es  = g_E1 + (size_t)(s-1)*E1T;         // h1(s-2); slot0 = zeros
      bf16x8 ap[8][4];
      #pragma unroll
      for(int d=0; d<8; d++)
        #pragma unroll
        for(int mt=0;mt<4;mt++)
          ap[d][mt] = *(const bf16x8*)(H0s + hoff[mt] + d*32);   // h0 frags (f0-gated)
      if(tid==0 && s>=2) spin_ge(&g_f1[m*(LSEQ+1) + (s-1)], 24); // overlap with h0 loads
      __syncthreads();
      asm volatile("" ::: "memory");
      f32x4 acc[4][4];
      #pragma unroll
      for(int mt=0;mt<4;mt++)
        #pragma unroll
        for(int g4=0;g4<4;g4++) acc[mt][g4] = (f32x4){0.f,0.f,0.f,0.f};
      #pragma unroll
      for(int ks=0;ks<24;ks++){
        bf16x8 bfr[4];
        #pragma unroll
        for(int g4=0;g4<4;g4++) bfr[g4] = *(const bf16x8*)(lds + (ks*4+g4)*1024 + lane*16);
        bf16x8 a[4];
        #pragma unroll
        for(int mt=0;mt<4;mt++) a[mt] = ap[ks&7][mt];
        int kn = ks+8;
        if(kn<24){
          if(kn<12){
            #pragma unroll
            for(int mt=0;mt<4;mt++) ap[ks&7][mt] = *(const bf16x8*)(H0s + hoff[mt] + kn*32);
          } else {
            #pragma unroll
            for(int mt=0;mt<4;mt++) ap[ks&7][mt] = *(const bf16x8*)(Es + (size_t)(kn-12)*32768 + eo[mt]);
          }
        }
        #pragma unroll
        for(int mt=0;mt<4;mt++)
          #pragma unroll
          for(int g4=0;g4<4;g4++)
            acc[mt][g4] = __builtin_amdgcn_mfma_f32_16x16x32_bf16(a[mt], bfr[g4], acc[mt][g4],0,0,0);
      }
      #pragma unroll
      for(int mt=0;mt<4;mt++)
        #pragma unroll
        for(int r=0;r<4;r++){
          float zi=acc[mt][0][r]+bi, zf=acc[mt][1][r]+bff,
                zg=acc[mt][2][r]+bg, zo=acc[mt][3][r]+bo;
          float cn = sigf(zf)*c[mt][r] + sigf(zi)*tanh_f(zg);
          c[mt][r]=cn;
          int lr = wv*64 + mt*16 + (lane>>4)*4 + r;
          tr[lr*16 + l15] = (bf16)(sigf(zo)*tanh_f(cn));
        }
      __syncthreads();
      // (a) h1 -> g_E1 slot s, block-exclusive region (plain stores)
      bf16* E1w = g_E1 + (size_t)s*E1T + (size_t)jn*(NB*16);
      #pragma unroll
      for(int h=0;h<2;h++){
        int p = tid + h*256;
        int row = p>>1, hf2 = p&1;
        s16x8 v = *(const s16x8*)(tr + row*16 + hf2*8);
        *(s16x8*)(E1w + (size_t)(m*256+row)*16 + hf2*8) = v;
      }
      // (b) even-jn blocks write g_enc[t=s-2] 32-col strip from g_E1[s-1] (f1-gated)
      if((jn&1)==0 && s>=2){
        const int t_out = s-2;
        const bf16* Ep = g_E1 + (size_t)(s-1)*E1T;
        #pragma unroll
        for(int h=0;h<4;h++){
          int cch = tid + h*256;        // 1024 chunks: row(256) x seg(4 x 16B)
          int row = cch>>2, seg = cch&3;
          const bf16* srcp = Ep + (size_t)(jn + (seg>>1))*(NB*16) + (size_t)(m*256+row)*16 + (seg&1)*8;
          s16x8 v = *(const s16x8*)srcp;
          *(s16x8*)(g_enc + ((size_t)(m*256+row)*LSEQ + t_out)*HID + jn*16 + seg*8) = v;
        }
      }
      __syncthreads();   // vmcnt drained
      if(tid==0){
        release_agent();
        __hip_atomic_fetch_add(&g_f1[m*(LSEQ+1) + s], 1, __ATOMIC_RELAXED, __HIP_MEMORY_SCOPE_AGENT);
      }
    }
    // tail: g_enc[t=335] from g_E1[336]
    if(tid==0) spin_ge(&g_f1[m*(LSEQ+1) + LSEQ], 24);
    __syncthreads();
    asm volatile("" ::: "memory");
    if((jn&1)==0){
      const bf16* Ep = g_E1 + (size_t)LSEQ*E1T;
      #pragma unroll
      for(int h=0;h<4;h++){
        int cch = tid + h*256;
        int row = cch>>2, seg = cch&3;
        const bf16* srcp = Ep + (size_t)(jn + (seg>>1))*(NB*16) + (size_t)(m*256+row)*16 + (seg&1)*8;
        s16x8 v = *(const s16x8*)srcp;
        *(s16x8*)(g_enc + ((size_t)(m*256+row)*LSEQ + (LSEQ-1))*HID + jn*16 + seg*8) = v;
      }
    }
  }
}

// ---------------- GEMM core (decoder) ----------------
struct SReg { s16x8 a0,a1,b0,b1; };

__device__ __forceinline__ void stage_load(const bf16* __restrict__ A, int ldA,
                                           const bf16* __restrict__ Bk, int tid, SReg& sr){
  int c0 = tid, c1 = tid+256;
  sr.a0 = *(const s16x8*)(A + (size_t)(c0>>2)*ldA + (c0&3)*8);
  sr.a1 = *(const s16x8*)(A + (size_t)(c1>>2)*ldA + (c1&3)*8);
  const s16x8* B8 = (const s16x8*)Bk;
  sr.b0 = B8[c0]; sr.b1 = B8[c1];
}

__device__ __forceinline__ void stage_write(char* Ab, char* Bb, int tid, const SReg& sr){
  int c0 = tid, c1 = tid+256;
  *(s16x8*)(Ab + (c0>>2)*80 + (c0&3)*16) = sr.a0;
  *(s16x8*)(Ab + (c1>>2)*80 + (c1&3)*16) = sr.a1;
  *(s16x8*)(Bb + c0*16) = sr.b0;
  *(s16x8*)(Bb + c1*16) = sr.b1;
}

__device__ __forceinline__ void gemm_core(const bf16* __restrict__ A, int ldA,
                                          const bf16* __restrict__ Bp, int nks,
                                          char* smem, f32x4 acc[4][4]){
  const int tid = threadIdx.x;
  const int lane = tid & 63, wv = tid>>6, wm = wv>>1, wn = wv&1;
  char* Ab0 = smem;            char* Ab1 = smem + 10240;
  char* Bb0 = smem + 20480;    char* Bb1 = smem + 28672;
  f32x4 z = {0.f,0.f,0.f,0.f};
  #pragma unroll
  for(int m=0;m<4;m++)
    #pragma unroll
    for(int g=0;g<4;g++) acc[m][g]=z;
  SReg sr;
  stage_load(A, ldA, Bp, tid, sr);
  stage_write(Ab0, Bb0, tid, sr);
  const int aoff = (wm*64 + (lane&15))*80 + (lane>>4)*16;
  const int boff = wn*1024 + lane*16;
  for(int ks=0; ks<nks; ks++){
    char* Ac = (ks&1)? Ab1: Ab0;
    char* Bc = (ks&1)? Bb1: Bb0;
    char* An = (ks&1)? Ab0: Ab1;
    char* Bn = (ks&1)? Bb0: Bb1;
    bool more = (ks+1)<nks;
    if(more) stage_load(A + (ks+1)*32, ldA, Bp + (size_t)(ks+1)*4096, tid, sr);
    __syncthreads();
    bf16x8 af[4], bfr[4];
    #pragma unroll
    for(int mt=0;mt<4;mt++) af[mt] = *(const bf16x8*)(Ac + aoff + mt*16*80);
    #pragma unroll
    for(int g=0;g<4;g++)    bfr[g] = *(const bf16x8*)(Bc + boff + g*2048);
    #pragma unroll
    for(int mt=0;mt<4;mt++)
      #pragma unroll
      for(int g=0;g<4;g++)
        acc[mt][g] = __builtin_amdgcn_mfma_f32_16x16x32_bf16(af[mt], bfr[g], acc[mt][g], 0,0,0);
    if(more) stage_write(An, Bn, tid, sr);
  }
}

// ---------------- LSTM epilogue (decoder) ----------------
__device__ __forceinline__ void lstm_epi(f32x4 acc[4][4], int mbase, int jb,
     const float* __restrict__ bias, float* __restrict__ cst,
     bf16* __restrict__ d0, int ld0, bf16* __restrict__ d1, size_t ld1){
  int lane = threadIdx.x&63, wv = threadIdx.x>>6, wm = wv>>1, wn = wv&1;
  int j = jb*32 + wn*16 + (lane&15);
  float bi = bias[j], bff = bias[384+j], bg = bias[768+j], bo = bias[1152+j];
  #pragma unroll
  for(int mt=0;mt<4;mt++){
    #pragma unroll
    for(int r=0;r<4;r++){
      int brow = mbase + wm*64 + mt*16 + (lane>>4)*4 + r;
      float zi = acc[mt][0][r]+bi, zf = acc[mt][1][r]+bff,
            zg = acc[mt][2][r]+bg, zo = acc[mt][3][r]+bo;
      size_t ci = (size_t)brow*HID + j;
      float cold = cst[ci];
      float cn = sigf(zf)*cold + sigf(zi)*tanh_f(zg);
      cst[ci] = cn;
      bf16 hb = (bf16)(sigf(zo)*tanh_f(cn));
      d0[(size_t)brow*ld0 + j] = hb;
      if(d1) d1[(size_t)brow*ld1 + j] = hb;
    }
  }
}

// ---------------- decoder LSTM ----------------
__global__ __launch_bounds__(256)
void dec_lstm_k(int t){
  __shared__ char smem[SMEM_BYTES];
  int bid = blockIdx.x, mb = bid/12, jb = bid%12;
  int rs = t&1, wsl = rs^1;
  f32x4 acc[4][4];
  gemm_core(g_Adec + (size_t)rs*NB*768 + (size_t)mb*128*768, 768,
            g_Bpd + (size_t)jb*24*4096, 24, smem, acc);
  lstm_epi(acc, mb*128, jb, g_biasd, g_cdec,
           g_Adec + (size_t)wsl*NB*768 + 384, 768, (bf16*)nullptr, 0);
}

// ---------------- plain GEMM: mode 1 = u-proj (+fused post for t-1), mode 0 = dec_in relu ----------------
__global__ __launch_bounds__(256)
void plain_gemm_k(int t, int mode, const float* __restrict__ outW,
                  const float* __restrict__ outb, float* __restrict__ out,
                  const float* __restrict__ ff){
  __shared__ char smem[SMEM_BYTES];
  int bid = blockIdx.x, mb = bid/3, nb = bid%3;
  int rs = t&1;
  const bf16* A; int ldA, nks; const bf16* Bp;
  if(mode==1){ A = g_Adec + (size_t)rs*NB*768 + 384; ldA=768; Bp = g_Bpu; nks=12; }
  else       { A = g_Adin;                           ldA=416; Bp = g_Bpi; nks=13; }
  f32x4 acc[4][4];
  gemm_core(A + (size_t)mb*128*ldA, ldA, Bp + (size_t)nb*nks*4096, nks, smem, acc);
  int lane = threadIdx.x&63, wv = threadIdx.x>>6, wm = wv>>1, wn = wv&1;
  bf16* dbf = g_Adec + (size_t)rs*NB*768;
  #pragma unroll
  for(int mt=0;mt<4;mt++){
    #pragma unroll
    for(int ti=0;ti<4;ti++){
      int n = nb*128 + (ti*2+wn)*16 + (lane&15);
      #pragma unroll
      for(int r=0;r<4;r++){
        int brow = mb*128 + wm*64 + mt*16 + (lane>>4)*4 + r;
        float v = acc[mt][ti][r];
        if(mode==0){ v += g_biasdin[n]; v = fmaxf(v,0.f); dbf[(size_t)brow*768 + n] = (bf16)v; }
        else g_u[(size_t)brow*384 + n] = v;
      }
    }
  }
  if(mode==1 && t>=1 && nb==0 && threadIdx.x<128){
    int b = mb*128 + threadIdx.x;
    const s16x8* hp = (const s16x8*)(g_Adec + (size_t)rs*NB*768 + (size_t)b*768 + 384);
    float acc2 = 0.f;
    #pragma unroll 4
    for(int i=0;i<48;i++){
      s16x8 v = hp[i];
      #pragma unroll
      for(int e=0;e<8;e++){
        float hv = __uint_as_float(((u32)(uint16_t)v[e])<<16);
        acc2 += hv*outW[i*8+e];
      }
    }
    float y = acc2 + outb[0];
    out[(size_t)b*HOR + (t-1)] = y;
    g_Adin[(size_t)b*416] = (bf16)y;
    #pragma unroll
    for(int k=0;k<4;k++) g_Adin[(size_t)b*416 + 1 + k] = (bf16)ff[(size_t)b*HOR*4 + t*4 + k];
  }
}

// ---------------- attention: fused scores+softmax+ctx (online, alternating sweep) ----------------
__global__ __launch_bounds__(256)
void attn_k(int t){
  __shared__ float sm[4][392];
  int tid = threadIdx.x, lane = tid&63, w = tid>>6;
  int bl = w>>1, hf = w&1;
  int b = blockIdx.x*2 + bl;
  const float* ub = g_u + (size_t)b*HID + lane*6;
  float u0=ub[0],u1=ub[1],u2=ub[2],u3=ub[3],u4=ub[4],u5=ub[5];
  const u32* er = (const u32*)(g_enc + (size_t)b*LSEQ*HID) + (size_t)hf*168*192 + lane*3;
  int estep = 192;
  if(t & 1){ er += (size_t)167*192; estep = -192; }
  float m=-1e30f, den=0.f, a0=0,a1=0,a2=0,a3=0,a4=0,a5=0;
  for(int l=0;l<168;l++){
    u32 w0 = er[0], w1 = er[1], w2 = er[2];
    er += estep;
    float e0 = __uint_as_float(w0<<16);
    float e1 = __uint_as_float(w0 & 0xffff0000u);
    float e2 = __uint_as_float(w1<<16);
    float e3 = __uint_as_float(w1 & 0xffff0000u);
    float e4 = __uint_as_float(w2<<16);
    float e5 = __uint_as_float(w2 & 0xffff0000u);
    float p = e0*u0 + e1*u1 + e2*u2 + e3*u3 + e4*u4 + e5*u5;
    #pragma unroll
    for(int o=1;o<64;o<<=1) p += __shfl_xor(p, o, 64);
    float mn = fmaxf(m, p);
    float al = __expf(m - mn), pe = __expf(p - mn);
    den = den*al + pe;
    a0 = a0*al + pe*e0; a1 = a1*al + pe*e1; a2 = a2*al + pe*e2;
    a3 = a3*al + pe*e3; a4 = a4*al + pe*e4; a5 = a5*al + pe*e5;
    m = mn;
  }
  if(lane==0){ sm[w][0]=m; sm[w][1]=den; }
  sm[w][2+lane*6+0]=a0; sm[w][2+lane*6+1]=a1; sm[w][2+lane*6+2]=a2;
  sm[w][2+lane*6+3]=a3; sm[w][2+lane*6+4]=a4; sm[w][2+lane*6+5]=a5;
  __syncthreads();
  if(hf==0){
    float m2 = sm[w+1][0], d2 = sm[w+1][1];
    float M = fmaxf(m, m2);
    float f1 = __expf(m - M), f2 = __expf(m2 - M);
    float inv = 1.f/(den*f1 + d2*f2);
    bf16* cd = g_Adin + (size_t)b*416 + 5 + lane*6;
    cd[0] = (bf16)((a0*f1 + sm[w+1][2+lane*6+0]*f2)*inv);
    cd[1] = (bf16)((a1*f1 + sm[w+1][2+lane*6+1]*f2)*inv);
    cd[2] = (bf16)((a2*f1 + sm[w+1][2+lane*6+2]*f2)*inv);
    cd[3] = (bf16)((a3*f1 + sm[w+1][2+lane*6+3]*f2)*inv);
    cd[4] = (bf16)((a4*f1 + sm[w+1][2+lane*6+4]*f2)*inv);
    cd[5] = (bf16)((a5*f1 + sm[w+1][2+lane*6+5]*f2)*inv);
  }
}

// ---------------- output head (final step only) ----------------
__global__ void post_k(int t, const float* __restrict__ outW,
                       const float* __restrict__ outb, float* __restrict__ out){
  int b = blockIdx.x*256 + threadIdx.x;
  if(b>=NB) return;
  int wsl = (t&1)^1;
  const s16x8* hp = (const s16x8*)(g_Adec + (size_t)wsl*NB*768 + (size_t)b*768 + 384);
  float acc = 0.f;
  #pragma unroll 4
  for(int i=0;i<48;i++){
    s16x8 v = hp[i];
    #pragma unroll
    for(int e=0;e<8;e++){
      float hv = __uint_as_float(((u32)(uint16_t)v[e])<<16);
      acc += hv*outW[i*8+e];
    }
  }
  out[(size_t)b*HOR + t] = acc + outb[0];
}

// ---------------- decoder init ----------------
__global__ void dec_prep_k(const float* __restrict__ ff){
  int i = blockIdx.x*256 + threadIdx.x;
  if(i < NB*HID){
    int b = i/HID, j = i%HID;
    g_Adec[(size_t)b*768 + 384 + j] = g_enc[(size_t)b*LSEQ*HID + (size_t)(LSEQ-1)*HID + j];
  }
  if(i < NB*4){
    int b = i>>2, k = i&3;
    g_Adin[(size_t)b*416 + 1 + k] = (bf16)ff[(size_t)b*HOR*4 + k];
  }
  if(i < NB) g_Adin[(size_t)i*416] = (bf16)0.f;
}

extern "C" void kernel_launch(void* const* d_in, const int* in_sizes, int n_in,
                              void* d_out, int out_size, void* d_ws, size_t ws_size,
                              hipStream_t stream){
  const float* x    = (const float*)d_in[0];
  const float* ff   = (const float*)d_in[1];
  const float* Wih0 = (const float*)d_in[2];
  const float* Whh0 = (const float*)d_in[3];
  const float* bih0 = (const float*)d_in[4];
  const float* bhh0 = (const float*)d_in[5];
  const float* Wih1 = (const float*)d_in[6];
  const float* Whh1 = (const float*)d_in[7];
  const float* bih1 = (const float*)d_in[8];
  const float* bhh1 = (const float*)d_in[9];
  const float* Wa   = (const float*)d_in[10];
  const float* dinW = (const float*)d_in[11];
  const float* dinb = (const float*)d_in[12];
  const float* dWih = (const float*)d_in[13];
  const float* dWhh = (const float*)d_in[14];
  const float* dbih = (const float*)d_in[15];
  const float* dbhh = (const float*)d_in[16];
  const float* outW = (const float*)d_in[17];
  const float* outb = (const float*)d_in[18];
  float* out = (float*)d_out;

  zero_state_k<<<1024,256,0,stream>>>();
  pack_xb_k<<<2048,256,0,stream>>>(x);
  pack_gates_k<<<(12*13*512)/256,256,0,stream>>>(0, Whh0, Wih0, 13);
  pack_gates16_k<<<576,256,0,stream>>>(Wih1, Whh1);
  pack_gates_k<<<(12*24*512)/256,256,0,stream>>>(2, dWih, dWhh, 24);
  pack_plain_k<<<(3*13*512)/256,256,0,stream>>>(0, dinW, 13, 3);
  pack_plain_k<<<(3*12*512)/256,256,0,stream>>>(1, Wa, 12, 3);
  prep_misc_k<<<8,256,0,stream>>>(bih0,bhh0,bih1,bhh1,dbih,dbhh,dinb);

  hipFuncSetAttribute((const void*)enc8_k,
                      hipFuncAttributeMaxDynamicSharedMemorySize, 114688);
  enc8_k<<<192,256,114688,stream>>>();

  dec_prep_k<<<1536,256,0,stream>>>(ff);
  for(int t=0;t<HOR;t++){
    plain_gemm_k<<<24,256,0,stream>>>(t, 1, outW, outb, out, ff);
    attn_k<<<512,256,0,stream>>>(t);
    plain_gemm_k<<<24,256,0,stream>>>(t, 0, outW, outb, out, ff);
    dec_lstm_k<<<96,256,0,stream>>>(t);
  }
  post_k<<<4,256,0,stream>>>(17, outW, outb, out);
  (void)in_sizes; (void)n_in; (void)out_size; (void)d_ws; (void)ws_size;
}

// Round 13
// 7580.357 us; speedup vs baseline: 1.7089x; 1.0480x over previous
//
#include <hip/hip_runtime.h>
#include <stdint.h>

typedef __bf16 bf16;
typedef __bf16 bf16x8 __attribute__((ext_vector_type(8)));
typedef short  s16x8  __attribute__((ext_vector_type(8)));
typedef float  f32x4  __attribute__((ext_vector_type(4)));
typedef uint32_t u32;

#define NB   1024
#define LSEQ 336
#define HID  384
#define HOR  18
#define SMEM_BYTES 36864
#define E1T  ((size_t)24*NB*16)   // 393216 elems per g_E1 slot

// ---------------- device-global scratch ----------------
__device__ bf16  g_H0[(size_t)(LSEQ+1)*NB*HID];  // 265 MB: h0 chain; slot w+1 = h0(w); slot0 zeroed
__device__ bf16  g_E1[(size_t)(LSEQ+1)*E1T];     // 265 MB: h1 chain; slot t+1 = h1(t), [slot][jn][row][16]
__device__ bf16  g_enc[(size_t)NB*LSEQ*HID];     // 264 MB, [B][L][H] (decoder input)
__device__ bf16  g_Adec[2*NB*768];    // [2][1024][768]: din | h_dec
__device__ bf16  g_Adin[NB*416];      // [1024][416]: y | feat4 | ctx384 | pad
__device__ bf16  g_xb[NB*LSEQ*8];     // bf16 x
__device__ float g_cdec[NB*HID];
__device__ float g_u[NB*HID];
__device__ float g_bias0[1536], g_bias1[1536], g_biasd[1536], g_biasdin[384];
__device__ bf16  g_Bp0[12*13*4096];         // enc L0 pack (32-col jb granularity)
__device__ bf16  g_Bp1n[24*24*4*64*8];      // enc L1 pack (16-col jn granularity)
__device__ bf16  g_Bpd[12*24*4096];
__device__ bf16  g_Bpi[3*13*4096];
__device__ bf16  g_Bpu[3*12*4096];
// flags: one 64B line per (group, generation); mirror splits reader populations
__device__ int   g_f0 [8*LSEQ*16];       // L0 siblings poll this
__device__ int   g_f0m[8*LSEQ*16];       // L1 blocks poll this (mirror)
__device__ int   g_f1 [4*(LSEQ+1)*16];

__device__ __forceinline__ float sigf(float x){ return 1.0f/(1.0f + __expf(-x)); }
__device__ __forceinline__ float tanh_f(float x){
  x = fminf(fmaxf(x, -15.f), 15.f);
  float e = __expf(2.f*x);
  return (e - 1.f)/(e + 1.f);
}

// ---------------- per-call state zeroing (replay determinism) ----------------
__global__ void zero_state_k(){
  int i = blockIdx.x*blockDim.x + threadIdx.x;
  int st = gridDim.x*blockDim.x;
  bf16 z = (bf16)0.f;
  for(int k=i;k<NB*HID;k+=st){ g_H0[k]=z; g_E1[k]=z; g_cdec[k]=0.f; }  // slot 0 of chains
  for(int k=i;k<8*LSEQ*16;k+=st){ g_f0[k]=0; g_f0m[k]=0; }
  for(int k=i;k<4*(LSEQ+1)*16;k+=st) g_f1[k]=0;
}

__global__ void pack_xb_k(const float* __restrict__ x){
  int i = blockIdx.x*256 + threadIdx.x;
  int n = NB*LSEQ*8;
  for(int k=i; k<n; k+=gridDim.x*256) g_xb[k] = (bf16)x[k];
}

// ---------------- weight packs ----------------
__global__ void pack_gates_k(int mode, const float* __restrict__ W1, const float* __restrict__ W2,
                             int nks){
  bf16* out = (mode==0)? g_Bp0 : g_Bpd;
  size_t idx = (size_t)blockIdx.x*256 + threadIdx.x;
  size_t total = (size_t)12*nks*512;
  if(idx >= total) return;
  int lane = (int)(idx & 63);
  int tt   = (int)((idx>>6) & 7);
  size_t tmp = idx >> 9;
  int ks = (int)(tmp % nks);
  int jb = (int)(tmp / nks);
  int n  = (tt>>1)*HID + jb*32 + (tt&1)*16 + (lane&15);
  int kb = ks*32 + (lane>>4)*8;
  bf16x8 v;
  #pragma unroll
  for(int i=0;i<8;i++){
    int k = kb + i;
    float f;
    if(mode==0) f = (k<384) ? W1[(size_t)n*384 + k] : (k<392 ? W2[(size_t)n*8 + (k-384)] : 0.f);
    else        f = (k<384) ? W1[(size_t)n*384 + k] : W2[(size_t)n*384 + (k-384)];
    v[i] = (bf16)f;
  }
  *(bf16x8*)(out + idx*8) = v;
}

__global__ void pack_gates16_k(const float* __restrict__ Wih1, const float* __restrict__ Whh1){
  int idx = blockIdx.x*256 + threadIdx.x;
  if(idx >= 24*24*4*64) return;
  int lane = idx&63, rem = idx>>6;
  int g = rem&3; rem >>= 2;
  int ks = rem%24, jn = rem/24;
  int n  = g*HID + jn*16 + (lane&15);
  int kb = ks*32 + (lane>>4)*8;
  bf16x8 v;
  #pragma unroll
  for(int i=0;i<8;i++){
    int k = kb+i;
    float f = (k<384)? Wih1[(size_t)n*384 + k] : Whh1[(size_t)n*384 + (k-384)];
    v[i] = (bf16)f;
  }
  *(bf16x8*)(g_Bp1n + (size_t)idx*8) = v;
}

__global__ void pack_plain_k(int mode, const float* __restrict__ W, int nks, int nb_cnt){
  bf16* out = mode ? g_Bpu : g_Bpi;
  size_t idx = (size_t)blockIdx.x*256 + threadIdx.x;
  size_t total = (size_t)nb_cnt*nks*512;
  if(idx>=total) return;
  int lane = (int)(idx&63);
  int tt   = (int)((idx>>6)&7);
  size_t tmp = idx>>9;
  int ks = (int)(tmp%nks);
  int nb = (int)(tmp/nks);
  int n  = nb*128 + tt*16 + (lane&15);
  int kb = ks*32 + (lane>>4)*8;
  bf16x8 v;
  #pragma unroll
  for(int i=0;i<8;i++){
    int k = kb+i;
    float f;
    if(mode==0) f = (k<389)? W[(size_t)n*389 + k] : 0.f;
    else        f = W[(size_t)k*384 + n];
    v[i]=(bf16)f;
  }
  *(bf16x8*)(out + idx*8) = v;
}

__global__ void prep_misc_k(const float* bih0,const float* bhh0,const float* bih1,const float* bhh1,
                            const float* dbih,const float* dbhh,const float* dinb){
  int i = blockIdx.x*256 + threadIdx.x;
  if(i<1536){ g_bias0[i]=bih0[i]+bhh0[i]; g_bias1[i]=bih1[i]+bhh1[i]; g_biasd[i]=dbih[i]+dbhh[i]; }
  if(i<384) g_biasdin[i]=dinb[i];
}

// ---------------- dataflow spin (busy poll; relaxed agent atomics on flags only) ----------------
__device__ __forceinline__ void spin_ge(int* p, int tgt){
  while(__hip_atomic_load(p, __ATOMIC_RELAXED, __HIP_MEMORY_SCOPE_AGENT) < tgt){}
}
__device__ __forceinline__ void release_agent(){
  __builtin_amdgcn_fence(__ATOMIC_RELEASE, "agent");
}

// ---------------- persistent 2-layer encoder v4: line-isolated flags, split pollers ----------------
__global__ __launch_bounds__(256,1)
void enc9_k(){
  extern __shared__ char lds[];
  const int bid = blockIdx.x, tid = threadIdx.x;
  const int lane = tid&63, wv = tid>>6;
  const int l15 = lane&15, lk = (lane>>4)*8;

  if(bid < 96){
    const int g = bid & 7, jb = bid >> 3;
    { const s16x8* src = (const s16x8*)(g_Bp0 + (size_t)jb*13*4096);
      s16x8* dst = (s16x8*)lds;
      #pragma unroll
      for(int h=0;h<26;h++) dst[tid + h*256] = src[tid + h*256];
    }
    bf16* tr = (bf16*)(lds + 13*8192);        // [128][32] bf16
    __syncthreads();
    const int jj0 = jb*32 + l15;
    float bia[2],bfa[2],bga[2],boa[2];
    #pragma unroll
    for(int jh=0;jh<2;jh++){
      bia[jh]=g_bias0[jj0+jh*16];     bfa[jh]=g_bias0[384+jj0+jh*16];
      bga[jh]=g_bias0[768+jj0+jh*16]; boa[jh]=g_bias0[1152+jj0+jh*16];
    }
    size_t hoff[2], xoff[2];
    #pragma unroll
    for(int mt=0;mt<2;mt++){
      int row = g*128 + wv*32 + mt*16 + l15;
      hoff[mt] = (size_t)row*HID + lk;
      xoff[mt] = (size_t)row*LSEQ*8;
    }
    float c[2][2][4] = {};
    for(int w=0; w<LSEQ; w++){
      if(tid==0 && w>=1) spin_ge(&g_f0[(g*LSEQ + (w-1))*16], 12);
      __syncthreads();
      asm volatile("" ::: "memory");
      const bf16* H0w = g_H0 + (size_t)w*NB*HID;
      bf16x8 af[13][2];
      #pragma unroll
      for(int ks=0;ks<12;ks++)
        #pragma unroll
        for(int mt=0;mt<2;mt++)
          af[ks][mt] = *(const bf16x8*)(H0w + hoff[mt] + ks*32);
      #pragma unroll
      for(int mt=0;mt<2;mt++){
        bf16x8 z;
        #pragma unroll
        for(int e=0;e<8;e++) z[e]=(bf16)0.f;
        if(lk==0) z = *(const bf16x8*)(g_xb + xoff[mt] + (size_t)w*8);
        af[12][mt] = z;
      }
      f32x4 acc[2][8];
      #pragma unroll
      for(int m2=0;m2<2;m2++)
        #pragma unroll
        for(int tt=0;tt<8;tt++) acc[m2][tt] = (f32x4){0.f,0.f,0.f,0.f};
      #pragma unroll
      for(int ks=0;ks<13;ks++){
        #pragma unroll
        for(int tt=0;tt<8;tt++){
          bf16x8 bfr = *(const bf16x8*)(lds + (ks*8+tt)*1024 + lane*16);
          acc[0][tt] = __builtin_amdgcn_mfma_f32_16x16x32_bf16(af[ks][0], bfr, acc[0][tt],0,0,0);
          acc[1][tt] = __builtin_amdgcn_mfma_f32_16x16x32_bf16(af[ks][1], bfr, acc[1][tt],0,0,0);
        }
      }
      #pragma unroll
      for(int mt=0;mt<2;mt++)
        #pragma unroll
        for(int jh=0;jh<2;jh++)
          #pragma unroll
          for(int r=0;r<4;r++){
            float zi=acc[mt][0+jh][r]+bia[jh], zf=acc[mt][2+jh][r]+bfa[jh],
                  zg=acc[mt][4+jh][r]+bga[jh], zo=acc[mt][6+jh][r]+boa[jh];
            float cn = sigf(zf)*c[mt][jh][r] + sigf(zi)*tanh_f(zg);
            c[mt][jh][r]=cn;
            int lr = wv*32 + mt*16 + (lane>>4)*4 + r;
            tr[lr*32 + jh*16 + l15] = (bf16)(sigf(zo)*tanh_f(cn));
          }
      __syncthreads();
      bf16* H0n = g_H0 + (size_t)(w+1)*NB*HID;
      #pragma unroll
      for(int h=0;h<2;h++){
        int p = tid + h*256;
        int row = p>>2, cc = p&3;
        s16x8 v = *(const s16x8*)(tr + row*32 + cc*8);
        *(s16x8*)(H0n + (size_t)(g*128+row)*HID + jb*32 + cc*8) = v;   // plain; 64B-line exclusive
      }
      __syncthreads();   // vmcnt drained (stores in L2)
      if(tid==0){
        release_agent();  // wbl2: dirty lines -> MALL
        __hip_atomic_fetch_add(&g_f0 [(g*LSEQ + w)*16], 1, __ATOMIC_RELAXED, __HIP_MEMORY_SCOPE_AGENT);
        __hip_atomic_fetch_add(&g_f0m[(g*LSEQ + w)*16], 1, __ATOMIC_RELAXED, __HIP_MEMORY_SCOPE_AGENT);
      }
    }
  } else {
    const int idx = bid-96, m = idx & 3, jn = idx >> 2;
    { const s16x8* src = (const s16x8*)(g_Bp1n + (size_t)jn*24*2048);
      s16x8* dst = (s16x8*)lds;
      #pragma unroll
      for(int h=0;h<24;h++) dst[tid + h*256] = src[tid + h*256];
    }
    bf16* tr = (bf16*)(lds + 24*4096);        // [256][16] bf16
    __syncthreads();
    const int jj = jn*16 + l15;
    const float bi=g_bias1[jj], bff=g_bias1[384+jj], bg=g_bias1[768+jj], bo=g_bias1[1152+jj];
    int rows[4]; size_t hoff[4], eo[4];
    const int jn_half = (lane>>4)>>1, colin = ((lane>>4)&1)*8;
    #pragma unroll
    for(int mt=0;mt<4;mt++){
      rows[mt] = m*256 + wv*64 + mt*16 + l15;
      hoff[mt] = (size_t)rows[mt]*HID + lk;
      eo[mt]   = (size_t)jn_half*(NB*16) + (size_t)rows[mt]*16 + colin;
    }
    float c[4][4] = {};
    for(int s=1; s<=LSEQ; s++){
      if(tid==0)      spin_ge(&g_f0m[((2*m)*LSEQ + (s-1))*16], 12);
      else if(tid==1) spin_ge(&g_f0m[((2*m+1)*LSEQ + (s-1))*16], 12);
      __syncthreads();
      asm volatile("" ::: "memory");
      const bf16* H0s = g_H0 + (size_t)s*NB*HID;          // h0(s-1)
      const bf16* Es  = g_E1 + (size_t)(s-1)*E1T;         // h1(s-2); slot0 = zeros
      bf16x8 ap[8][4];
      #pragma unroll
      for(int d=0; d<8; d++)
        #pragma unroll
        for(int mt=0;mt<4;mt++)
          ap[d][mt] = *(const bf16x8*)(H0s + hoff[mt] + d*32);   // h0 frags (f0-gated)
      if(tid==0 && s>=2) spin_ge(&g_f1[(m*(LSEQ+1) + (s-1))*16], 24); // overlap with h0 loads
      __syncthreads();
      asm volatile("" ::: "memory");
      f32x4 acc[4][4];
      #pragma unroll
      for(int mt=0;mt<4;mt++)
        #pragma unroll
        for(int g4=0;g4<4;g4++) acc[mt][g4] = (f32x4){0.f,0.f,0.f,0.f};
      #pragma unroll
      for(int ks=0;ks<24;ks++){
        bf16x8 bfr[4];
        #pragma unroll
        for(int g4=0;g4<4;g4++) bfr[g4] = *(const bf16x8*)(lds + (ks*4+g4)*1024 + lane*16);
        bf16x8 a[4];
        #pragma unroll
        for(int mt=0;mt<4;mt++) a[mt] = ap[ks&7][mt];
        int kn = ks+8;
        if(kn<24){
          if(kn<12){
            #pragma unroll
            for(int mt=0;mt<4;mt++) ap[ks&7][mt] = *(const bf16x8*)(H0s + hoff[mt] + kn*32);
          } else {
            #pragma unroll
            for(int mt=0;mt<4;mt++) ap[ks&7][mt] = *(const bf16x8*)(Es + (size_t)(kn-12)*32768 + eo[mt]);
          }
        }
        #pragma unroll
        for(int mt=0;mt<4;mt++)
          #pragma unroll
          for(int g4=0;g4<4;g4++)
            acc[mt][g4] = __builtin_amdgcn_mfma_f32_16x16x32_bf16(a[mt], bfr[g4], acc[mt][g4],0,0,0);
      }
      #pragma unroll
      for(int mt=0;mt<4;mt++)
        #pragma unroll
        for(int r=0;r<4;r++){
          float zi=acc[mt][0][r]+bi, zf=acc[mt][1][r]+bff,
                zg=acc[mt][2][r]+bg, zo=acc[mt][3][r]+bo;
          float cn = sigf(zf)*c[mt][r] + sigf(zi)*tanh_f(zg);
          c[mt][r]=cn;
          int lr = wv*64 + mt*16 + (lane>>4)*4 + r;
          tr[lr*16 + l15] = (bf16)(sigf(zo)*tanh_f(cn));
        }
      __syncthreads();
      // h1 -> g_E1 slot s, block-exclusive region (plain stores)
      bf16* E1w = g_E1 + (size_t)s*E1T + (size_t)jn*(NB*16);
      #pragma unroll
      for(int h=0;h<2;h++){
        int p = tid + h*256;
        int row = p>>1, hf2 = p&1;
        s16x8 v = *(const s16x8*)(tr + row*16 + hf2*8);
        *(s16x8*)(E1w + (size_t)(m*256+row)*16 + hf2*8) = v;
      }
      __syncthreads();   // vmcnt drained
      if(tid==0){
        release_agent();
        __hip_atomic_fetch_add(&g_f1[(m*(LSEQ+1) + s)*16], 1, __ATOMIC_RELAXED, __HIP_MEMORY_SCOPE_AGENT);
      }
      // g_enc gather for t=s-2: OFF the critical path (after flag). Reads g_E1[s-1]
      // (f1-gated at iteration start); stores flushed by kernel-end writeback.
      if((jn&1)==0 && s>=2){
        const int t_out = s-2;
        const bf16* Ep = g_E1 + (size_t)(s-1)*E1T;
        #pragma unroll
        for(int h=0;h<4;h++){
          int cch = tid + h*256;        // 1024 chunks: row(256) x seg(4 x 16B)
          int row = cch>>2, seg = cch&3;
          const bf16* srcp = Ep + (size_t)(jn + (seg>>1))*(NB*16) + (size_t)(m*256+row)*16 + (seg&1)*8;
          s16x8 v = *(const s16x8*)srcp;
          *(s16x8*)(g_enc + ((size_t)(m*256+row)*LSEQ + t_out)*HID + jn*16 + seg*8) = v;
        }
      }
    }
    // tail: g_enc[t=334] handled by loop's s=336 iteration; t=335 from g_E1[336]
    if(tid==0) spin_ge(&g_f1[(m*(LSEQ+1) + LSEQ)*16], 24);
    __syncthreads();
    asm volatile("" ::: "memory");
    if((jn&1)==0){
      const bf16* Ep = g_E1 + (size_t)LSEQ*E1T;
      #pragma unroll
      for(int h=0;h<4;h++){
        int cch = tid + h*256;
        int row = cch>>2, seg = cch&3;
        const bf16* srcp = Ep + (size_t)(jn + (seg>>1))*(NB*16) + (size_t)(m*256+row)*16 + (seg&1)*8;
        s16x8 v = *(const s16x8*)srcp;
        *(s16x8*)(g_enc + ((size_t)(m*256+row)*LSEQ + (LSEQ-1))*HID + jn*16 + seg*8) = v;
      }
    }
  }
}

// ---------------- GEMM core (decoder) ----------------
struct SReg { s16x8 a0,a1,b0,b1; };

__device__ __forceinline__ void stage_load(const bf16* __restrict__ A, int ldA,
                                           const bf16* __restrict__ Bk, int tid, SReg& sr){
  int c0 = tid, c1 = tid+256;
  sr.a0 = *(const s16x8*)(A + (size_t)(c0>>2)*ldA + (c0&3)*8);
  sr.a1 = *(const s16x8*)(A + (size_t)(c1>>2)*ldA + (c1&3)*8);
  const s16x8* B8 = (const s16x8*)Bk;
  sr.b0 = B8[c0]; sr.b1 = B8[c1];
}

__device__ __forceinline__ void stage_write(char* Ab, char* Bb, int tid, const SReg& sr){
  int c0 = tid, c1 = tid+256;
  *(s16x8*)(Ab + (c0>>2)*80 + (c0&3)*16) = sr.a0;
  *(s16x8*)(Ab + (c1>>2)*80 + (c1&3)*16) = sr.a1;
  *(s16x8*)(Bb + c0*16) = sr.b0;
  *(s16x8*)(Bb + c1*16) = sr.b1;
}

__device__ __forceinline__ void gemm_core(const bf16* __restrict__ A, int ldA,
                                          const bf16* __restrict__ Bp, int nks,
                                          char* smem, f32x4 acc[4][4]){
  const int tid = threadIdx.x;
  const int lane = tid & 63, wv = tid>>6, wm = wv>>1, wn = wv&1;
  char* Ab0 = smem;            char* Ab1 = smem + 10240;
  char* Bb0 = smem + 20480;    char* Bb1 = smem + 28672;
  f32x4 z = {0.f,0.f,0.f,0.f};
  #pragma unroll
  for(int m=0;m<4;m++)
    #pragma unroll
    for(int g=0;g<4;g++) acc[m][g]=z;
  SReg sr;
  stage_load(A, ldA, Bp, tid, sr);
  stage_write(Ab0, Bb0, tid, sr);
  const int aoff = (wm*64 + (lane&15))*80 + (lane>>4)*16;
  const int boff = wn*1024 + lane*16;
  for(int ks=0; ks<nks; ks++){
    char* Ac = (ks&1)? Ab1: Ab0;
    char* Bc = (ks&1)? Bb1: Bb0;
    char* An = (ks&1)? Ab0: Ab1;
    char* Bn = (ks&1)? Bb0: Bb1;
    bool more = (ks+1)<nks;
    if(more) stage_load(A + (ks+1)*32, ldA, Bp + (size_t)(ks+1)*4096, tid, sr);
    __syncthreads();
    bf16x8 af[4], bfr[4];
    #pragma unroll
    for(int mt=0;mt<4;mt++) af[mt] = *(const bf16x8*)(Ac + aoff + mt*16*80);
    #pragma unroll
    for(int g=0;g<4;g++)    bfr[g] = *(const bf16x8*)(Bc + boff + g*2048);
    #pragma unroll
    for(int mt=0;mt<4;mt++)
      #pragma unroll
      for(int g=0;g<4;g++)
        acc[mt][g] = __builtin_amdgcn_mfma_f32_16x16x32_bf16(af[mt], bfr[g], acc[mt][g], 0,0,0);
    if(more) stage_write(An, Bn, tid, sr);
  }
}

// ---------------- LSTM epilogue (decoder) ----------------
__device__ __forceinline__ void lstm_epi(f32x4 acc[4][4], int mbase, int jb,
     const float* __restrict__ bias, float* __restrict__ cst,
     bf16* __restrict__ d0, int ld0, bf16* __restrict__ d1, size_t ld1){
  int lane = threadIdx.x&63, wv = threadIdx.x>>6, wm = wv>>1, wn = wv&1;
  int j = jb*32 + wn*16 + (lane&15);
  float bi = bias[j], bff = bias[384+j], bg = bias[768+j], bo = bias[1152+j];
  #pragma unroll
  for(int mt=0;mt<4;mt++){
    #pragma unroll
    for(int r=0;r<4;r++){
      int brow = mbase + wm*64 + mt*16 + (lane>>4)*4 + r;
      float zi = acc[mt][0][r]+bi, zf = acc[mt][1][r]+bff,
            zg = acc[mt][2][r]+bg, zo = acc[mt][3][r]+bo;
      size_t ci = (size_t)brow*HID + j;
      float cold = cst[ci];
      float cn = sigf(zf)*cold + sigf(zi)*tanh_f(zg);
      cst[ci] = cn;
      bf16 hb = (bf16)(sigf(zo)*tanh_f(cn));
      d0[(size_t)brow*ld0 + j] = hb;
      if(d1) d1[(size_t)brow*ld1 + j] = hb;
    }
  }
}

// ---------------- decoder LSTM ----------------
__global__ __launch_bounds__(256)
void dec_lstm_k(int t){
  __shared__ char smem[SMEM_BYTES];
  int bid = blockIdx.x, mb = bid/12, jb = bid%12;
  int rs = t&1, wsl = rs^1;
  f32x4 acc[4][4];
  gemm_core(g_Adec + (size_t)rs*NB*768 + (size_t)mb*128*768, 768,
            g_Bpd + (size_t)jb*24*4096, 24, smem, acc);
  lstm_epi(acc, mb*128, jb, g_biasd, g_cdec,
           g_Adec + (size_t)wsl*NB*768 + 384, 768, (bf16*)nullptr, 0);
}

// ---------------- plain GEMM: mode 1 = u-proj (+fused post for t-1), mode 0 = dec_in relu ----------------
__global__ __launch_bounds__(256)
void plain_gemm_k(int t, int mode, const float* __restrict__ outW,
                  const float* __restrict__ outb, float* __restrict__ out,
                  const float* __restrict__ ff){
  __shared__ char smem[SMEM_BYTES];
  int bid = blockIdx.x, mb = bid/3, nb = bid%3;
  int rs = t&1;
  const bf16* A; int ldA, nks; const bf16* Bp;
  if(mode==1){ A = g_Adec + (size_t)rs*NB*768 + 384; ldA=768; Bp = g_Bpu; nks=12; }
  else       { A = g_Adin;                           ldA=416; Bp = g_Bpi; nks=13; }
  f32x4 acc[4][4];
  gemm_core(A + (size_t)mb*128*ldA, ldA, Bp + (size_t)nb*nks*4096, nks, smem, acc);
  int lane = threadIdx.x&63, wv = threadIdx.x>>6, wm = wv>>1, wn = wv&1;
  bf16* dbf = g_Adec + (size_t)rs*NB*768;
  #pragma unroll
  for(int mt=0;mt<4;mt++){
    #pragma unroll
    for(int ti=0;ti<4;ti++){
      int n = nb*128 + (ti*2+wn)*16 + (lane&15);
      #pragma unroll
      for(int r=0;r<4;r++){
        int brow = mb*128 + wm*64 + mt*16 + (lane>>4)*4 + r;
        float v = acc[mt][ti][r];
        if(mode==0){ v += g_biasdin[n]; v = fmaxf(v,0.f); dbf[(size_t)brow*768 + n] = (bf16)v; }
        else g_u[(size_t)brow*384 + n] = v;
      }
    }
  }
  if(mode==1 && t>=1 && nb==0 && threadIdx.x<128){
    int b = mb*128 + threadIdx.x;
    const s16x8* hp = (const s16x8*)(g_Adec + (size_t)rs*NB*768 + (size_t)b*768 + 384);
    float acc2 = 0.f;
    #pragma unroll 4
    for(int i=0;i<48;i++){
      s16x8 v = hp[i];
      #pragma unroll
      for(int e=0;e<8;e++){
        float hv = __uint_as_float(((u32)(uint16_t)v[e])<<16);
        acc2 += hv*outW[i*8+e];
      }
    }
    float y = acc2 + outb[0];
    out[(size_t)b*HOR + (t-1)] = y;
    g_Adin[(size_t)b*416] = (bf16)y;
    #pragma unroll
    for(int k=0;k<4;k++) g_Adin[(size_t)b*416 + 1 + k] = (bf16)ff[(size_t)b*HOR*4 + t*4 + k];
  }
}

// ---------------- attention: fused scores+softmax+ctx (online, alternating sweep) ----------------
__global__ __launch_bounds__(256)
void attn_k(int t){
  __shared__ float sm[4][392];
  int tid = threadIdx.x, lane = tid&63, w = tid>>6;
  int bl = w>>1, hf = w&1;
  int b = blockIdx.x*2 + bl;
  const float* ub = g_u + (size_t)b*HID + lane*6;
  float u0=ub[0],u1=ub[1],u2=ub[2],u3=ub[3],u4=ub[4],u5=ub[5];
  const u32* er = (const u32*)(g_enc + (size_t)b*LSEQ*HID) + (size_t)hf*168*192 + lane*3;
  int estep = 192;
  if(t & 1){ er += (size_t)167*192; estep = -192; }
  float m=-1e30f, den=0.f, a0=0,a1=0,a2=0,a3=0,a4=0,a5=0;
  for(int l=0;l<168;l++){
    u32 w0 = er[0], w1 = er[1], w2 = er[2];
    er += estep;
    float e0 = __uint_as_float(w0<<16);
    float e1 = __uint_as_float(w0 & 0xffff0000u);
    float e2 = __uint_as_float(w1<<16);
    float e3 = __uint_as_float(w1 & 0xffff0000u);
    float e4 = __uint_as_float(w2<<16);
    float e5 = __uint_as_float(w2 & 0xffff0000u);
    float p = e0*u0 + e1*u1 + e2*u2 + e3*u3 + e4*u4 + e5*u5;
    #pragma unroll
    for(int o=1;o<64;o<<=1) p += __shfl_xor(p, o, 64);
    float mn = fmaxf(m, p);
    float al = __expf(m - mn), pe = __expf(p - mn);
    den = den*al + pe;
    a0 = a0*al + pe*e0; a1 = a1*al + pe*e1; a2 = a2*al + pe*e2;
    a3 = a3*al + pe*e3; a4 = a4*al + pe*e4; a5 = a5*al + pe*e5;
    m = mn;
  }
  if(lane==0){ sm[w][0]=m; sm[w][1]=den; }
  sm[w][2+lane*6+0]=a0; sm[w][2+lane*6+1]=a1; sm[w][2+lane*6+2]=a2;
  sm[w][2+lane*6+3]=a3; sm[w][2+lane*6+4]=a4; sm[w][2+lane*6+5]=a5;
  __syncthreads();
  if(hf==0){
    float m2 = sm[w+1][0], d2 = sm[w+1][1];
    float M = fmaxf(m, m2);
    float f1 = __expf(m - M), f2 = __expf(m2 - M);
    float inv = 1.f/(den*f1 + d2*f2);
    bf16* cd = g_Adin + (size_t)b*416 + 5 + lane*6;
    cd[0] = (bf16)((a0*f1 + sm[w+1][2+lane*6+0]*f2)*inv);
    cd[1] = (bf16)((a1*f1 + sm[w+1][2+lane*6+1]*f2)*inv);
    cd[2] = (bf16)((a2*f1 + sm[w+1][2+lane*6+2]*f2)*inv);
    cd[3] = (bf16)((a3*f1 + sm[w+1][2+lane*6+3]*f2)*inv);
    cd[4] = (bf16)((a4*f1 + sm[w+1][2+lane*6+4]*f2)*inv);
    cd[5] = (bf16)((a5*f1 + sm[w+1][2+lane*6+5]*f2)*inv);
  }
}

// ---------------- output head (final step only) ----------------
__global__ void post_k(int t, const float* __restrict__ outW,
                       const float* __restrict__ outb, float* __restrict__ out){
  int b = blockIdx.x*256 + threadIdx.x;
  if(b>=NB) return;
  int wsl = (t&1)^1;
  const s16x8* hp = (const s16x8*)(g_Adec + (size_t)wsl*NB*768 + (size_t)b*768 + 384);
  float acc = 0.f;
  #pragma unroll 4
  for(int i=0;i<48;i++){
    s16x8 v = hp[i];
    #pragma unroll
    for(int e=0;e<8;e++){
      float hv = __uint_as_float(((u32)(uint16_t)v[e])<<16);
      acc += hv*outW[i*8+e];
    }
  }
  out[(size_t)b*HOR + t] = acc + outb[0];
}

// ---------------- decoder init ----------------
__global__ void dec_prep_k(const float* __restrict__ ff){
  int i = blockIdx.x*256 + threadIdx.x;
  if(i < NB*HID){
    int b = i/HID, j = i%HID;
    g_Adec[(size_t)b*768 + 384 + j] = g_enc[(size_t)b*LSEQ*HID + (size_t)(LSEQ-1)*HID + j];
  }
  if(i < NB*4){
    int b = i>>2, k = i&3;
    g_Adin[(size_t)b*416 + 1 + k] = (bf16)ff[(size_t)b*HOR*4 + k];
  }
  if(i < NB) g_Adin[(size_t)i*416] = (bf16)0.f;
}

extern "C" void kernel_launch(void* const* d_in, const int* in_sizes, int n_in,
                              void* d_out, int out_size, void* d_ws, size_t ws_size,
                              hipStream_t stream){
  const float* x    = (const float*)d_in[0];
  const float* ff   = (const float*)d_in[1];
  const float* Wih0 = (const float*)d_in[2];
  const float* Whh0 = (const float*)d_in[3];
  const float* bih0 = (const float*)d_in[4];
  const float* bhh0 = (const float*)d_in[5];
  const float* Wih1 = (const float*)d_in[6];
  const float* Whh1 = (const float*)d_in[7];
  const float* bih1 = (const float*)d_in[8];
  const float* bhh1 = (const float*)d_in[9];
  const float* Wa   = (const float*)d_in[10];
  const float* dinW = (const float*)d_in[11];
  const float* dinb = (const float*)d_in[12];
  const float* dWih = (const float*)d_in[13];
  const float* dWhh = (const float*)d_in[14];
  const float* dbih = (const float*)d_in[15];
  const float* dbhh = (const float*)d_in[16];
  const float* outW = (const float*)d_in[17];
  const float* outb = (const float*)d_in[18];
  float* out = (float*)d_out;

  zero_state_k<<<1024,256,0,stream>>>();
  pack_xb_k<<<2048,256,0,stream>>>(x);
  pack_gates_k<<<(12*13*512)/256,256,0,stream>>>(0, Whh0, Wih0, 13);
  pack_gates16_k<<<576,256,0,stream>>>(Wih1, Whh1);
  pack_gates_k<<<(12*24*512)/256,256,0,stream>>>(2, dWih, dWhh, 24);
  pack_plain_k<<<(3*13*512)/256,256,0,stream>>>(0, dinW, 13, 3);
  pack_plain_k<<<(3*12*512)/256,256,0,stream>>>(1, Wa, 12, 3);
  prep_misc_k<<<8,256,0,stream>>>(bih0,bhh0,bih1,bhh1,dbih,dbhh,dinb);

  hipFuncSetAttribute((const void*)enc9_k,
                      hipFuncAttributeMaxDynamicSharedMemorySize, 114688);
  enc9_k<<<192,256,114688,stream>>>();

  dec_prep_k<<<1536,256,0,stream>>>(ff);
  for(int t=0;t<HOR;t++){
    plain_gemm_k<<<24,256,0,stream>>>(t, 1, outW, outb, out, ff);
    attn_k<<<512,256,0,stream>>>(t);
    plain_gemm_k<<<24,256,0,stream>>>(t, 0, outW, outb, out, ff);
    dec_lstm_k<<<96,256,0,stream>>>(t);
  }
  post_k<<<4,256,0,stream>>>(17, outW, outb, out);
  (void)in_sizes; (void)n_in; (void)out_size; (void)d_ws; (void)ws_size;
}